// Round 6
// baseline (888.366 us; speedup 1.0000x reference)
//
#include <hip/hip_runtime.h>

#define B_ 32
#define N_ 4096
#define D_ 512
#define S_ 8
#define ITERS_ 3

__device__ __forceinline__ float sigmoid_f(float x) {
    return 1.0f / (1.0f + __expf(-x));
}
__device__ __forceinline__ float tanh_f(float x) {
    float e = __expf(2.0f * x);
    return 1.0f - 2.0f / (e + 1.0f);
}

// ---------------------------------------------------------------- slot init (+ LN stats per row)
__global__ __launch_bounds__(256) void k_init(const float* __restrict__ noise,
                                              const float* __restrict__ mu,
                                              const float* __restrict__ sg,
                                              float* __restrict__ slots,
                                              float* __restrict__ stats) {
    int wid = threadIdx.x >> 6, lane = threadIdx.x & 63;
    int row = blockIdx.x * 4 + wid;                       // 0..255
    const float4* nz = (const float4*)(noise + (size_t)row * D_);
    const float4* m4 = (const float4*)(mu + (size_t)(row & 7) * D_);
    const float4* s4 = (const float4*)(sg + (size_t)(row & 7) * D_);
    float4 v0 = nz[lane], v1 = nz[64 + lane];
    float4 a0 = m4[lane], a1 = m4[64 + lane];
    float4 c0 = s4[lane], c1 = s4[64 + lane];
    v0.x = fmaf(c0.x, v0.x, a0.x); v0.y = fmaf(c0.y, v0.y, a0.y);
    v0.z = fmaf(c0.z, v0.z, a0.z); v0.w = fmaf(c0.w, v0.w, a0.w);
    v1.x = fmaf(c1.x, v1.x, a1.x); v1.y = fmaf(c1.y, v1.y, a1.y);
    v1.z = fmaf(c1.z, v1.z, a1.z); v1.w = fmaf(c1.w, v1.w, a1.w);
    float4* o4 = (float4*)(slots + (size_t)row * D_);
    o4[lane] = v0; o4[64 + lane] = v1;
    float s1 = v0.x + v0.y + v0.z + v0.w + v1.x + v1.y + v1.z + v1.w;
    float s2 = v0.x*v0.x; s2 = fmaf(v0.y,v0.y,s2); s2 = fmaf(v0.z,v0.z,s2); s2 = fmaf(v0.w,v0.w,s2);
    s2 = fmaf(v1.x,v1.x,s2); s2 = fmaf(v1.y,v1.y,s2); s2 = fmaf(v1.z,v1.z,s2); s2 = fmaf(v1.w,v1.w,s2);
#pragma unroll
    for (int off = 32; off > 0; off >>= 1) {
        s1 += __shfl_xor(s1, off, 64);
        s2 += __shfl_xor(s2, off, 64);
    }
    if (lane == 0) {
        float mean = s1 * (1.0f / D_);
        float var  = s2 * (1.0f / D_) - mean * mean;
        stats[row * 2]     = mean;
        stats[row * 2 + 1] = rsqrtf(var + 1e-5f);
    }
}

// ---------------------------------------------------------------- small GEMM (prologue only)
template<int WT, int LNA>
__global__ __launch_bounds__(256) void k_gemm(const float* __restrict__ A,
                                              const float* __restrict__ W,
                                              const float* __restrict__ bias,
                                              float* __restrict__ C,
                                              int M, int N, int K,
                                              const float* __restrict__ stats,
                                              const float* __restrict__ lng,
                                              const float* __restrict__ lnb) {
    __shared__ float As[64][68];
    __shared__ float Ws[64][36];
    int t  = threadIdx.x;
    int bm = blockIdx.y * 64, bn = blockIdx.x * 32;
    int tm = t >> 4, tn = t & 15;
    float acc[4][2] = {{0.f,0.f},{0.f,0.f},{0.f,0.f},{0.f,0.f}};

    for (int kk = 0; kk < K; kk += 64) {
        __syncthreads();
        if (WT == 2) {
#pragma unroll
            for (int r = 0; r < 4; ++r) {
                int idx = t + r * 256;
                int k = idx >> 4, m4 = idx & 15;
                float4 a4 = *(const float4*)(A + (size_t)(kk + k) * M + bm + (m4 << 2));
                *(float4*)&As[k][m4 << 2] = a4;
            }
        } else {
#pragma unroll
            for (int r = 0; r < 4; ++r) {
                int flat = t * 4 + r * 1024;
                int m = flat >> 6, k = flat & 63;
                float4 a4 = *(const float4*)(A + (size_t)(bm + m) * K + kk + k);
                if (LNA) {
                    float mean = stats[(bm + m) * 2];
                    float rs   = stats[(bm + m) * 2 + 1];
                    float4 g4 = *(const float4*)(lng + kk + k);
                    float4 b4 = *(const float4*)(lnb + kk + k);
                    a4.x = fmaf((a4.x - mean) * rs, g4.x, b4.x);
                    a4.y = fmaf((a4.y - mean) * rs, g4.y, b4.y);
                    a4.z = fmaf((a4.z - mean) * rs, g4.z, b4.z);
                    a4.w = fmaf((a4.w - mean) * rs, g4.w, b4.w);
                }
                As[k + 0][m] = a4.x; As[k + 1][m] = a4.y;
                As[k + 2][m] = a4.z; As[k + 3][m] = a4.w;
            }
        }
        if (WT == 1) {
#pragma unroll
            for (int r = 0; r < 2; ++r) {
                int flat = t * 4 + r * 1024;
                int n = flat >> 6, k = flat & 63;
                float4 w4 = *(const float4*)(W + (size_t)(bn + n) * K + kk + k);
                Ws[k + 0][n] = w4.x; Ws[k + 1][n] = w4.y;
                Ws[k + 2][n] = w4.z; Ws[k + 3][n] = w4.w;
            }
        } else {
#pragma unroll
            for (int r = 0; r < 2; ++r) {
                int flat = t * 4 + r * 1024;
                int k = flat >> 5, n = flat & 31;
                float4 w4 = *(const float4*)(W + (size_t)(kk + k) * N + bn + n);
                *(float4*)&Ws[k][n] = w4;
            }
        }
        __syncthreads();
#pragma unroll
        for (int k = 0; k < 64; ++k) {
            float4 a = *(const float4*)&As[k][tm << 2];
            float2 w = *(const float2*)&Ws[k][tn << 1];
            acc[0][0] = fmaf(a.x, w.x, acc[0][0]); acc[0][1] = fmaf(a.x, w.y, acc[0][1]);
            acc[1][0] = fmaf(a.y, w.x, acc[1][0]); acc[1][1] = fmaf(a.y, w.y, acc[1][1]);
            acc[2][0] = fmaf(a.z, w.x, acc[2][0]); acc[2][1] = fmaf(a.z, w.y, acc[2][1]);
            acc[3][0] = fmaf(a.w, w.x, acc[3][0]); acc[3][1] = fmaf(a.w, w.y, acc[3][1]);
        }
    }
#pragma unroll
    for (int i = 0; i < 4; ++i) {
#pragma unroll
        for (int j = 0; j < 2; ++j) {
            int row = bm + (tm << 2) + i;
            int col = bn + (tn << 1) + j;
            float v = acc[i][j];
            if (bias) v += bias[col];
            C[(size_t)row * N + col] = v;
        }
    }
}

// ---------------------------------------------------------------- fused attention, 512 threads
// 2 threads/row in phase A (depth-4 prefetch), 1 float/thread coalesced phase B
__global__ __launch_bounds__(512, 4) void k_attn2(const float* __restrict__ x,
                                                  const float* __restrict__ qk,
                                                  const float* __restrict__ g,
                                                  const float* __restrict__ bvec,
                                                  float* __restrict__ part,
                                                  float* __restrict__ bsum) {
    __shared__ float qts[4096];   // q-tilde, k-major: [(k4)*8 + s] float4s
    __shared__ float ws[2048];    // per-row w[8] for 256 rows
    __shared__ float red[64];
    __shared__ float red2[64];
    __shared__ float c12[16];
    const int nc = blockIdx.x, b = blockIdx.y;
    const int t = threadIdx.x;
    const int w = t >> 6, lane = t & 63;

    // ---- q-prep: qts = g .* qk (k-major), c1[s]=sum(g*qk), c2[s]=sum(b*qk)
    {
        const float4* qk4 = (const float4*)(qk + (size_t)b * 4096);
        const float4* g4 = (const float4*)g;
        const float4* b4 = (const float4*)bvec;
        float c1p[2], c2p[2];
#pragma unroll
        for (int r = 0; r < 2; ++r) {
            int f = t + r * 512;                 // s = f>>7 (wave-uniform)
            float4 v = qk4[f];
            float4 gg = g4[f & 127];
            float4 bb = b4[f & 127];
            float4 qv = make_float4(v.x*gg.x, v.y*gg.y, v.z*gg.z, v.w*gg.w);
            *(float4*)&qts[((f & 127) * 8 + (f >> 7)) * 4] = qv;
            c1p[r] = qv.x + qv.y + qv.z + qv.w;
            c2p[r] = bb.x*v.x + bb.y*v.y + bb.z*v.z + bb.w*v.w;
        }
#pragma unroll
        for (int off = 32; off > 0; off >>= 1) {
#pragma unroll
            for (int r = 0; r < 2; ++r) {
                c1p[r] += __shfl_xor(c1p[r], off, 64);
                c2p[r] += __shfl_xor(c2p[r], off, 64);
            }
        }
        if (lane == 0) {
            red[w * 2 + 0] = c1p[0]; red[w * 2 + 1] = c1p[1];
            red2[w * 2 + 0] = c2p[0]; red2[w * 2 + 1] = c2p[1];
        }
    }
    __syncthreads();
    if (t < 8) {
        int s = t;
        float v1, v2;
        if (s < 4) { v1 = red[4*s]     + red[4*s + 2];     v2 = red2[4*s]     + red2[4*s + 2]; }
        else       { v1 = red[4*(s-4)+1] + red[4*(s-4)+3]; v2 = red2[4*(s-4)+1] + red2[4*(s-4)+3]; }
        c12[s] = v1; c12[8 + s] = v2;
    }
    __syncthreads();

    const float cnorm = 1.0f / (1.0f + 8.0f * 1e-8f);
    const float eadd  = 1e-8f * cnorm;
    float aa[8], wmu[8];
    // ---- phase A: 2 threads per row, depth-4 prefetch
    {
        const int row = t >> 1, half = t & 1;
        const float4* rp = (const float4*)(x + ((size_t)b * N_ + (size_t)nc * 256 + row) * D_)
                           + half * 64;
        float dot8[8] = {0.f,0.f,0.f,0.f,0.f,0.f,0.f,0.f};
        float sx = 0.f, sxx = 0.f;
        const int kb = half * 64;

        float4 c0 = rp[0], c1 = rp[1], c2 = rp[2], c3 = rp[3];
#define PROC(V, K4)                                                              \
        {                                                                        \
            sx += (V).x + (V).y + (V).z + (V).w;                                 \
            sxx = fmaf((V).x,(V).x,sxx); sxx = fmaf((V).y,(V).y,sxx);            \
            sxx = fmaf((V).z,(V).z,sxx); sxx = fmaf((V).w,(V).w,sxx);            \
            _Pragma("unroll")                                                    \
            for (int s = 0; s < 8; ++s) {                                        \
                float4 qv = *(const float4*)&qts[((K4) * 8 + s) * 4];            \
                dot8[s] = fmaf((V).x, qv.x, dot8[s]);                            \
                dot8[s] = fmaf((V).y, qv.y, dot8[s]);                            \
                dot8[s] = fmaf((V).z, qv.z, dot8[s]);                            \
                dot8[s] = fmaf((V).w, qv.w, dot8[s]);                            \
            }                                                                    \
        }
        for (int j = 0; j < 64; j += 4) {
            int jn = (j < 60) ? j + 4 : 60;
            float4 n0 = rp[jn], n1 = rp[jn + 1], n2 = rp[jn + 2], n3 = rp[jn + 3];
            PROC(c0, kb + j);
            PROC(c1, kb + j + 1);
            PROC(c2, kb + j + 2);
            PROC(c3, kb + j + 3);
            c0 = n0; c1 = n1; c2 = n2; c3 = n3;
        }
#undef PROC
        // merge the two halves (lane pairs) -> both get bitwise-identical sums
        sx  += __shfl_xor(sx, 1, 64);
        sxx += __shfl_xor(sxx, 1, 64);
#pragma unroll
        for (int s = 0; s < 8; ++s) dot8[s] += __shfl_xor(dot8[s], 1, 64);

        float mean = sx * (1.0f / D_);
        float rs   = rsqrtf(sxx * (1.0f / D_) - mean * mean + 1e-5f);
        float mc   = -rs * mean;
        float l[8];
#pragma unroll
        for (int s = 0; s < 8; ++s)
            l[s] = fmaf(rs, dot8[s], fmaf(mc, c12[s], c12[8 + s]));
        float mx = l[0];
#pragma unroll
        for (int s = 1; s < 8; ++s) mx = fmaxf(mx, l[s]);
        float psum = 0.f;
#pragma unroll
        for (int s = 0; s < 8; ++s) { l[s] = __expf(l[s] - mx); psum += l[s]; }
        float ip = cnorm / psum;
        float wv0[8];
#pragma unroll
        for (int s = 0; s < 8; ++s) {
            aa[s]  = fmaf(l[s], ip, eadd);
            wv0[s] = aa[s] * rs;
            wmu[s] = wv0[s] * mean;
        }
        if (half == 0)
            *(float4*)&ws[row * 8]     = make_float4(wv0[0], wv0[1], wv0[2], wv0[3]);
        else
            *(float4*)&ws[row * 8 + 4] = make_float4(wv0[4], wv0[5], wv0[6], wv0[7]);
    }
    // ---- block reduce Av (sum a) and Tv (sum w*mu); lane-pairs hold duplicates -> x2
#pragma unroll
    for (int off = 32; off > 0; off >>= 1) {
#pragma unroll
        for (int s = 0; s < 8; ++s) {
            aa[s]  += __shfl_xor(aa[s], off, 64);
            wmu[s] += __shfl_xor(wmu[s], off, 64);
        }
    }
    if (lane == 0) {
#pragma unroll
        for (int s = 0; s < 8; ++s) { red[w * 8 + s] = aa[s]; red2[w * 8 + s] = wmu[s]; }
    }
    __syncthreads();
    if (t < 16) {
        int s = t & 7;
        const float* src = (t < 8) ? red : red2;
        float v = 0.f;
#pragma unroll
        for (int w2 = 0; w2 < 8; ++w2) v += src[w2 * 8 + s];
        bsum[(size_t)(b * 16 + nc) * 16 + t] = 0.5f * v;   // halve the pair-duplicate
    }
    // ---- phase B: coalesced P[s][d] partials, 1 float/thread
    {
        const float* xp = x + ((size_t)b * N_ + (size_t)nc * 256) * D_ + t;
        float P[8] = {0.f,0.f,0.f,0.f,0.f,0.f,0.f,0.f};
#pragma unroll 4
        for (int i = 0; i < 256; ++i) {
            float xv = xp[(size_t)i * D_];
            float4 w01 = *(const float4*)&ws[i * 8];       // LDS broadcast
            float4 w23 = *(const float4*)&ws[i * 8 + 4];
            P[0] = fmaf(w01.x, xv, P[0]);
            P[1] = fmaf(w01.y, xv, P[1]);
            P[2] = fmaf(w01.z, xv, P[2]);
            P[3] = fmaf(w01.w, xv, P[3]);
            P[4] = fmaf(w23.x, xv, P[4]);
            P[5] = fmaf(w23.y, xv, P[5]);
            P[6] = fmaf(w23.z, xv, P[6]);
            P[7] = fmaf(w23.w, xv, P[7]);
        }
        float* o = part + (size_t)(b * 16 + nc) * 4096 + t;
#pragma unroll
        for (int s = 0; s < 8; ++s) o[s * 512] = P[s];
    }
}

// ---------------------------------------------------------------- u0 reduce + affine correction
__global__ __launch_bounds__(256) void k_ured(const float* __restrict__ part,
                                              const float* __restrict__ bsum,
                                              const float* __restrict__ g,
                                              const float* __restrict__ bvec,
                                              float* __restrict__ u0) {
    __shared__ float avs[16];
    const int b = blockIdx.x, t = threadIdx.x;
    if (t < 16) {
        float v = 0.f;
#pragma unroll
        for (int nc = 0; nc < 16; ++nc) v += bsum[(size_t)(b * 16 + nc) * 16 + t];
        avs[t] = v;
    }
    __syncthreads();
    const int d0 = t * 2;
    float gg0 = g[d0], gg1 = g[d0 + 1], bb0 = bvec[d0], bb1 = bvec[d0 + 1];
#pragma unroll
    for (int s = 0; s < 8; ++s) {
        float p0 = 0.f, p1 = 0.f;
#pragma unroll
        for (int nc = 0; nc < 16; ++nc) {
            float2 pv = *(const float2*)(part + (size_t)(b * 16 + nc) * 4096 + s * 512 + d0);
            p0 += pv.x; p1 += pv.y;
        }
        float Av = avs[s], Tv = avs[8 + s];
        float* o = u0 + (size_t)(b * 8 + s) * D_ + d0;
        o[0] = fmaf(gg0, p0 - Tv, Av * bb0);
        o[1] = fmaf(gg1, p1 - Tv, Av * bb1);
    }
}

// ---------------------------------------------------------------- gi+gh merged GEMM: gg[256][3072]
__global__ __launch_bounds__(256) void k_gg(const float* __restrict__ slots,
                                            const float* __restrict__ u0,
                                            const float* __restrict__ w_hh,
                                            const float* __restrict__ Wiv,
                                            const float* __restrict__ b_hh,
                                            const float* __restrict__ b_ih,
                                            float* __restrict__ gg) {
    __shared__ float As[64][68];
    __shared__ float Ws[64][36];
    const int t = threadIdx.x;
    const int bx = blockIdx.x;
    const int isGi = (bx >= 48);
    const float* A    = isGi ? u0 : slots;
    const float* W    = isGi ? Wiv : w_hh;
    const float* bias = isGi ? b_ih : b_hh;
    const int bnw = (isGi ? (bx - 48) : bx) * 32;
    const int bnc = bx * 32;
    const int bm  = blockIdx.y * 64;
    int tm = t >> 4, tn = t & 15;
    float acc[4][2] = {{0.f,0.f},{0.f,0.f},{0.f,0.f},{0.f,0.f}};

    for (int kk = 0; kk < 512; kk += 64) {
        __syncthreads();
#pragma unroll
        for (int r = 0; r < 4; ++r) {
            int flat = t * 4 + r * 1024;
            int m = flat >> 6, k = flat & 63;
            float4 a4 = *(const float4*)(A + (size_t)(bm + m) * 512 + kk + k);
            As[k + 0][m] = a4.x; As[k + 1][m] = a4.y;
            As[k + 2][m] = a4.z; As[k + 3][m] = a4.w;
        }
#pragma unroll
        for (int r = 0; r < 2; ++r) {
            int flat = t * 4 + r * 1024;
            int n = flat >> 6, k = flat & 63;
            float4 w4 = *(const float4*)(W + (size_t)(bnw + n) * 512 + kk + k);
            Ws[k + 0][n] = w4.x; Ws[k + 1][n] = w4.y;
            Ws[k + 2][n] = w4.z; Ws[k + 3][n] = w4.w;
        }
        __syncthreads();
#pragma unroll
        for (int k = 0; k < 64; ++k) {
            float4 a = *(const float4*)&As[k][tm << 2];
            float2 w = *(const float2*)&Ws[k][tn << 1];
            acc[0][0] = fmaf(a.x, w.x, acc[0][0]); acc[0][1] = fmaf(a.x, w.y, acc[0][1]);
            acc[1][0] = fmaf(a.y, w.x, acc[1][0]); acc[1][1] = fmaf(a.y, w.y, acc[1][1]);
            acc[2][0] = fmaf(a.z, w.x, acc[2][0]); acc[2][1] = fmaf(a.z, w.y, acc[2][1]);
            acc[3][0] = fmaf(a.w, w.x, acc[3][0]); acc[3][1] = fmaf(a.w, w.y, acc[3][1]);
        }
    }
#pragma unroll
    for (int i = 0; i < 4; ++i) {
#pragma unroll
        for (int j = 0; j < 2; ++j) {
            int row = bm + (tm << 2) + i;
            int cw  = bnw + (tn << 1) + j;
            gg[(size_t)row * 3072 + bnc + (tn << 1) + j] = acc[i][j] + bias[cw];
        }
    }
}

// ---------------------------------------------------------------- P2: GRU + MLP + LN + qk_next
__global__ __launch_bounds__(512) void k_p2(const float* __restrict__ gg,
                                            const float* __restrict__ slots,
                                            const float* __restrict__ w1, const float* __restrict__ b1,
                                            const float* __restrict__ w2, const float* __restrict__ b2,
                                            const float* __restrict__ wqkT,
                                            const float* __restrict__ ln_m_g, const float* __restrict__ ln_m_b,
                                            const float* __restrict__ ln_s_g, const float* __restrict__ ln_s_b,
                                            float* __restrict__ dst, float* __restrict__ qkout, int last) {
    __shared__ float s2s[2][512];
    __shared__ float t0s[2][512];
    __shared__ float hs[2][512];
    __shared__ float stat[4];
    const int t = threadIdx.x;
    const int wid = t >> 6, lane = t & 63;
    const int r0 = blockIdx.x * 2;

#pragma unroll
    for (int j = 0; j < 2; ++j) {
        int flat = t + j * 512;
        int r = flat >> 9, d = flat & 511;
        size_t row = r0 + r;
        const float* ghb = gg + row * 3072;
        const float* gib = ghb + 1536;
        float gir = gib[d], giz = gib[d + 512], gin = gib[d + 1024];
        float ghr = ghb[d], ghz = ghb[d + 512], ghn = ghb[d + 1024];
        float rr = sigmoid_f(gir + ghr);
        float zz = sigmoid_f(giz + ghz);
        float nn = tanh_f(fmaf(rr, ghn, gin));
        float sp = slots[row * 512 + d];
        s2s[r][d] = fmaf(1.0f - zz, nn, zz * sp);
    }
    __syncthreads();
    if (wid < 2) {
        const float4* sr = (const float4*)s2s[wid];
        float4 a = sr[lane], bq = sr[64 + lane];
        float s1 = a.x + a.y + a.z + a.w + bq.x + bq.y + bq.z + bq.w;
        float s2 = a.x*a.x; s2 = fmaf(a.y,a.y,s2); s2 = fmaf(a.z,a.z,s2); s2 = fmaf(a.w,a.w,s2);
        s2 = fmaf(bq.x,bq.x,s2); s2 = fmaf(bq.y,bq.y,s2); s2 = fmaf(bq.z,bq.z,s2); s2 = fmaf(bq.w,bq.w,s2);
#pragma unroll
        for (int off = 32; off > 0; off >>= 1) {
            s1 += __shfl_xor(s1, off, 64);
            s2 += __shfl_xor(s2, off, 64);
        }
        if (lane == 0) {
            float mean = s1 * (1.0f / D_);
            float var  = s2 * (1.0f / D_) - mean * mean;
            stat[wid * 2] = mean;
            stat[wid * 2 + 1] = rsqrtf(var + 1e-5f);
        }
    }
    __syncthreads();
#pragma unroll
    for (int j = 0; j < 2; ++j) {
        int flat = t + j * 512;
        int r = flat >> 9, d = flat & 511;
        t0s[r][d] = fmaf((s2s[r][d] - stat[r * 2]) * stat[r * 2 + 1], ln_m_g[d], ln_m_b[d]);
    }
    __syncthreads();
    {
        const int c = t;
        const float4* wr = (const float4*)(w1 + (size_t)c * 512);
        float a0 = 0.f, a1 = 0.f;
#pragma unroll 8
        for (int k4 = 0; k4 < 128; ++k4) {
            float4 w4 = wr[k4];
            float4 q0 = *(const float4*)&t0s[0][k4 << 2];
            float4 q1 = *(const float4*)&t0s[1][k4 << 2];
            a0 = fmaf(q0.x, w4.x, a0); a0 = fmaf(q0.y, w4.y, a0);
            a0 = fmaf(q0.z, w4.z, a0); a0 = fmaf(q0.w, w4.w, a0);
            a1 = fmaf(q1.x, w4.x, a1); a1 = fmaf(q1.y, w4.y, a1);
            a1 = fmaf(q1.z, w4.z, a1); a1 = fmaf(q1.w, w4.w, a1);
        }
        float bc = b1[c];
        hs[0][c] = fmaxf(a0 + bc, 0.f);
        hs[1][c] = fmaxf(a1 + bc, 0.f);
    }
    __syncthreads();
    {
        const int c = t;
        const float4* wr = (const float4*)(w2 + (size_t)c * 512);
        float a0 = 0.f, a1 = 0.f;
#pragma unroll 8
        for (int k4 = 0; k4 < 128; ++k4) {
            float4 w4 = wr[k4];
            float4 q0 = *(const float4*)&hs[0][k4 << 2];
            float4 q1 = *(const float4*)&hs[1][k4 << 2];
            a0 = fmaf(q0.x, w4.x, a0); a0 = fmaf(q0.y, w4.y, a0);
            a0 = fmaf(q0.z, w4.z, a0); a0 = fmaf(q0.w, w4.w, a0);
            a1 = fmaf(q1.x, w4.x, a1); a1 = fmaf(q1.y, w4.y, a1);
            a1 = fmaf(q1.z, w4.z, a1); a1 = fmaf(q1.w, w4.w, a1);
        }
        float bc = b2[c];
        float o0 = s2s[0][c] + a0 + bc;
        float o1 = s2s[1][c] + a1 + bc;
        dst[(size_t)r0 * 512 + c] = o0;
        dst[(size_t)(r0 + 1) * 512 + c] = o1;
        s2s[0][c] = o0;
        s2s[1][c] = o1;
    }
    if (last) return;
    __syncthreads();
    if (wid < 2) {
        const float4* sr = (const float4*)s2s[wid];
        float4 a = sr[lane], bq = sr[64 + lane];
        float s1 = a.x + a.y + a.z + a.w + bq.x + bq.y + bq.z + bq.w;
        float s2 = a.x*a.x; s2 = fmaf(a.y,a.y,s2); s2 = fmaf(a.z,a.z,s2); s2 = fmaf(a.w,a.w,s2);
        s2 = fmaf(bq.x,bq.x,s2); s2 = fmaf(bq.y,bq.y,s2); s2 = fmaf(bq.z,bq.z,s2); s2 = fmaf(bq.w,bq.w,s2);
#pragma unroll
        for (int off = 32; off > 0; off >>= 1) {
            s1 += __shfl_xor(s1, off, 64);
            s2 += __shfl_xor(s2, off, 64);
        }
        if (lane == 0) {
            float mean = s1 * (1.0f / D_);
            float var  = s2 * (1.0f / D_) - mean * mean;
            stat[wid * 2] = mean;
            stat[wid * 2 + 1] = rsqrtf(var + 1e-5f);
        }
    }
    __syncthreads();
#pragma unroll
    for (int j = 0; j < 2; ++j) {
        int flat = t + j * 512;
        int r = flat >> 9, d = flat & 511;
        t0s[r][d] = fmaf((s2s[r][d] - stat[r * 2]) * stat[r * 2 + 1], ln_s_g[d], ln_s_b[d]);
    }
    __syncthreads();
    {
        const int c = t;
        const float4* wr = (const float4*)(wqkT + (size_t)c * 512);
        float a0 = 0.f, a1 = 0.f;
#pragma unroll 8
        for (int k4 = 0; k4 < 128; ++k4) {
            float4 w4 = wr[k4];
            float4 q0 = *(const float4*)&t0s[0][k4 << 2];
            float4 q1 = *(const float4*)&t0s[1][k4 << 2];
            a0 = fmaf(q0.x, w4.x, a0); a0 = fmaf(q0.y, w4.y, a0);
            a0 = fmaf(q0.z, w4.z, a0); a0 = fmaf(q0.w, w4.w, a0);
            a1 = fmaf(q1.x, w4.x, a1); a1 = fmaf(q1.y, w4.y, a1);
            a1 = fmaf(q1.z, w4.z, a1); a1 = fmaf(q1.w, w4.w, a1);
        }
        qkout[(size_t)r0 * 512 + c] = a0;
        qkout[(size_t)(r0 + 1) * 512 + c] = a1;
    }
}

// ---------------------------------------------------------------- launch
extern "C" void kernel_launch(void* const* d_in, const int* in_sizes, int n_in,
                              void* d_out, int out_size, void* d_ws, size_t ws_size,
                              hipStream_t stream) {
    const float* inputs  = (const float*)d_in[0];
    const float* noise   = (const float*)d_in[1];
    const float* mu      = (const float*)d_in[2];
    const float* sg      = (const float*)d_in[3];
    const float* ln_in_g = (const float*)d_in[4];
    const float* ln_in_b = (const float*)d_in[5];
    const float* ln_s_g  = (const float*)d_in[6];
    const float* ln_s_b  = (const float*)d_in[7];
    const float* wq      = (const float*)d_in[8];
    const float* wk      = (const float*)d_in[9];
    const float* wv      = (const float*)d_in[10];
    const float* w_ih    = (const float*)d_in[11];
    const float* w_hh    = (const float*)d_in[12];
    const float* b_ih    = (const float*)d_in[13];
    const float* b_hh    = (const float*)d_in[14];
    const float* ln_m_g  = (const float*)d_in[15];
    const float* ln_m_b  = (const float*)d_in[16];
    const float* w1      = (const float*)d_in[17];
    const float* b1      = (const float*)d_in[18];
    const float* w2      = (const float*)d_in[19];
    const float* b2      = (const float*)d_in[20];

    float* ws = (float*)d_ws;
    const size_t SLOT = (size_t)B_ * S_ * D_;      // 131072
    size_t o = 0;
    float* slots = ws + o; o += SLOT;
    float* qk    = ws + o; o += SLOT;
    float* u0    = ws + o; o += SLOT;
    float* gg    = ws + o; o += (size_t)256 * 3072;       // 786432
    float* Mqk   = ws + o; o += (size_t)D_ * D_;          // 262144
    float* Wiv   = ws + o; o += (size_t)3 * D_ * D_;      // 786432
    float* statsS= ws + o; o += 512;
    float* part  = ws + o; o += (size_t)16 * B_ * 4096;   // 2097152
    float* bsum  = ws + o; o += (size_t)B_ * 16 * 16;     // 8192

    // ---- prologue (4 dispatches)
    k_gemm<2,0><<<dim3(16, 8), 256, 0, stream>>>(wk, wq, nullptr, Mqk,
                                                 512, 512, 512, nullptr, nullptr, nullptr);
    k_gemm<0,0><<<dim3(16, 24), 256, 0, stream>>>(w_ih, wv, nullptr, Wiv,
                                                  1536, 512, 512, nullptr, nullptr, nullptr);
    k_init<<<64, 256, 0, stream>>>(noise, mu, sg, slots, statsS);
    k_gemm<1,1><<<dim3(16, 4), 256, 0, stream>>>(slots, Mqk, nullptr, qk,
                                                 256, 512, 512, statsS, ln_s_g, ln_s_b);

    for (int it = 0; it < ITERS_; ++it) {
        k_attn2<<<dim3(16, B_), 512, 0, stream>>>(inputs, qk, ln_in_g, ln_in_b, part, bsum);
        k_ured<<<B_, 256, 0, stream>>>(part, bsum, ln_in_g, ln_in_b, u0);
        k_gg<<<dim3(96, 4), 256, 0, stream>>>(slots, u0, w_hh, Wiv, b_hh, b_ih, gg);
        int last = (it == ITERS_ - 1);
        float* dst = last ? (float*)d_out : slots;
        k_p2<<<128, 512, 0, stream>>>(gg, slots, w1, b1, w2, b2, Mqk,
                                      ln_m_g, ln_m_b, ln_s_g, ln_s_b, dst, qk, last);
    }
}

// Round 7
// 730.578 us; speedup vs baseline: 1.2160x; 1.2160x over previous
//
#include <hip/hip_runtime.h>

#define B_ 32
#define N_ 4096
#define D_ 512
#define S_ 8
#define ITERS_ 3

__device__ __forceinline__ float sigmoid_f(float x) {
    return 1.0f / (1.0f + __expf(-x));
}
__device__ __forceinline__ float tanh_f(float x) {
    float e = __expf(2.0f * x);
    return 1.0f - 2.0f / (e + 1.0f);
}

// ---------------------------------------------------------------- slot init (+ LN stats per row)
__global__ __launch_bounds__(256) void k_init(const float* __restrict__ noise,
                                              const float* __restrict__ mu,
                                              const float* __restrict__ sg,
                                              float* __restrict__ slots,
                                              float* __restrict__ stats) {
    int wid = threadIdx.x >> 6, lane = threadIdx.x & 63;
    int row = blockIdx.x * 4 + wid;                       // 0..255
    const float4* nz = (const float4*)(noise + (size_t)row * D_);
    const float4* m4 = (const float4*)(mu + (size_t)(row & 7) * D_);
    const float4* s4 = (const float4*)(sg + (size_t)(row & 7) * D_);
    float4 v0 = nz[lane], v1 = nz[64 + lane];
    float4 a0 = m4[lane], a1 = m4[64 + lane];
    float4 c0 = s4[lane], c1 = s4[64 + lane];
    v0.x = fmaf(c0.x, v0.x, a0.x); v0.y = fmaf(c0.y, v0.y, a0.y);
    v0.z = fmaf(c0.z, v0.z, a0.z); v0.w = fmaf(c0.w, v0.w, a0.w);
    v1.x = fmaf(c1.x, v1.x, a1.x); v1.y = fmaf(c1.y, v1.y, a1.y);
    v1.z = fmaf(c1.z, v1.z, a1.z); v1.w = fmaf(c1.w, v1.w, a1.w);
    float4* o4 = (float4*)(slots + (size_t)row * D_);
    o4[lane] = v0; o4[64 + lane] = v1;
    float s1 = v0.x + v0.y + v0.z + v0.w + v1.x + v1.y + v1.z + v1.w;
    float s2 = v0.x*v0.x; s2 = fmaf(v0.y,v0.y,s2); s2 = fmaf(v0.z,v0.z,s2); s2 = fmaf(v0.w,v0.w,s2);
    s2 = fmaf(v1.x,v1.x,s2); s2 = fmaf(v1.y,v1.y,s2); s2 = fmaf(v1.z,v1.z,s2); s2 = fmaf(v1.w,v1.w,s2);
#pragma unroll
    for (int off = 32; off > 0; off >>= 1) {
        s1 += __shfl_xor(s1, off, 64);
        s2 += __shfl_xor(s2, off, 64);
    }
    if (lane == 0) {
        float mean = s1 * (1.0f / D_);
        float var  = s2 * (1.0f / D_) - mean * mean;
        stats[row * 2]     = mean;
        stats[row * 2 + 1] = rsqrtf(var + 1e-5f);
    }
}

// ---------------------------------------------------------------- small GEMM (prologue only)
template<int WT, int LNA>
__global__ __launch_bounds__(256) void k_gemm(const float* __restrict__ A,
                                              const float* __restrict__ W,
                                              const float* __restrict__ bias,
                                              float* __restrict__ C,
                                              int M, int N, int K,
                                              const float* __restrict__ stats,
                                              const float* __restrict__ lng,
                                              const float* __restrict__ lnb) {
    __shared__ float As[64][68];
    __shared__ float Ws[64][36];
    int t  = threadIdx.x;
    int bm = blockIdx.y * 64, bn = blockIdx.x * 32;
    int tm = t >> 4, tn = t & 15;
    float acc[4][2] = {{0.f,0.f},{0.f,0.f},{0.f,0.f},{0.f,0.f}};

    for (int kk = 0; kk < K; kk += 64) {
        __syncthreads();
        if (WT == 2) {
#pragma unroll
            for (int r = 0; r < 4; ++r) {
                int idx = t + r * 256;
                int k = idx >> 4, m4 = idx & 15;
                float4 a4 = *(const float4*)(A + (size_t)(kk + k) * M + bm + (m4 << 2));
                *(float4*)&As[k][m4 << 2] = a4;
            }
        } else {
#pragma unroll
            for (int r = 0; r < 4; ++r) {
                int flat = t * 4 + r * 1024;
                int m = flat >> 6, k = flat & 63;
                float4 a4 = *(const float4*)(A + (size_t)(bm + m) * K + kk + k);
                if (LNA) {
                    float mean = stats[(bm + m) * 2];
                    float rs   = stats[(bm + m) * 2 + 1];
                    float4 g4 = *(const float4*)(lng + kk + k);
                    float4 b4 = *(const float4*)(lnb + kk + k);
                    a4.x = fmaf((a4.x - mean) * rs, g4.x, b4.x);
                    a4.y = fmaf((a4.y - mean) * rs, g4.y, b4.y);
                    a4.z = fmaf((a4.z - mean) * rs, g4.z, b4.z);
                    a4.w = fmaf((a4.w - mean) * rs, g4.w, b4.w);
                }
                As[k + 0][m] = a4.x; As[k + 1][m] = a4.y;
                As[k + 2][m] = a4.z; As[k + 3][m] = a4.w;
            }
        }
        if (WT == 1) {
#pragma unroll
            for (int r = 0; r < 2; ++r) {
                int flat = t * 4 + r * 1024;
                int n = flat >> 6, k = flat & 63;
                float4 w4 = *(const float4*)(W + (size_t)(bn + n) * K + kk + k);
                Ws[k + 0][n] = w4.x; Ws[k + 1][n] = w4.y;
                Ws[k + 2][n] = w4.z; Ws[k + 3][n] = w4.w;
            }
        } else {
#pragma unroll
            for (int r = 0; r < 2; ++r) {
                int flat = t * 4 + r * 1024;
                int k = flat >> 5, n = flat & 31;
                float4 w4 = *(const float4*)(W + (size_t)(kk + k) * N + bn + n);
                *(float4*)&Ws[k][n] = w4;
            }
        }
        __syncthreads();
#pragma unroll
        for (int k = 0; k < 64; ++k) {
            float4 a = *(const float4*)&As[k][tm << 2];
            float2 w = *(const float2*)&Ws[k][tn << 1];
            acc[0][0] = fmaf(a.x, w.x, acc[0][0]); acc[0][1] = fmaf(a.x, w.y, acc[0][1]);
            acc[1][0] = fmaf(a.y, w.x, acc[1][0]); acc[1][1] = fmaf(a.y, w.y, acc[1][1]);
            acc[2][0] = fmaf(a.z, w.x, acc[2][0]); acc[2][1] = fmaf(a.z, w.y, acc[2][1]);
            acc[3][0] = fmaf(a.w, w.x, acc[3][0]); acc[3][1] = fmaf(a.w, w.y, acc[3][1]);
        }
    }
#pragma unroll
    for (int i = 0; i < 4; ++i) {
#pragma unroll
        for (int j = 0; j < 2; ++j) {
            int row = bm + (tm << 2) + i;
            int col = bn + (tn << 1) + j;
            float v = acc[i][j];
            if (bias) v += bias[col];
            C[(size_t)row * N + col] = v;
        }
    }
}

// ---------------------------------------------------------------- fused attention v3
// q in wave-distributed VGPRs; one x pass: per row coalesced wave read -> local dots
// -> fold-reduce -> softmax -> fused P accumulation in VGPRs. No per-row LDS.
__global__ __launch_bounds__(512, 2) void k_attn3(const float* __restrict__ x,
                                                  const float* __restrict__ qk,
                                                  const float* __restrict__ g,
                                                  const float* __restrict__ bvec,
                                                  float* __restrict__ part,
                                                  float* __restrict__ bsum) {
    __shared__ float qts[4096];   // q-tilde, k-major: [(k4)*8 + s] float4s
    __shared__ float u0s[4096];   // block P accumulation
    __shared__ float red[64];
    __shared__ float red2[64];
    __shared__ float c12[16];
    const int nc = blockIdx.x, b = blockIdx.y;
    const int t = threadIdx.x;
    const int w = t >> 6, lane = t & 63;

    // ---- q-prep (verified R6 block): qts = g .* qk (k-major), c1, c2
    {
        const float4* qk4 = (const float4*)(qk + (size_t)b * 4096);
        const float4* g4 = (const float4*)g;
        const float4* b4 = (const float4*)bvec;
        float c1p[2], c2p[2];
#pragma unroll
        for (int r = 0; r < 2; ++r) {
            int f = t + r * 512;                 // s = f>>7 (wave-uniform)
            float4 v = qk4[f];
            float4 gg = g4[f & 127];
            float4 bb = b4[f & 127];
            float4 qv = make_float4(v.x*gg.x, v.y*gg.y, v.z*gg.z, v.w*gg.w);
            *(float4*)&qts[((f & 127) * 8 + (f >> 7)) * 4] = qv;
            c1p[r] = qv.x + qv.y + qv.z + qv.w;
            c2p[r] = bb.x*v.x + bb.y*v.y + bb.z*v.z + bb.w*v.w;
        }
#pragma unroll
        for (int off = 32; off > 0; off >>= 1) {
#pragma unroll
            for (int r = 0; r < 2; ++r) {
                c1p[r] += __shfl_xor(c1p[r], off, 64);
                c2p[r] += __shfl_xor(c2p[r], off, 64);
            }
        }
        if (lane == 0) {
            red[w * 2 + 0] = c1p[0]; red[w * 2 + 1] = c1p[1];
            red2[w * 2 + 0] = c2p[0]; red2[w * 2 + 1] = c2p[1];
        }
    }
    __syncthreads();
    if (t < 8) {
        int s = t;
        float v1, v2;
        if (s < 4) { v1 = red[4*s]       + red[4*s + 2];       v2 = red2[4*s]       + red2[4*s + 2]; }
        else       { v1 = red[4*(s-4)+1] + red[4*(s-4)+3];     v2 = red2[4*(s-4)+1] + red2[4*(s-4)+3]; }
        c12[s] = v1; c12[8 + s] = v2;
    }
    __syncthreads();

    // ---- load q into wave-distributed registers: lane holds k4 = lane and 64+lane
    float4 qa[8], qb[8];
#pragma unroll
    for (int s = 0; s < 8; ++s) {
        qa[s] = *(const float4*)&qts[(lane * 8 + s) * 4];
        qb[s] = *(const float4*)&qts[((64 + lane) * 8 + s) * 4];
    }
    const int gq = (lane >> 3) & 7;       // this lane's fold-slot
    const float c1g = c12[gq], c2g = c12[8 + gq];
    const bool hb5 = (lane & 32) != 0, hb4 = (lane & 16) != 0, hb3 = (lane & 8) != 0;
    const int gbase = lane & 7;
    const float cnorm = 1.0f / (1.0f + 8.0f * 1e-8f);
    const float eadd  = 1e-8f * cnorm;

    float4 acc0[8], acc1[8];
#pragma unroll
    for (int s = 0; s < 8; ++s) {
        acc0[s] = make_float4(0.f, 0.f, 0.f, 0.f);
        acc1[s] = make_float4(0.f, 0.f, 0.f, 0.f);
    }
    float aS = 0.f, tS = 0.f;

    // rows for this wave: 32 consecutive
    const float4* xr = (const float4*)(x + ((size_t)b * N_ + (size_t)nc * 256 + w * 32) * D_);
    float4 xa0 = xr[lane],        xb0 = xr[64 + lane];
    float4 xa1 = xr[128 + lane],  xb1 = xr[192 + lane];

    for (int j = 0; j < 32; ++j) {
        int jn = (j < 30) ? j + 2 : 31;
        float4 na = xr[jn * 128 + lane], nb = xr[jn * 128 + 64 + lane];

        // local partial stats + dots (zero LDS)
        float sx = xa0.x + xa0.y + xa0.z + xa0.w + xb0.x + xb0.y + xb0.z + xb0.w;
        float sxx = xa0.x*xa0.x; sxx = fmaf(xa0.y,xa0.y,sxx); sxx = fmaf(xa0.z,xa0.z,sxx); sxx = fmaf(xa0.w,xa0.w,sxx);
        sxx = fmaf(xb0.x,xb0.x,sxx); sxx = fmaf(xb0.y,xb0.y,sxx); sxx = fmaf(xb0.z,xb0.z,sxx); sxx = fmaf(xb0.w,xb0.w,sxx);
        float dd[8];
#pragma unroll
        for (int s = 0; s < 8; ++s) {
            float td = xa0.x * qa[s].x;
            td = fmaf(xa0.y, qa[s].y, td); td = fmaf(xa0.z, qa[s].z, td); td = fmaf(xa0.w, qa[s].w, td);
            td = fmaf(xb0.x, qb[s].x, td); td = fmaf(xb0.y, qb[s].y, td);
            td = fmaf(xb0.z, qb[s].z, td); td = fmaf(xb0.w, qb[s].w, td);
            dd[s] = td;
        }
        // fold reduction (verified R2 pattern) -> lane holds dot for slot gq
        float r4[4];
#pragma unroll
        for (int s = 0; s < 4; ++s) {
            float snd = hb5 ? dd[s] : dd[s + 4];
            float kp  = hb5 ? dd[s + 4] : dd[s];
            r4[s] = kp + __shfl_xor(snd, 32, 64);
        }
        float r2[2];
#pragma unroll
        for (int s = 0; s < 2; ++s) {
            float snd = hb4 ? r4[s] : r4[s + 2];
            float kp  = hb4 ? r4[s + 2] : r4[s];
            r2[s] = kp + __shfl_xor(snd, 16, 64);
        }
        float v;
        {
            float snd = hb3 ? r2[0] : r2[1];
            float kp  = hb3 ? r2[1] : r2[0];
            v = kp + __shfl_xor(snd, 8, 64);
        }
        v += __shfl_xor(v, 4, 64);
        v += __shfl_xor(v, 2, 64);
        v += __shfl_xor(v, 1, 64);
        // stats butterfly
#pragma unroll
        for (int off = 32; off > 0; off >>= 1) {
            sx  += __shfl_xor(sx, off, 64);
            sxx += __shfl_xor(sxx, off, 64);
        }
        float mean = sx * (1.0f / D_);
        float rs   = rsqrtf(sxx * (1.0f / D_) - mean * mean + 1e-5f);
        float lg   = fmaf(rs, v, fmaf(-rs * mean, c1g, c2g));
        // softmax across the 8 slot-groups
        float mx = lg;
        mx = fmaxf(mx, __shfl_xor(mx, 8, 64));
        mx = fmaxf(mx, __shfl_xor(mx, 16, 64));
        mx = fmaxf(mx, __shfl_xor(mx, 32, 64));
        float p = __expf(lg - mx);
        float ps = p;
        ps += __shfl_xor(ps, 8, 64);
        ps += __shfl_xor(ps, 16, 64);
        ps += __shfl_xor(ps, 32, 64);
        float a  = fmaf(p, cnorm / ps, eadd);
        float wv = a * rs;
        aS += a;
        tS = fmaf(wv, mean, tS);
        // gather w for all slots, accumulate P in registers
        float w8[8];
#pragma unroll
        for (int s = 0; s < 8; ++s) w8[s] = __shfl(wv, (s << 3) | gbase, 64);
#pragma unroll
        for (int s = 0; s < 8; ++s) {
            acc0[s].x = fmaf(w8[s], xa0.x, acc0[s].x); acc0[s].y = fmaf(w8[s], xa0.y, acc0[s].y);
            acc0[s].z = fmaf(w8[s], xa0.z, acc0[s].z); acc0[s].w = fmaf(w8[s], xa0.w, acc0[s].w);
            acc1[s].x = fmaf(w8[s], xb0.x, acc1[s].x); acc1[s].y = fmaf(w8[s], xb0.y, acc1[s].y);
            acc1[s].z = fmaf(w8[s], xb0.z, acc1[s].z); acc1[s].w = fmaf(w8[s], xb0.w, acc1[s].w);
        }
        xa0 = xa1; xb0 = xb1; xa1 = na; xb1 = nb;
    }

    // ---- per-wave Av/Tv (group lanes hold duplicates; take one per group)
    if ((lane & 7) == 0) { red[w * 8 + gq] = aS; red2[w * 8 + gq] = tS; }
    // ---- cross-wave P reduction into LDS
    for (int w2 = 0; w2 < 8; ++w2) {
        if (w == w2) {
#pragma unroll
            for (int s = 0; s < 8; ++s) {
                float* p0 = &u0s[s * 512 + (lane << 2)];
                float* p1 = p0 + 256;
                if (w2 == 0) {
                    *(float4*)p0 = acc0[s];
                    *(float4*)p1 = acc1[s];
                } else {
                    float4 v0 = *(float4*)p0;
                    v0.x += acc0[s].x; v0.y += acc0[s].y; v0.z += acc0[s].z; v0.w += acc0[s].w;
                    *(float4*)p0 = v0;
                    float4 v1 = *(float4*)p1;
                    v1.x += acc1[s].x; v1.y += acc1[s].y; v1.z += acc1[s].z; v1.w += acc1[s].w;
                    *(float4*)p1 = v1;
                }
            }
        }
        __syncthreads();
    }
    if (t < 16) {
        int s = t & 7;
        const float* src = (t < 8) ? red : red2;
        float v = 0.f;
#pragma unroll
        for (int w2 = 0; w2 < 8; ++w2) v += src[w2 * 8 + s];
        bsum[(size_t)(b * 16 + nc) * 16 + t] = v;
    }
    float4* d4 = (float4*)(part + (size_t)(b * 16 + nc) * 4096);
    const float4* s4 = (const float4*)u0s;
    d4[t] = s4[t];
    d4[t + 512] = s4[t + 512];
}

// ---------------------------------------------------------------- u0 reduce + affine correction
__global__ __launch_bounds__(256) void k_ured(const float* __restrict__ part,
                                              const float* __restrict__ bsum,
                                              const float* __restrict__ g,
                                              const float* __restrict__ bvec,
                                              float* __restrict__ u0) {
    __shared__ float avs[16];
    const int b = blockIdx.x, t = threadIdx.x;
    if (t < 16) {
        float v = 0.f;
#pragma unroll
        for (int nc = 0; nc < 16; ++nc) v += bsum[(size_t)(b * 16 + nc) * 16 + t];
        avs[t] = v;
    }
    __syncthreads();
    const int d0 = t * 2;
    float gg0 = g[d0], gg1 = g[d0 + 1], bb0 = bvec[d0], bb1 = bvec[d0 + 1];
#pragma unroll
    for (int s = 0; s < 8; ++s) {
        float p0 = 0.f, p1 = 0.f;
#pragma unroll
        for (int nc = 0; nc < 16; ++nc) {
            float2 pv = *(const float2*)(part + (size_t)(b * 16 + nc) * 4096 + s * 512 + d0);
            p0 += pv.x; p1 += pv.y;
        }
        float Av = avs[s], Tv = avs[8 + s];
        float* o = u0 + (size_t)(b * 8 + s) * D_ + d0;
        o[0] = fmaf(gg0, p0 - Tv, Av * bb0);
        o[1] = fmaf(gg1, p1 - Tv, Av * bb1);
    }
}

// ---------------------------------------------------------------- gi+gh merged GEMM: gg[256][3072]
__global__ __launch_bounds__(256) void k_gg(const float* __restrict__ slots,
                                            const float* __restrict__ u0,
                                            const float* __restrict__ w_hh,
                                            const float* __restrict__ Wiv,
                                            const float* __restrict__ b_hh,
                                            const float* __restrict__ b_ih,
                                            float* __restrict__ gg) {
    __shared__ float As[64][68];
    __shared__ float Ws[64][36];
    const int t = threadIdx.x;
    const int bx = blockIdx.x;
    const int isGi = (bx >= 48);
    const float* A    = isGi ? u0 : slots;
    const float* W    = isGi ? Wiv : w_hh;
    const float* bias = isGi ? b_ih : b_hh;
    const int bnw = (isGi ? (bx - 48) : bx) * 32;
    const int bnc = bx * 32;
    const int bm  = blockIdx.y * 64;
    int tm = t >> 4, tn = t & 15;
    float acc[4][2] = {{0.f,0.f},{0.f,0.f},{0.f,0.f},{0.f,0.f}};

    for (int kk = 0; kk < 512; kk += 64) {
        __syncthreads();
#pragma unroll
        for (int r = 0; r < 4; ++r) {
            int flat = t * 4 + r * 1024;
            int m = flat >> 6, k = flat & 63;
            float4 a4 = *(const float4*)(A + (size_t)(bm + m) * 512 + kk + k);
            As[k + 0][m] = a4.x; As[k + 1][m] = a4.y;
            As[k + 2][m] = a4.z; As[k + 3][m] = a4.w;
        }
#pragma unroll
        for (int r = 0; r < 2; ++r) {
            int flat = t * 4 + r * 1024;
            int n = flat >> 6, k = flat & 63;
            float4 w4 = *(const float4*)(W + (size_t)(bnw + n) * 512 + kk + k);
            Ws[k + 0][n] = w4.x; Ws[k + 1][n] = w4.y;
            Ws[k + 2][n] = w4.z; Ws[k + 3][n] = w4.w;
        }
        __syncthreads();
#pragma unroll
        for (int k = 0; k < 64; ++k) {
            float4 a = *(const float4*)&As[k][tm << 2];
            float2 w = *(const float2*)&Ws[k][tn << 1];
            acc[0][0] = fmaf(a.x, w.x, acc[0][0]); acc[0][1] = fmaf(a.x, w.y, acc[0][1]);
            acc[1][0] = fmaf(a.y, w.x, acc[1][0]); acc[1][1] = fmaf(a.y, w.y, acc[1][1]);
            acc[2][0] = fmaf(a.z, w.x, acc[2][0]); acc[2][1] = fmaf(a.z, w.y, acc[2][1]);
            acc[3][0] = fmaf(a.w, w.x, acc[3][0]); acc[3][1] = fmaf(a.w, w.y, acc[3][1]);
        }
    }
#pragma unroll
    for (int i = 0; i < 4; ++i) {
#pragma unroll
        for (int j = 0; j < 2; ++j) {
            int row = bm + (tm << 2) + i;
            int cw  = bnw + (tn << 1) + j;
            gg[(size_t)row * 3072 + bnc + (tn << 1) + j] = acc[i][j] + bias[cw];
        }
    }
}

// ---------------------------------------------------------------- P2: GRU + MLP + LN + qk_next
__global__ __launch_bounds__(512) void k_p2(const float* __restrict__ gg,
                                            const float* __restrict__ slots,
                                            const float* __restrict__ w1, const float* __restrict__ b1,
                                            const float* __restrict__ w2, const float* __restrict__ b2,
                                            const float* __restrict__ wqkT,
                                            const float* __restrict__ ln_m_g, const float* __restrict__ ln_m_b,
                                            const float* __restrict__ ln_s_g, const float* __restrict__ ln_s_b,
                                            float* __restrict__ dst, float* __restrict__ qkout, int last) {
    __shared__ float s2s[2][512];
    __shared__ float t0s[2][512];
    __shared__ float hs[2][512];
    __shared__ float stat[4];
    const int t = threadIdx.x;
    const int wid = t >> 6, lane = t & 63;
    const int r0 = blockIdx.x * 2;

#pragma unroll
    for (int j = 0; j < 2; ++j) {
        int flat = t + j * 512;
        int r = flat >> 9, d = flat & 511;
        size_t row = r0 + r;
        const float* ghb = gg + row * 3072;
        const float* gib = ghb + 1536;
        float gir = gib[d], giz = gib[d + 512], gin = gib[d + 1024];
        float ghr = ghb[d], ghz = ghb[d + 512], ghn = ghb[d + 1024];
        float rr = sigmoid_f(gir + ghr);
        float zz = sigmoid_f(giz + ghz);
        float nn = tanh_f(fmaf(rr, ghn, gin));
        float sp = slots[row * 512 + d];
        s2s[r][d] = fmaf(1.0f - zz, nn, zz * sp);
    }
    __syncthreads();
    if (wid < 2) {
        const float4* sr = (const float4*)s2s[wid];
        float4 a = sr[lane], bq = sr[64 + lane];
        float s1 = a.x + a.y + a.z + a.w + bq.x + bq.y + bq.z + bq.w;
        float s2 = a.x*a.x; s2 = fmaf(a.y,a.y,s2); s2 = fmaf(a.z,a.z,s2); s2 = fmaf(a.w,a.w,s2);
        s2 = fmaf(bq.x,bq.x,s2); s2 = fmaf(bq.y,bq.y,s2); s2 = fmaf(bq.z,bq.z,s2); s2 = fmaf(bq.w,bq.w,s2);
#pragma unroll
        for (int off = 32; off > 0; off >>= 1) {
            s1 += __shfl_xor(s1, off, 64);
            s2 += __shfl_xor(s2, off, 64);
        }
        if (lane == 0) {
            float mean = s1 * (1.0f / D_);
            float var  = s2 * (1.0f / D_) - mean * mean;
            stat[wid * 2] = mean;
            stat[wid * 2 + 1] = rsqrtf(var + 1e-5f);
        }
    }
    __syncthreads();
#pragma unroll
    for (int j = 0; j < 2; ++j) {
        int flat = t + j * 512;
        int r = flat >> 9, d = flat & 511;
        t0s[r][d] = fmaf((s2s[r][d] - stat[r * 2]) * stat[r * 2 + 1], ln_m_g[d], ln_m_b[d]);
    }
    __syncthreads();
    {
        const int c = t;
        const float4* wr = (const float4*)(w1 + (size_t)c * 512);
        float a0 = 0.f, a1 = 0.f;
#pragma unroll 8
        for (int k4 = 0; k4 < 128; ++k4) {
            float4 w4 = wr[k4];
            float4 q0 = *(const float4*)&t0s[0][k4 << 2];
            float4 q1 = *(const float4*)&t0s[1][k4 << 2];
            a0 = fmaf(q0.x, w4.x, a0); a0 = fmaf(q0.y, w4.y, a0);
            a0 = fmaf(q0.z, w4.z, a0); a0 = fmaf(q0.w, w4.w, a0);
            a1 = fmaf(q1.x, w4.x, a1); a1 = fmaf(q1.y, w4.y, a1);
            a1 = fmaf(q1.z, w4.z, a1); a1 = fmaf(q1.w, w4.w, a1);
        }
        float bc = b1[c];
        hs[0][c] = fmaxf(a0 + bc, 0.f);
        hs[1][c] = fmaxf(a1 + bc, 0.f);
    }
    __syncthreads();
    {
        const int c = t;
        const float4* wr = (const float4*)(w2 + (size_t)c * 512);
        float a0 = 0.f, a1 = 0.f;
#pragma unroll 8
        for (int k4 = 0; k4 < 128; ++k4) {
            float4 w4 = wr[k4];
            float4 q0 = *(const float4*)&hs[0][k4 << 2];
            float4 q1 = *(const float4*)&hs[1][k4 << 2];
            a0 = fmaf(q0.x, w4.x, a0); a0 = fmaf(q0.y, w4.y, a0);
            a0 = fmaf(q0.z, w4.z, a0); a0 = fmaf(q0.w, w4.w, a0);
            a1 = fmaf(q1.x, w4.x, a1); a1 = fmaf(q1.y, w4.y, a1);
            a1 = fmaf(q1.z, w4.z, a1); a1 = fmaf(q1.w, w4.w, a1);
        }
        float bc = b2[c];
        float o0 = s2s[0][c] + a0 + bc;
        float o1 = s2s[1][c] + a1 + bc;
        dst[(size_t)r0 * 512 + c] = o0;
        dst[(size_t)(r0 + 1) * 512 + c] = o1;
        s2s[0][c] = o0;
        s2s[1][c] = o1;
    }
    if (last) return;
    __syncthreads();
    if (wid < 2) {
        const float4* sr = (const float4*)s2s[wid];
        float4 a = sr[lane], bq = sr[64 + lane];
        float s1 = a.x + a.y + a.z + a.w + bq.x + bq.y + bq.z + bq.w;
        float s2 = a.x*a.x; s2 = fmaf(a.y,a.y,s2); s2 = fmaf(a.z,a.z,s2); s2 = fmaf(a.w,a.w,s2);
        s2 = fmaf(bq.x,bq.x,s2); s2 = fmaf(bq.y,bq.y,s2); s2 = fmaf(bq.z,bq.z,s2); s2 = fmaf(bq.w,bq.w,s2);
#pragma unroll
        for (int off = 32; off > 0; off >>= 1) {
            s1 += __shfl_xor(s1, off, 64);
            s2 += __shfl_xor(s2, off, 64);
        }
        if (lane == 0) {
            float mean = s1 * (1.0f / D_);
            float var  = s2 * (1.0f / D_) - mean * mean;
            stat[wid * 2] = mean;
            stat[wid * 2 + 1] = rsqrtf(var + 1e-5f);
        }
    }
    __syncthreads();
#pragma unroll
    for (int j = 0; j < 2; ++j) {
        int flat = t + j * 512;
        int r = flat >> 9, d = flat & 511;
        t0s[r][d] = fmaf((s2s[r][d] - stat[r * 2]) * stat[r * 2 + 1], ln_s_g[d], ln_s_b[d]);
    }
    __syncthreads();
    {
        const int c = t;
        const float4* wr = (const float4*)(wqkT + (size_t)c * 512);
        float a0 = 0.f, a1 = 0.f;
#pragma unroll 8
        for (int k4 = 0; k4 < 128; ++k4) {
            float4 w4 = wr[k4];
            float4 q0 = *(const float4*)&t0s[0][k4 << 2];
            float4 q1 = *(const float4*)&t0s[1][k4 << 2];
            a0 = fmaf(q0.x, w4.x, a0); a0 = fmaf(q0.y, w4.y, a0);
            a0 = fmaf(q0.z, w4.z, a0); a0 = fmaf(q0.w, w4.w, a0);
            a1 = fmaf(q1.x, w4.x, a1); a1 = fmaf(q1.y, w4.y, a1);
            a1 = fmaf(q1.z, w4.z, a1); a1 = fmaf(q1.w, w4.w, a1);
        }
        qkout[(size_t)r0 * 512 + c] = a0;
        qkout[(size_t)(r0 + 1) * 512 + c] = a1;
    }
}

// ---------------------------------------------------------------- launch
extern "C" void kernel_launch(void* const* d_in, const int* in_sizes, int n_in,
                              void* d_out, int out_size, void* d_ws, size_t ws_size,
                              hipStream_t stream) {
    const float* inputs  = (const float*)d_in[0];
    const float* noise   = (const float*)d_in[1];
    const float* mu      = (const float*)d_in[2];
    const float* sg      = (const float*)d_in[3];
    const float* ln_in_g = (const float*)d_in[4];
    const float* ln_in_b = (const float*)d_in[5];
    const float* ln_s_g  = (const float*)d_in[6];
    const float* ln_s_b  = (const float*)d_in[7];
    const float* wq      = (const float*)d_in[8];
    const float* wk      = (const float*)d_in[9];
    const float* wv      = (const float*)d_in[10];
    const float* w_ih    = (const float*)d_in[11];
    const float* w_hh    = (const float*)d_in[12];
    const float* b_ih    = (const float*)d_in[13];
    const float* b_hh    = (const float*)d_in[14];
    const float* ln_m_g  = (const float*)d_in[15];
    const float* ln_m_b  = (const float*)d_in[16];
    const float* w1      = (const float*)d_in[17];
    const float* b1      = (const float*)d_in[18];
    const float* w2      = (const float*)d_in[19];
    const float* b2      = (const float*)d_in[20];

    float* ws = (float*)d_ws;
    const size_t SLOT = (size_t)B_ * S_ * D_;      // 131072
    size_t o = 0;
    float* slots = ws + o; o += SLOT;
    float* qk    = ws + o; o += SLOT;
    float* u0    = ws + o; o += SLOT;
    float* gg    = ws + o; o += (size_t)256 * 3072;       // 786432
    float* Mqk   = ws + o; o += (size_t)D_ * D_;          // 262144
    float* Wiv   = ws + o; o += (size_t)3 * D_ * D_;      // 786432
    float* statsS= ws + o; o += 512;
    float* part  = ws + o; o += (size_t)16 * B_ * 4096;   // 2097152
    float* bsum  = ws + o; o += (size_t)B_ * 16 * 16;     // 8192

    // ---- prologue (4 dispatches)
    k_gemm<2,0><<<dim3(16, 8), 256, 0, stream>>>(wk, wq, nullptr, Mqk,
                                                 512, 512, 512, nullptr, nullptr, nullptr);
    k_gemm<0,0><<<dim3(16, 24), 256, 0, stream>>>(w_ih, wv, nullptr, Wiv,
                                                  1536, 512, 512, nullptr, nullptr, nullptr);
    k_init<<<64, 256, 0, stream>>>(noise, mu, sg, slots, statsS);
    k_gemm<1,1><<<dim3(16, 4), 256, 0, stream>>>(slots, Mqk, nullptr, qk,
                                                 256, 512, 512, statsS, ln_s_g, ln_s_b);

    for (int it = 0; it < ITERS_; ++it) {
        k_attn3<<<dim3(16, B_), 512, 0, stream>>>(inputs, qk, ln_in_g, ln_in_b, part, bsum);
        k_ured<<<B_, 256, 0, stream>>>(part, bsum, ln_in_g, ln_in_b, u0);
        k_gg<<<dim3(96, 4), 256, 0, stream>>>(slots, u0, w_hh, Wiv, b_hh, b_ih, gg);
        int last = (it == ITERS_ - 1);
        float* dst = last ? (float*)d_out : slots;
        k_p2<<<128, 512, 0, stream>>>(gg, slots, w1, b1, w2, b2, Mqk,
                                      ln_m_g, ln_m_b, ln_s_g, ln_s_b, dst, qk, last);
    }
}

// Round 8
// 700.439 us; speedup vs baseline: 1.2683x; 1.0430x over previous
//
#include <hip/hip_runtime.h>

#define B_ 32
#define N_ 4096
#define D_ 512
#define S_ 8
#define ITERS_ 3

__device__ __forceinline__ float sigmoid_f(float x) {
    return 1.0f / (1.0f + __expf(-x));
}
__device__ __forceinline__ float tanh_f(float x) {
    float e = __expf(2.0f * x);
    return 1.0f - 2.0f / (e + 1.0f);
}

// ---------------------------------------------------------------- slot init (+ LN stats per row)
__global__ __launch_bounds__(256) void k_init(const float* __restrict__ noise,
                                              const float* __restrict__ mu,
                                              const float* __restrict__ sg,
                                              float* __restrict__ slots,
                                              float* __restrict__ stats) {
    int wid = threadIdx.x >> 6, lane = threadIdx.x & 63;
    int row = blockIdx.x * 4 + wid;                       // 0..255
    const float4* nz = (const float4*)(noise + (size_t)row * D_);
    const float4* m4 = (const float4*)(mu + (size_t)(row & 7) * D_);
    const float4* s4 = (const float4*)(sg + (size_t)(row & 7) * D_);
    float4 v0 = nz[lane], v1 = nz[64 + lane];
    float4 a0 = m4[lane], a1 = m4[64 + lane];
    float4 c0 = s4[lane], c1 = s4[64 + lane];
    v0.x = fmaf(c0.x, v0.x, a0.x); v0.y = fmaf(c0.y, v0.y, a0.y);
    v0.z = fmaf(c0.z, v0.z, a0.z); v0.w = fmaf(c0.w, v0.w, a0.w);
    v1.x = fmaf(c1.x, v1.x, a1.x); v1.y = fmaf(c1.y, v1.y, a1.y);
    v1.z = fmaf(c1.z, v1.z, a1.z); v1.w = fmaf(c1.w, v1.w, a1.w);
    float4* o4 = (float4*)(slots + (size_t)row * D_);
    o4[lane] = v0; o4[64 + lane] = v1;
    float s1 = v0.x + v0.y + v0.z + v0.w + v1.x + v1.y + v1.z + v1.w;
    float s2 = v0.x*v0.x; s2 = fmaf(v0.y,v0.y,s2); s2 = fmaf(v0.z,v0.z,s2); s2 = fmaf(v0.w,v0.w,s2);
    s2 = fmaf(v1.x,v1.x,s2); s2 = fmaf(v1.y,v1.y,s2); s2 = fmaf(v1.z,v1.z,s2); s2 = fmaf(v1.w,v1.w,s2);
#pragma unroll
    for (int off = 32; off > 0; off >>= 1) {
        s1 += __shfl_xor(s1, off, 64);
        s2 += __shfl_xor(s2, off, 64);
    }
    if (lane == 0) {
        float mean = s1 * (1.0f / D_);
        float var  = s2 * (1.0f / D_) - mean * mean;
        stats[row * 2]     = mean;
        stats[row * 2 + 1] = rsqrtf(var + 1e-5f);
    }
}

// ---------------------------------------------------------------- small GEMM (prologue only)
template<int WT, int LNA>
__global__ __launch_bounds__(256) void k_gemm(const float* __restrict__ A,
                                              const float* __restrict__ W,
                                              const float* __restrict__ bias,
                                              float* __restrict__ C,
                                              int M, int N, int K,
                                              const float* __restrict__ stats,
                                              const float* __restrict__ lng,
                                              const float* __restrict__ lnb) {
    __shared__ float As[64][68];
    __shared__ float Ws[64][36];
    int t  = threadIdx.x;
    int bm = blockIdx.y * 64, bn = blockIdx.x * 32;
    int tm = t >> 4, tn = t & 15;
    float acc[4][2] = {{0.f,0.f},{0.f,0.f},{0.f,0.f},{0.f,0.f}};

    for (int kk = 0; kk < K; kk += 64) {
        __syncthreads();
        if (WT == 2) {
#pragma unroll
            for (int r = 0; r < 4; ++r) {
                int idx = t + r * 256;
                int k = idx >> 4, m4 = idx & 15;
                float4 a4 = *(const float4*)(A + (size_t)(kk + k) * M + bm + (m4 << 2));
                *(float4*)&As[k][m4 << 2] = a4;
            }
        } else {
#pragma unroll
            for (int r = 0; r < 4; ++r) {
                int flat = t * 4 + r * 1024;
                int m = flat >> 6, k = flat & 63;
                float4 a4 = *(const float4*)(A + (size_t)(bm + m) * K + kk + k);
                if (LNA) {
                    float mean = stats[(bm + m) * 2];
                    float rs   = stats[(bm + m) * 2 + 1];
                    float4 g4 = *(const float4*)(lng + kk + k);
                    float4 b4 = *(const float4*)(lnb + kk + k);
                    a4.x = fmaf((a4.x - mean) * rs, g4.x, b4.x);
                    a4.y = fmaf((a4.y - mean) * rs, g4.y, b4.y);
                    a4.z = fmaf((a4.z - mean) * rs, g4.z, b4.z);
                    a4.w = fmaf((a4.w - mean) * rs, g4.w, b4.w);
                }
                As[k + 0][m] = a4.x; As[k + 1][m] = a4.y;
                As[k + 2][m] = a4.z; As[k + 3][m] = a4.w;
            }
        }
        if (WT == 1) {
#pragma unroll
            for (int r = 0; r < 2; ++r) {
                int flat = t * 4 + r * 1024;
                int n = flat >> 6, k = flat & 63;
                float4 w4 = *(const float4*)(W + (size_t)(bn + n) * K + kk + k);
                Ws[k + 0][n] = w4.x; Ws[k + 1][n] = w4.y;
                Ws[k + 2][n] = w4.z; Ws[k + 3][n] = w4.w;
            }
        } else {
#pragma unroll
            for (int r = 0; r < 2; ++r) {
                int flat = t * 4 + r * 1024;
                int k = flat >> 5, n = flat & 31;
                float4 w4 = *(const float4*)(W + (size_t)(kk + k) * N + bn + n);
                *(float4*)&Ws[k][n] = w4;
            }
        }
        __syncthreads();
#pragma unroll
        for (int k = 0; k < 64; ++k) {
            float4 a = *(const float4*)&As[k][tm << 2];
            float2 w = *(const float2*)&Ws[k][tn << 1];
            acc[0][0] = fmaf(a.x, w.x, acc[0][0]); acc[0][1] = fmaf(a.x, w.y, acc[0][1]);
            acc[1][0] = fmaf(a.y, w.x, acc[1][0]); acc[1][1] = fmaf(a.y, w.y, acc[1][1]);
            acc[2][0] = fmaf(a.z, w.x, acc[2][0]); acc[2][1] = fmaf(a.z, w.y, acc[2][1]);
            acc[3][0] = fmaf(a.w, w.x, acc[3][0]); acc[3][1] = fmaf(a.w, w.y, acc[3][1]);
        }
    }
#pragma unroll
    for (int i = 0; i < 4; ++i) {
#pragma unroll
        for (int j = 0; j < 2; ++j) {
            int row = bm + (tm << 2) + i;
            int col = bn + (tn << 1) + j;
            float v = acc[i][j];
            if (bias) v += bias[col];
            C[(size_t)row * N + col] = v;
        }
    }
}

// ---------------------------------------------------------------- fused attention v4 + gh GEMM overlay
// blocks [0,512): attention, 2 rows in flight per wave (chain ILP x2)
// blocks [512,608): gh = slots @ w_hh^T + b_hh  (independent -> hides under attn)
__global__ __launch_bounds__(512, 2) void k_attn_gh(const float* __restrict__ x,
                                                    const float* __restrict__ qk,
                                                    const float* __restrict__ g,
                                                    const float* __restrict__ bvec,
                                                    float* __restrict__ part,
                                                    float* __restrict__ bsum,
                                                    const float* __restrict__ slots,
                                                    const float* __restrict__ w_hh,
                                                    const float* __restrict__ b_hh,
                                                    float* __restrict__ gg) {
    __shared__ float smem[8704];    // 34.8 KB, unioned
    const int blk = blockIdx.x;
    const int t = threadIdx.x;

    if (blk >= 512) {
        // ---------------- gh GEMM: 64x64 tile, 512 threads, micro 4x2
        const int t2 = blk - 512;
        const int ci = t2 % 24, ri = t2 / 24;      // 24 col-tiles x 4 row-tiles
        const int bm = ri * 64, bn = ci * 64;
        float (*As)[68] = (float (*)[68])smem;
        float (*Ws)[68] = (float (*)[68])(smem + 64 * 68);
        const int tm = t >> 5, tn = t & 31;
        float acc[4][2] = {{0.f,0.f},{0.f,0.f},{0.f,0.f},{0.f,0.f}};
        for (int kk = 0; kk < 512; kk += 64) {
            __syncthreads();
#pragma unroll
            for (int r = 0; r < 2; ++r) {
                int flat = t * 4 + r * 2048;
                int m = flat >> 6, k = flat & 63;
                float4 a4 = *(const float4*)(slots + (size_t)(bm + m) * 512 + kk + k);
                As[k + 0][m] = a4.x; As[k + 1][m] = a4.y;
                As[k + 2][m] = a4.z; As[k + 3][m] = a4.w;
            }
#pragma unroll
            for (int r = 0; r < 2; ++r) {
                int flat = t * 4 + r * 2048;
                int n = flat >> 6, k = flat & 63;
                float4 w4 = *(const float4*)(w_hh + (size_t)(bn + n) * 512 + kk + k);
                Ws[k + 0][n] = w4.x; Ws[k + 1][n] = w4.y;
                Ws[k + 2][n] = w4.z; Ws[k + 3][n] = w4.w;
            }
            __syncthreads();
#pragma unroll
            for (int k = 0; k < 64; ++k) {
                const float4 a = *(const float4*)&As[k][tm << 2];
                const float2 w = *(const float2*)&Ws[k][tn << 1];
                acc[0][0] = fmaf(a.x, w.x, acc[0][0]); acc[0][1] = fmaf(a.x, w.y, acc[0][1]);
                acc[1][0] = fmaf(a.y, w.x, acc[1][0]); acc[1][1] = fmaf(a.y, w.y, acc[1][1]);
                acc[2][0] = fmaf(a.z, w.x, acc[2][0]); acc[2][1] = fmaf(a.z, w.y, acc[2][1]);
                acc[3][0] = fmaf(a.w, w.x, acc[3][0]); acc[3][1] = fmaf(a.w, w.y, acc[3][1]);
            }
        }
#pragma unroll
        for (int i = 0; i < 4; ++i) {
#pragma unroll
            for (int j = 0; j < 2; ++j) {
                int row = bm + (tm << 2) + i;
                int col = bn + (tn << 1) + j;
                gg[(size_t)row * 3072 + col] = acc[i][j] + b_hh[col];
            }
        }
        return;
    }

    // ---------------- attention
    float* qts  = smem;            // 4096
    float* u0s  = smem + 4096;     // 4096
    float* red  = smem + 8192;     // 64
    float* red2 = smem + 8256;     // 64
    float* c12  = smem + 8320;     // 16
    const int nc = blk & 15, b = blk >> 4;
    const int w = t >> 6, lane = t & 63;

    // ---- q-prep: qts = g .* qk (k-major), c1[s], c2[s]
    {
        const float4* qk4 = (const float4*)(qk + (size_t)b * 4096);
        const float4* g4 = (const float4*)g;
        const float4* b4 = (const float4*)bvec;
        float c1p[2], c2p[2];
#pragma unroll
        for (int r = 0; r < 2; ++r) {
            int f = t + r * 512;                 // s = f>>7 (wave-uniform)
            float4 v = qk4[f];
            float4 gg4 = g4[f & 127];
            float4 bb = b4[f & 127];
            float4 qv = make_float4(v.x*gg4.x, v.y*gg4.y, v.z*gg4.z, v.w*gg4.w);
            *(float4*)&qts[((f & 127) * 8 + (f >> 7)) * 4] = qv;
            c1p[r] = qv.x + qv.y + qv.z + qv.w;
            c2p[r] = bb.x*v.x + bb.y*v.y + bb.z*v.z + bb.w*v.w;
        }
#pragma unroll
        for (int off = 32; off > 0; off >>= 1) {
#pragma unroll
            for (int r = 0; r < 2; ++r) {
                c1p[r] += __shfl_xor(c1p[r], off, 64);
                c2p[r] += __shfl_xor(c2p[r], off, 64);
            }
        }
        if (lane == 0) {
            red[w * 2 + 0] = c1p[0]; red[w * 2 + 1] = c1p[1];
            red2[w * 2 + 0] = c2p[0]; red2[w * 2 + 1] = c2p[1];
        }
    }
    __syncthreads();
    if (t < 8) {
        int s = t;
        float v1, v2;
        if (s < 4) { v1 = red[4*s]       + red[4*s + 2];       v2 = red2[4*s]       + red2[4*s + 2]; }
        else       { v1 = red[4*(s-4)+1] + red[4*(s-4)+3];     v2 = red2[4*(s-4)+1] + red2[4*(s-4)+3]; }
        c12[s] = v1; c12[8 + s] = v2;
    }
    __syncthreads();

    // ---- q into wave-distributed registers: lane holds k4 = lane and 64+lane
    float4 qa[8], qb[8];
#pragma unroll
    for (int s = 0; s < 8; ++s) {
        qa[s] = *(const float4*)&qts[(lane * 8 + s) * 4];
        qb[s] = *(const float4*)&qts[((64 + lane) * 8 + s) * 4];
    }
    const int gq = (lane >> 3) & 7;
    const float c1g = c12[gq], c2g = c12[8 + gq];
    const bool hb5 = (lane & 32) != 0, hb4 = (lane & 16) != 0, hb3 = (lane & 8) != 0;
    const int gbase = lane & 7;
    const float cnorm = 1.0f / (1.0f + 8.0f * 1e-8f);
    const float eadd  = 1e-8f * cnorm;

    float4 acc0[8], acc1[8];
#pragma unroll
    for (int s = 0; s < 8; ++s) {
        acc0[s] = make_float4(0.f, 0.f, 0.f, 0.f);
        acc1[s] = make_float4(0.f, 0.f, 0.f, 0.f);
    }
    float aS = 0.f, tS = 0.f;

    // rows for this wave: 32 consecutive; process 2 per iteration
    const float4* xr = (const float4*)(x + ((size_t)b * N_ + (size_t)nc * 256 + w * 32) * D_);
    float4 cur0 = xr[lane],       cur1 = xr[64 + lane];        // row 0
    float4 cur2 = xr[128 + lane], cur3 = xr[192 + lane];       // row 1

#define DOTS(X0, X1, R)                                                          \
    {                                                                            \
        sx[R] = (X0).x + (X0).y + (X0).z + (X0).w                                \
              + (X1).x + (X1).y + (X1).z + (X1).w;                               \
        float t_ = (X0).x*(X0).x;                                                \
        t_ = fmaf((X0).y,(X0).y,t_); t_ = fmaf((X0).z,(X0).z,t_);                \
        t_ = fmaf((X0).w,(X0).w,t_); t_ = fmaf((X1).x,(X1).x,t_);                \
        t_ = fmaf((X1).y,(X1).y,t_); t_ = fmaf((X1).z,(X1).z,t_);                \
        t_ = fmaf((X1).w,(X1).w,t_); sxx[R] = t_;                                \
        _Pragma("unroll")                                                        \
        for (int s = 0; s < 8; ++s) {                                            \
            float td = (X0).x * qa[s].x;                                         \
            td = fmaf((X0).y, qa[s].y, td); td = fmaf((X0).z, qa[s].z, td);      \
            td = fmaf((X0).w, qa[s].w, td);                                      \
            td = fmaf((X1).x, qb[s].x, td); td = fmaf((X1).y, qb[s].y, td);      \
            td = fmaf((X1).z, qb[s].z, td); td = fmaf((X1).w, qb[s].w, td);      \
            dd[R][s] = td;                                                       \
        }                                                                        \
    }

    for (int jp = 0; jp < 16; ++jp) {
        int jn = (jp < 15) ? (2 * jp + 2) : 30;
        float4 n0 = xr[jn * 128 + lane],       n1 = xr[jn * 128 + 64 + lane];
        float4 n2 = xr[(jn + 1) * 128 + lane], n3 = xr[(jn + 1) * 128 + 64 + lane];

        float sx[2], sxx[2], dd[2][8];
        DOTS(cur0, cur1, 0);
        DOTS(cur2, cur3, 1);

        // fold reduction, both rows interleaved
        float r4[2][4];
#pragma unroll
        for (int r = 0; r < 2; ++r) {
#pragma unroll
            for (int s = 0; s < 4; ++s) {
                float snd = hb5 ? dd[r][s] : dd[r][s + 4];
                float kp  = hb5 ? dd[r][s + 4] : dd[r][s];
                r4[r][s] = kp + __shfl_xor(snd, 32, 64);
            }
        }
        float r2v[2][2];
#pragma unroll
        for (int r = 0; r < 2; ++r) {
#pragma unroll
            for (int s = 0; s < 2; ++s) {
                float snd = hb4 ? r4[r][s] : r4[r][s + 2];
                float kp  = hb4 ? r4[r][s + 2] : r4[r][s];
                r2v[r][s] = kp + __shfl_xor(snd, 16, 64);
            }
        }
        float vv[2];
#pragma unroll
        for (int r = 0; r < 2; ++r) {
            float snd = hb3 ? r2v[r][0] : r2v[r][1];
            float kp  = hb3 ? r2v[r][1] : r2v[r][0];
            vv[r] = kp + __shfl_xor(snd, 8, 64);
        }
#pragma unroll
        for (int off = 4; off > 0; off >>= 1) {
#pragma unroll
            for (int r = 0; r < 2; ++r) vv[r] += __shfl_xor(vv[r], off, 64);
        }
        // stats butterfly, interleaved
#pragma unroll
        for (int off = 32; off > 0; off >>= 1) {
#pragma unroll
            for (int r = 0; r < 2; ++r) {
                sx[r]  += __shfl_xor(sx[r], off, 64);
                sxx[r] += __shfl_xor(sxx[r], off, 64);
            }
        }
        float mean[2], rsv[2], lg[2];
#pragma unroll
        for (int r = 0; r < 2; ++r) {
            mean[r] = sx[r] * (1.0f / D_);
            rsv[r]  = rsqrtf(sxx[r] * (1.0f / D_) - mean[r] * mean[r] + 1e-5f);
            lg[r]   = fmaf(rsv[r], vv[r], fmaf(-rsv[r] * mean[r], c1g, c2g));
        }
        float mx[2] = { lg[0], lg[1] };
#pragma unroll
        for (int r = 0; r < 2; ++r) {
            mx[r] = fmaxf(mx[r], __shfl_xor(mx[r], 8, 64));
            mx[r] = fmaxf(mx[r], __shfl_xor(mx[r], 16, 64));
            mx[r] = fmaxf(mx[r], __shfl_xor(mx[r], 32, 64));
        }
        float pv[2], ps[2];
#pragma unroll
        for (int r = 0; r < 2; ++r) { pv[r] = __expf(lg[r] - mx[r]); ps[r] = pv[r]; }
#pragma unroll
        for (int r = 0; r < 2; ++r) {
            ps[r] += __shfl_xor(ps[r], 8, 64);
            ps[r] += __shfl_xor(ps[r], 16, 64);
            ps[r] += __shfl_xor(ps[r], 32, 64);
        }
        float av[2], wv[2];
#pragma unroll
        for (int r = 0; r < 2; ++r) {
            av[r] = fmaf(pv[r], cnorm / ps[r], eadd);
            wv[r] = av[r] * rsv[r];
        }
        aS += av[0]; aS += av[1];
        tS = fmaf(wv[0], mean[0], tS);
        tS = fmaf(wv[1], mean[1], tS);
        // gather + accumulate, fused per slot (both rows)
#pragma unroll
        for (int s = 0; s < 8; ++s) {
            float w0 = __shfl(wv[0], (s << 3) | gbase, 64);
            float w1 = __shfl(wv[1], (s << 3) | gbase, 64);
            acc0[s].x = fmaf(w0, cur0.x, acc0[s].x); acc0[s].y = fmaf(w0, cur0.y, acc0[s].y);
            acc0[s].z = fmaf(w0, cur0.z, acc0[s].z); acc0[s].w = fmaf(w0, cur0.w, acc0[s].w);
            acc1[s].x = fmaf(w0, cur1.x, acc1[s].x); acc1[s].y = fmaf(w0, cur1.y, acc1[s].y);
            acc1[s].z = fmaf(w0, cur1.z, acc1[s].z); acc1[s].w = fmaf(w0, cur1.w, acc1[s].w);
            acc0[s].x = fmaf(w1, cur2.x, acc0[s].x); acc0[s].y = fmaf(w1, cur2.y, acc0[s].y);
            acc0[s].z = fmaf(w1, cur2.z, acc0[s].z); acc0[s].w = fmaf(w1, cur2.w, acc0[s].w);
            acc1[s].x = fmaf(w1, cur3.x, acc1[s].x); acc1[s].y = fmaf(w1, cur3.y, acc1[s].y);
            acc1[s].z = fmaf(w1, cur3.z, acc1[s].z); acc1[s].w = fmaf(w1, cur3.w, acc1[s].w);
        }
        cur0 = n0; cur1 = n1; cur2 = n2; cur3 = n3;
    }
#undef DOTS

    // ---- per-wave Av/Tv
    if ((lane & 7) == 0) { red[w * 8 + gq] = aS; red2[w * 8 + gq] = tS; }
    // ---- cross-wave P reduction into LDS
    for (int w2 = 0; w2 < 8; ++w2) {
        if (w == w2) {
#pragma unroll
            for (int s = 0; s < 8; ++s) {
                float* p0 = &u0s[s * 512 + (lane << 2)];
                float* p1 = p0 + 256;
                if (w2 == 0) {
                    *(float4*)p0 = acc0[s];
                    *(float4*)p1 = acc1[s];
                } else {
                    float4 v0 = *(float4*)p0;
                    v0.x += acc0[s].x; v0.y += acc0[s].y; v0.z += acc0[s].z; v0.w += acc0[s].w;
                    *(float4*)p0 = v0;
                    float4 v1 = *(float4*)p1;
                    v1.x += acc1[s].x; v1.y += acc1[s].y; v1.z += acc1[s].z; v1.w += acc1[s].w;
                    *(float4*)p1 = v1;
                }
            }
        }
        __syncthreads();
    }
    if (t < 16) {
        int s = t & 7;
        const float* src = (t < 8) ? red : red2;
        float v = 0.f;
#pragma unroll
        for (int w2 = 0; w2 < 8; ++w2) v += src[w2 * 8 + s];
        bsum[(size_t)(b * 16 + nc) * 16 + t] = v;
    }
    float4* d4 = (float4*)(part + (size_t)(b * 16 + nc) * 4096);
    const float4* s4 = (const float4*)u0s;
    d4[t] = s4[t];
    d4[t + 512] = s4[t + 512];
}

// ---------------------------------------------------------------- u0 reduce + affine correction
// one block per (b, s) row, one thread per d
__global__ __launch_bounds__(512) void k_ured(const float* __restrict__ part,
                                              const float* __restrict__ bsum,
                                              const float* __restrict__ g,
                                              const float* __restrict__ bvec,
                                              float* __restrict__ u0) {
    const int bs = blockIdx.x;          // 0..255
    const int b = bs >> 3, s = bs & 7;
    const int d = threadIdx.x;
    float Av = 0.f, Tv = 0.f;
#pragma unroll
    for (int nc = 0; nc < 16; ++nc) {
        Av += bsum[(size_t)(b * 16 + nc) * 16 + s];
        Tv += bsum[(size_t)(b * 16 + nc) * 16 + 8 + s];
    }
    float p = 0.f;
#pragma unroll
    for (int nc = 0; nc < 16; ++nc)
        p += part[(size_t)(b * 16 + nc) * 4096 + s * 512 + d];
    u0[(size_t)bs * 512 + d] = fmaf(g[d], p - Tv, Av * bvec[d]);
}

// ---------------------------------------------------------------- gi GEMM into gg cols 1536..3071
__global__ __launch_bounds__(256) void k_gi(const float* __restrict__ u0,
                                            const float* __restrict__ Wiv,
                                            const float* __restrict__ b_ih,
                                            float* __restrict__ gg) {
    __shared__ float As[64][68];
    __shared__ float Ws[64][36];
    const int t = threadIdx.x;
    const int bn = blockIdx.x * 32;                 // within 1536
    const int bm = blockIdx.y * 64;
    int tm = t >> 4, tn = t & 15;
    float acc[4][2] = {{0.f,0.f},{0.f,0.f},{0.f,0.f},{0.f,0.f}};

    for (int kk = 0; kk < 512; kk += 64) {
        __syncthreads();
#pragma unroll
        for (int r = 0; r < 4; ++r) {
            int flat = t * 4 + r * 1024;
            int m = flat >> 6, k = flat & 63;
            float4 a4 = *(const float4*)(u0 + (size_t)(bm + m) * 512 + kk + k);
            As[k + 0][m] = a4.x; As[k + 1][m] = a4.y;
            As[k + 2][m] = a4.z; As[k + 3][m] = a4.w;
        }
#pragma unroll
        for (int r = 0; r < 2; ++r) {
            int flat = t * 4 + r * 1024;
            int n = flat >> 6, k = flat & 63;
            float4 w4 = *(const float4*)(Wiv + (size_t)(bn + n) * 512 + kk + k);
            Ws[k + 0][n] = w4.x; Ws[k + 1][n] = w4.y;
            Ws[k + 2][n] = w4.z; Ws[k + 3][n] = w4.w;
        }
        __syncthreads();
#pragma unroll
        for (int k = 0; k < 64; ++k) {
            float4 a = *(const float4*)&As[k][tm << 2];
            float2 w = *(const float2*)&Ws[k][tn << 1];
            acc[0][0] = fmaf(a.x, w.x, acc[0][0]); acc[0][1] = fmaf(a.x, w.y, acc[0][1]);
            acc[1][0] = fmaf(a.y, w.x, acc[1][0]); acc[1][1] = fmaf(a.y, w.y, acc[1][1]);
            acc[2][0] = fmaf(a.z, w.x, acc[2][0]); acc[2][1] = fmaf(a.z, w.y, acc[2][1]);
            acc[3][0] = fmaf(a.w, w.x, acc[3][0]); acc[3][1] = fmaf(a.w, w.y, acc[3][1]);
        }
    }
#pragma unroll
    for (int i = 0; i < 4; ++i) {
#pragma unroll
        for (int j = 0; j < 2; ++j) {
            int row = bm + (tm << 2) + i;
            int cw  = bn + (tn << 1) + j;
            gg[(size_t)row * 3072 + 1536 + cw] = acc[i][j] + b_ih[cw];
        }
    }
}

// ---------------------------------------------------------------- P2: GRU + MLP + LN + qk_next
__global__ __launch_bounds__(512) void k_p2(const float* __restrict__ gg,
                                            const float* __restrict__ slots,
                                            const float* __restrict__ w1, const float* __restrict__ b1,
                                            const float* __restrict__ w2, const float* __restrict__ b2,
                                            const float* __restrict__ wqkT,
                                            const float* __restrict__ ln_m_g, const float* __restrict__ ln_m_b,
                                            const float* __restrict__ ln_s_g, const float* __restrict__ ln_s_b,
                                            float* __restrict__ dst, float* __restrict__ qkout, int last) {
    __shared__ float s2s[2][512];
    __shared__ float t0s[2][512];
    __shared__ float hs[2][512];
    __shared__ float stat[4];
    const int t = threadIdx.x;
    const int wid = t >> 6, lane = t & 63;
    const int r0 = blockIdx.x * 2;

#pragma unroll
    for (int j = 0; j < 2; ++j) {
        int flat = t + j * 512;
        int r = flat >> 9, d = flat & 511;
        size_t row = r0 + r;
        const float* ghb = gg + row * 3072;
        const float* gib = ghb + 1536;
        float gir = gib[d], giz = gib[d + 512], gin = gib[d + 1024];
        float ghr = ghb[d], ghz = ghb[d + 512], ghn = ghb[d + 1024];
        float rr = sigmoid_f(gir + ghr);
        float zz = sigmoid_f(giz + ghz);
        float nn = tanh_f(fmaf(rr, ghn, gin));
        float sp = slots[row * 512 + d];
        s2s[r][d] = fmaf(1.0f - zz, nn, zz * sp);
    }
    __syncthreads();
    if (wid < 2) {
        const float4* sr = (const float4*)s2s[wid];
        float4 a = sr[lane], bq = sr[64 + lane];
        float s1 = a.x + a.y + a.z + a.w + bq.x + bq.y + bq.z + bq.w;
        float s2 = a.x*a.x; s2 = fmaf(a.y,a.y,s2); s2 = fmaf(a.z,a.z,s2); s2 = fmaf(a.w,a.w,s2);
        s2 = fmaf(bq.x,bq.x,s2); s2 = fmaf(bq.y,bq.y,s2); s2 = fmaf(bq.z,bq.z,s2); s2 = fmaf(bq.w,bq.w,s2);
#pragma unroll
        for (int off = 32; off > 0; off >>= 1) {
            s1 += __shfl_xor(s1, off, 64);
            s2 += __shfl_xor(s2, off, 64);
        }
        if (lane == 0) {
            float mean = s1 * (1.0f / D_);
            float var  = s2 * (1.0f / D_) - mean * mean;
            stat[wid * 2] = mean;
            stat[wid * 2 + 1] = rsqrtf(var + 1e-5f);
        }
    }
    __syncthreads();
#pragma unroll
    for (int j = 0; j < 2; ++j) {
        int flat = t + j * 512;
        int r = flat >> 9, d = flat & 511;
        t0s[r][d] = fmaf((s2s[r][d] - stat[r * 2]) * stat[r * 2 + 1], ln_m_g[d], ln_m_b[d]);
    }
    __syncthreads();
    {
        const int c = t;
        const float4* wr = (const float4*)(w1 + (size_t)c * 512);
        float a0 = 0.f, a1 = 0.f;
#pragma unroll 8
        for (int k4 = 0; k4 < 128; ++k4) {
            float4 w4 = wr[k4];
            float4 q0 = *(const float4*)&t0s[0][k4 << 2];
            float4 q1 = *(const float4*)&t0s[1][k4 << 2];
            a0 = fmaf(q0.x, w4.x, a0); a0 = fmaf(q0.y, w4.y, a0);
            a0 = fmaf(q0.z, w4.z, a0); a0 = fmaf(q0.w, w4.w, a0);
            a1 = fmaf(q1.x, w4.x, a1); a1 = fmaf(q1.y, w4.y, a1);
            a1 = fmaf(q1.z, w4.z, a1); a1 = fmaf(q1.w, w4.w, a1);
        }
        float bc = b1[c];
        hs[0][c] = fmaxf(a0 + bc, 0.f);
        hs[1][c] = fmaxf(a1 + bc, 0.f);
    }
    __syncthreads();
    {
        const int c = t;
        const float4* wr = (const float4*)(w2 + (size_t)c * 512);
        float a0 = 0.f, a1 = 0.f;
#pragma unroll 8
        for (int k4 = 0; k4 < 128; ++k4) {
            float4 w4 = wr[k4];
            float4 q0 = *(const float4*)&hs[0][k4 << 2];
            float4 q1 = *(const float4*)&hs[1][k4 << 2];
            a0 = fmaf(q0.x, w4.x, a0); a0 = fmaf(q0.y, w4.y, a0);
            a0 = fmaf(q0.z, w4.z, a0); a0 = fmaf(q0.w, w4.w, a0);
            a1 = fmaf(q1.x, w4.x, a1); a1 = fmaf(q1.y, w4.y, a1);
            a1 = fmaf(q1.z, w4.z, a1); a1 = fmaf(q1.w, w4.w, a1);
        }
        float bc = b2[c];
        float o0 = s2s[0][c] + a0 + bc;
        float o1 = s2s[1][c] + a1 + bc;
        dst[(size_t)r0 * 512 + c] = o0;
        dst[(size_t)(r0 + 1) * 512 + c] = o1;
        s2s[0][c] = o0;
        s2s[1][c] = o1;
    }
    if (last) return;
    __syncthreads();
    if (wid < 2) {
        const float4* sr = (const float4*)s2s[wid];
        float4 a = sr[lane], bq = sr[64 + lane];
        float s1 = a.x + a.y + a.z + a.w + bq.x + bq.y + bq.z + bq.w;
        float s2 = a.x*a.x; s2 = fmaf(a.y,a.y,s2); s2 = fmaf(a.z,a.z,s2); s2 = fmaf(a.w,a.w,s2);
        s2 = fmaf(bq.x,bq.x,s2); s2 = fmaf(bq.y,bq.y,s2); s2 = fmaf(bq.z,bq.z,s2); s2 = fmaf(bq.w,bq.w,s2);
#pragma unroll
        for (int off = 32; off > 0; off >>= 1) {
            s1 += __shfl_xor(s1, off, 64);
            s2 += __shfl_xor(s2, off, 64);
        }
        if (lane == 0) {
            float mean = s1 * (1.0f / D_);
            float var  = s2 * (1.0f / D_) - mean * mean;
            stat[wid * 2] = mean;
            stat[wid * 2 + 1] = rsqrtf(var + 1e-5f);
        }
    }
    __syncthreads();
#pragma unroll
    for (int j = 0; j < 2; ++j) {
        int flat = t + j * 512;
        int r = flat >> 9, d = flat & 511;
        t0s[r][d] = fmaf((s2s[r][d] - stat[r * 2]) * stat[r * 2 + 1], ln_s_g[d], ln_s_b[d]);
    }
    __syncthreads();
    {
        const int c = t;
        const float4* wr = (const float4*)(wqkT + (size_t)c * 512);
        float a0 = 0.f, a1 = 0.f;
#pragma unroll 8
        for (int k4 = 0; k4 < 128; ++k4) {
            float4 w4 = wr[k4];
            float4 q0 = *(const float4*)&t0s[0][k4 << 2];
            float4 q1 = *(const float4*)&t0s[1][k4 << 2];
            a0 = fmaf(q0.x, w4.x, a0); a0 = fmaf(q0.y, w4.y, a0);
            a0 = fmaf(q0.z, w4.z, a0); a0 = fmaf(q0.w, w4.w, a0);
            a1 = fmaf(q1.x, w4.x, a1); a1 = fmaf(q1.y, w4.y, a1);
            a1 = fmaf(q1.z, w4.z, a1); a1 = fmaf(q1.w, w4.w, a1);
        }
        qkout[(size_t)r0 * 512 + c] = a0;
        qkout[(size_t)(r0 + 1) * 512 + c] = a1;
    }
}

// ---------------------------------------------------------------- launch
extern "C" void kernel_launch(void* const* d_in, const int* in_sizes, int n_in,
                              void* d_out, int out_size, void* d_ws, size_t ws_size,
                              hipStream_t stream) {
    const float* inputs  = (const float*)d_in[0];
    const float* noise   = (const float*)d_in[1];
    const float* mu      = (const float*)d_in[2];
    const float* sg      = (const float*)d_in[3];
    const float* ln_in_g = (const float*)d_in[4];
    const float* ln_in_b = (const float*)d_in[5];
    const float* ln_s_g  = (const float*)d_in[6];
    const float* ln_s_b  = (const float*)d_in[7];
    const float* wq      = (const float*)d_in[8];
    const float* wk      = (const float*)d_in[9];
    const float* wv      = (const float*)d_in[10];
    const float* w_ih    = (const float*)d_in[11];
    const float* w_hh    = (const float*)d_in[12];
    const float* b_ih    = (const float*)d_in[13];
    const float* b_hh    = (const float*)d_in[14];
    const float* ln_m_g  = (const float*)d_in[15];
    const float* ln_m_b  = (const float*)d_in[16];
    const float* w1      = (const float*)d_in[17];
    const float* b1      = (const float*)d_in[18];
    const float* w2      = (const float*)d_in[19];
    const float* b2      = (const float*)d_in[20];

    float* ws = (float*)d_ws;
    const size_t SLOT = (size_t)B_ * S_ * D_;      // 131072
    size_t o = 0;
    float* slots = ws + o; o += SLOT;
    float* qk    = ws + o; o += SLOT;
    float* u0    = ws + o; o += SLOT;
    float* gg    = ws + o; o += (size_t)256 * 3072;       // 786432
    float* Mqk   = ws + o; o += (size_t)D_ * D_;          // 262144
    float* Wiv   = ws + o; o += (size_t)3 * D_ * D_;      // 786432
    float* statsS= ws + o; o += 512;
    float* part  = ws + o; o += (size_t)16 * B_ * 4096;   // 2097152
    float* bsum  = ws + o; o += (size_t)B_ * 16 * 16;     // 8192

    // ---- prologue (4 dispatches)
    k_gemm<2,0><<<dim3(16, 8), 256, 0, stream>>>(wk, wq, nullptr, Mqk,
                                                 512, 512, 512, nullptr, nullptr, nullptr);
    k_gemm<0,0><<<dim3(16, 24), 256, 0, stream>>>(w_ih, wv, nullptr, Wiv,
                                                  1536, 512, 512, nullptr, nullptr, nullptr);
    k_init<<<64, 256, 0, stream>>>(noise, mu, sg, slots, statsS);
    k_gemm<1,1><<<dim3(16, 4), 256, 0, stream>>>(slots, Mqk, nullptr, qk,
                                                 256, 512, 512, statsS, ln_s_g, ln_s_b);

    for (int it = 0; it < ITERS_; ++it) {
        k_attn_gh<<<608, 512, 0, stream>>>(inputs, qk, ln_in_g, ln_in_b, part, bsum,
                                           slots, w_hh, b_hh, gg);
        k_ured<<<256, 512, 0, stream>>>(part, bsum, ln_in_g, ln_in_b, u0);
        k_gi<<<dim3(48, 4), 256, 0, stream>>>(u0, Wiv, b_ih, gg);
        int last = (it == ITERS_ - 1);
        float* dst = last ? (float*)d_out : slots;
        k_p2<<<128, 512, 0, stream>>>(gg, slots, w1, b1, w2, b2, Mqk,
                                      ln_m_g, ln_m_b, ln_s_g, ln_s_b, dst, qk, last);
    }
}

// Round 10
// 693.617 us; speedup vs baseline: 1.2808x; 1.0098x over previous
//
#include <hip/hip_runtime.h>

#define B_ 32
#define N_ 4096
#define D_ 512
#define S_ 8
#define ITERS_ 3

__device__ __forceinline__ float sigmoid_f(float x) {
    return 1.0f / (1.0f + __expf(-x));
}
__device__ __forceinline__ float tanh_f(float x) {
    float e = __expf(2.0f * x);
    return 1.0f - 2.0f / (e + 1.0f);
}

// ---------------------------------------------------------------- shared GEMM tile body
// WT=0: C = A[M,K] @ W[K,N]; WT=1: C = A[M,K] @ W[N,K]^T; WT=2: C = A[K,M]^T @ W[K,N]
template<int WT, int LNA>
__device__ void gemm_body(const float* __restrict__ A, const float* __restrict__ W,
                          const float* __restrict__ bias, float* __restrict__ C,
                          int M, int N, int K, int bxi, int byi,
                          const float* __restrict__ stats,
                          const float* __restrict__ lng, const float* __restrict__ lnb,
                          float* smem) {
    float (*As)[68] = (float (*)[68])smem;               // 64*68
    float (*Ws)[36] = (float (*)[36])(smem + 64 * 68);   // 64*36
    int t  = threadIdx.x;
    int bm = byi * 64, bn = bxi * 32;
    int tm = t >> 4, tn = t & 15;
    float acc[4][2] = {{0.f,0.f},{0.f,0.f},{0.f,0.f},{0.f,0.f}};

    for (int kk = 0; kk < K; kk += 64) {
        __syncthreads();
        if (WT == 2) {
#pragma unroll
            for (int r = 0; r < 4; ++r) {
                int idx = t + r * 256;
                int k = idx >> 4, m4 = idx & 15;
                float4 a4 = *(const float4*)(A + (size_t)(kk + k) * M + bm + (m4 << 2));
                *(float4*)&As[k][m4 << 2] = a4;
            }
        } else {
#pragma unroll
            for (int r = 0; r < 4; ++r) {
                int flat = t * 4 + r * 1024;
                int m = flat >> 6, k = flat & 63;
                float4 a4 = *(const float4*)(A + (size_t)(bm + m) * K + kk + k);
                if (LNA) {
                    float mean = stats[(bm + m) * 2];
                    float rs   = stats[(bm + m) * 2 + 1];
                    float4 g4 = *(const float4*)(lng + kk + k);
                    float4 b4 = *(const float4*)(lnb + kk + k);
                    a4.x = fmaf((a4.x - mean) * rs, g4.x, b4.x);
                    a4.y = fmaf((a4.y - mean) * rs, g4.y, b4.y);
                    a4.z = fmaf((a4.z - mean) * rs, g4.z, b4.z);
                    a4.w = fmaf((a4.w - mean) * rs, g4.w, b4.w);
                }
                As[k + 0][m] = a4.x; As[k + 1][m] = a4.y;
                As[k + 2][m] = a4.z; As[k + 3][m] = a4.w;
            }
        }
        if (WT == 1) {
#pragma unroll
            for (int r = 0; r < 2; ++r) {
                int flat = t * 4 + r * 1024;
                int n = flat >> 6, k = flat & 63;
                float4 w4 = *(const float4*)(W + (size_t)(bn + n) * K + kk + k);
                Ws[k + 0][n] = w4.x; Ws[k + 1][n] = w4.y;
                Ws[k + 2][n] = w4.z; Ws[k + 3][n] = w4.w;
            }
        } else {
#pragma unroll
            for (int r = 0; r < 2; ++r) {
                int flat = t * 4 + r * 1024;
                int k = flat >> 5, n = flat & 31;
                float4 w4 = *(const float4*)(W + (size_t)(kk + k) * N + bn + n);
                *(float4*)&Ws[k][n] = w4;
            }
        }
        __syncthreads();
#pragma unroll
        for (int k = 0; k < 64; ++k) {
            float4 a = *(const float4*)&As[k][tm << 2];
            float2 w = *(const float2*)&Ws[k][tn << 1];
            acc[0][0] = fmaf(a.x, w.x, acc[0][0]); acc[0][1] = fmaf(a.x, w.y, acc[0][1]);
            acc[1][0] = fmaf(a.y, w.x, acc[1][0]); acc[1][1] = fmaf(a.y, w.y, acc[1][1]);
            acc[2][0] = fmaf(a.z, w.x, acc[2][0]); acc[2][1] = fmaf(a.z, w.y, acc[2][1]);
            acc[3][0] = fmaf(a.w, w.x, acc[3][0]); acc[3][1] = fmaf(a.w, w.y, acc[3][1]);
        }
    }
#pragma unroll
    for (int i = 0; i < 4; ++i) {
#pragma unroll
        for (int j = 0; j < 2; ++j) {
            int row = bm + (tm << 2) + i;
            int col = bn + (tn << 1) + j;
            float v = acc[i][j];
            if (bias) v += bias[col];
            C[(size_t)row * N + col] = v;
        }
    }
}

// ---------------------------------------------------------------- slot init body
__device__ void init_body(const float* __restrict__ noise, const float* __restrict__ mu,
                          const float* __restrict__ sg, float* __restrict__ slots,
                          float* __restrict__ stats, int blk) {
    int wid = threadIdx.x >> 6, lane = threadIdx.x & 63;
    int row = blk * 4 + wid;                              // 0..255
    const float4* nz = (const float4*)(noise + (size_t)row * D_);
    const float4* m4 = (const float4*)(mu + (size_t)(row & 7) * D_);
    const float4* s4 = (const float4*)(sg + (size_t)(row & 7) * D_);
    float4 v0 = nz[lane], v1 = nz[64 + lane];
    float4 a0 = m4[lane], a1 = m4[64 + lane];
    float4 c0 = s4[lane], c1 = s4[64 + lane];
    v0.x = fmaf(c0.x, v0.x, a0.x); v0.y = fmaf(c0.y, v0.y, a0.y);
    v0.z = fmaf(c0.z, v0.z, a0.z); v0.w = fmaf(c0.w, v0.w, a0.w);
    v1.x = fmaf(c1.x, v1.x, a1.x); v1.y = fmaf(c1.y, v1.y, a1.y);
    v1.z = fmaf(c1.z, v1.z, a1.z); v1.w = fmaf(c1.w, v1.w, a1.w);
    float4* o4 = (float4*)(slots + (size_t)row * D_);
    o4[lane] = v0; o4[64 + lane] = v1;
    float s1 = v0.x + v0.y + v0.z + v0.w + v1.x + v1.y + v1.z + v1.w;
    float s2 = v0.x*v0.x; s2 = fmaf(v0.y,v0.y,s2); s2 = fmaf(v0.z,v0.z,s2); s2 = fmaf(v0.w,v0.w,s2);
    s2 = fmaf(v1.x,v1.x,s2); s2 = fmaf(v1.y,v1.y,s2); s2 = fmaf(v1.z,v1.z,s2); s2 = fmaf(v1.w,v1.w,s2);
#pragma unroll
    for (int off = 32; off > 0; off >>= 1) {
        s1 += __shfl_xor(s1, off, 64);
        s2 += __shfl_xor(s2, off, 64);
    }
    if (lane == 0) {
        float mean = s1 * (1.0f / D_);
        float var  = s2 * (1.0f / D_) - mean * mean;
        stats[row * 2]     = mean;
        stats[row * 2 + 1] = rsqrtf(var + 1e-5f);
    }
}

// ---------------------------------------------------------------- merged prologue
// blocks [0,128): Mqk = wk^T @ wq ; [128,512): Wiv = w_ih @ wv ; [512,576): slot init
__global__ __launch_bounds__(256) void k_pro(const float* __restrict__ wk, const float* __restrict__ wq,
                                             const float* __restrict__ w_ih, const float* __restrict__ wv,
                                             float* __restrict__ Mqk, float* __restrict__ Wiv,
                                             const float* __restrict__ noise, const float* __restrict__ mu,
                                             const float* __restrict__ sg, float* __restrict__ slots,
                                             float* __restrict__ stats) {
    __shared__ float smem[64 * 68 + 64 * 36];
    int blk = blockIdx.x;
    if (blk < 128) {
        gemm_body<2,0>(wk, wq, nullptr, Mqk, 512, 512, 512, blk & 15, blk >> 4,
                       nullptr, nullptr, nullptr, smem);
    } else if (blk < 512) {
        int t2 = blk - 128;
        gemm_body<0,0>(w_ih, wv, nullptr, Wiv, 1536, 512, 512, t2 & 15, t2 >> 4,
                       nullptr, nullptr, nullptr, smem);
    } else {
        init_body(noise, mu, sg, slots, stats, blk - 512);
    }
}

// ---------------------------------------------------------------- generic small GEMM kernel
template<int WT, int LNA>
__global__ __launch_bounds__(256) void k_gemm(const float* __restrict__ A, const float* __restrict__ W,
                                              const float* __restrict__ bias, float* __restrict__ C,
                                              int M, int N, int K,
                                              const float* __restrict__ stats,
                                              const float* __restrict__ lng, const float* __restrict__ lnb) {
    __shared__ float smem[64 * 68 + 64 * 36];
    gemm_body<WT,LNA>(A, W, bias, C, M, N, K, blockIdx.x, blockIdx.y, stats, lng, lnb, smem);
}

// ---------------------------------------------------------------- fused attention v6 + gh overlay
// loop1: dots + fold -> logits to LDS (all waves, 4 rows each)
// loop2: scalar softmax, lane-per-row (32 lanes), w -> LDS
// loop3: P accumulation from registers (x kept from loop1), w via LDS broadcast
// FIRST=1: compute LN stats in-loop and cache to murs; FIRST=0: load murs.
// NOTE: smem must be 8704 floats — the gh overlay uses two [64][68] tiles.
template<int FIRST>
__global__ __launch_bounds__(512, 2) void k_attn_gh(const float* __restrict__ x,
                                                    const float* __restrict__ qk,
                                                    const float* __restrict__ g,
                                                    const float* __restrict__ bvec,
                                                    float* __restrict__ part,
                                                    float* __restrict__ bsum,
                                                    float2* __restrict__ murs,
                                                    const float* __restrict__ slots,
                                                    const float* __restrict__ w_hh,
                                                    const float* __restrict__ b_hh,
                                                    float* __restrict__ gg) {
    __shared__ float smem[8704];    // 34.8 KB union: attn uses 5424, gh uses 8704
    const int blk = blockIdx.x;
    const int t = threadIdx.x;

    if (blk >= 512) {
        // ---------------- gh GEMM overlay: 64x64 tiles, 512 threads
        const int t2 = blk - 512;
        const int ci = t2 % 24, ri = t2 / 24;
        const int bm = ri * 64, bn = ci * 64;
        float (*As)[68] = (float (*)[68])smem;
        float (*Ws)[68] = (float (*)[68])(smem + 64 * 68);
        const int tm = t >> 5, tn = t & 31;
        float acc[4][2] = {{0.f,0.f},{0.f,0.f},{0.f,0.f},{0.f,0.f}};
        for (int kk = 0; kk < 512; kk += 64) {
            __syncthreads();
#pragma unroll
            for (int r = 0; r < 2; ++r) {
                int flat = t * 4 + r * 2048;
                int m = flat >> 6, k = flat & 63;
                float4 a4 = *(const float4*)(slots + (size_t)(bm + m) * 512 + kk + k);
                As[k + 0][m] = a4.x; As[k + 1][m] = a4.y;
                As[k + 2][m] = a4.z; As[k + 3][m] = a4.w;
            }
#pragma unroll
            for (int r = 0; r < 2; ++r) {
                int flat = t * 4 + r * 2048;
                int n = flat >> 6, k = flat & 63;
                float4 w4 = *(const float4*)(w_hh + (size_t)(bn + n) * 512 + kk + k);
                Ws[k + 0][n] = w4.x; Ws[k + 1][n] = w4.y;
                Ws[k + 2][n] = w4.z; Ws[k + 3][n] = w4.w;
            }
            __syncthreads();
#pragma unroll
            for (int k = 0; k < 64; ++k) {
                const float4 a = *(const float4*)&As[k][tm << 2];
                const float2 w = *(const float2*)&Ws[k][tn << 1];
                acc[0][0] = fmaf(a.x, w.x, acc[0][0]); acc[0][1] = fmaf(a.x, w.y, acc[0][1]);
                acc[1][0] = fmaf(a.y, w.x, acc[1][0]); acc[1][1] = fmaf(a.y, w.y, acc[1][1]);
                acc[2][0] = fmaf(a.z, w.x, acc[2][0]); acc[2][1] = fmaf(a.z, w.y, acc[2][1]);
                acc[3][0] = fmaf(a.w, w.x, acc[3][0]); acc[3][1] = fmaf(a.w, w.y, acc[3][1]);
            }
        }
#pragma unroll
        for (int i = 0; i < 4; ++i) {
#pragma unroll
            for (int j = 0; j < 2; ++j) {
                int row = bm + (tm << 2) + i;
                int col = bn + (tn << 1) + j;
                gg[(size_t)row * 3072 + col] = acc[i][j] + b_hh[col];
            }
        }
        return;
    }

    // ---------------- attention: LDS layout (floats)
    float* qts  = smem;            // [0,4096)  q-tilde k-major; reused as u0s at end
    float* dds  = smem + 4096;     // [4096,4480)  32 rows x 12 (logits)
    float* wls  = smem + 4480;     // [4480,4864)  32 rows x 12 (weights)
    float* mur  = smem + 4864;     // [4864,5376)  256 rows x {mean,rs}
    float* redA = smem + 5376;     // 16
    float* redB = smem + 5392;     // 16
    float* c12  = smem + 5408;     // 16
    float* u0s  = smem;
    const int nc = blk & 15, b = blk >> 4;
    const int w = t >> 6, lane = t & 63;
    const size_t rowbase = (size_t)b * N_ + (size_t)nc * 256;

    // ---- q-prep: qts = g .* qk (k-major), c1[s], c2[s]
    {
        const float4* qk4 = (const float4*)(qk + (size_t)b * 4096);
        const float4* g4 = (const float4*)g;
        const float4* b4 = (const float4*)bvec;
        float c1p[2], c2p[2];
#pragma unroll
        for (int r = 0; r < 2; ++r) {
            int f = t + r * 512;
            float4 v = qk4[f];
            float4 gg4 = g4[f & 127];
            float4 bb = b4[f & 127];
            float4 qv = make_float4(v.x*gg4.x, v.y*gg4.y, v.z*gg4.z, v.w*gg4.w);
            *(float4*)&qts[((f & 127) * 8 + (f >> 7)) * 4] = qv;
            c1p[r] = qv.x + qv.y + qv.z + qv.w;
            c2p[r] = bb.x*v.x + bb.y*v.y + bb.z*v.z + bb.w*v.w;
        }
#pragma unroll
        for (int off = 32; off > 0; off >>= 1) {
#pragma unroll
            for (int r = 0; r < 2; ++r) {
                c1p[r] += __shfl_xor(c1p[r], off, 64);
                c2p[r] += __shfl_xor(c2p[r], off, 64);
            }
        }
        if (lane == 0) {
            redA[w * 2 + 0] = c1p[0]; redA[w * 2 + 1] = c1p[1];
            redB[w * 2 + 0] = c2p[0]; redB[w * 2 + 1] = c2p[1];
        }
    }
    if (!FIRST && t < 256) {
        float2 mm = murs[rowbase + t];
        mur[2 * t] = mm.x; mur[2 * t + 1] = mm.y;
    }
    __syncthreads();
    if (t < 8) {
        int s = t;
        float v1, v2;
        if (s < 4) { v1 = redA[4*s]       + redA[4*s + 2];     v2 = redB[4*s]       + redB[4*s + 2]; }
        else       { v1 = redA[4*(s-4)+1] + redA[4*(s-4)+3];   v2 = redB[4*(s-4)+1] + redB[4*(s-4)+3]; }
        c12[s] = v1; c12[8 + s] = v2;
    }
    __syncthreads();

    // ---- q into wave-distributed registers; c12 into registers
    float4 qa[8], qb[8];
#pragma unroll
    for (int s = 0; s < 8; ++s) {
        qa[s] = *(const float4*)&qts[(lane * 8 + s) * 4];
        qb[s] = *(const float4*)&qts[((64 + lane) * 8 + s) * 4];
    }
    float c1r[8], c2r[8];
#pragma unroll
    for (int s = 0; s < 8; ++s) { c1r[s] = c12[s]; c2r[s] = c12[8 + s]; }

    const bool hb5 = (lane & 32) != 0, hb4 = (lane & 16) != 0, hb3 = (lane & 8) != 0;
    const float cnorm = 1.0f / (1.0f + 8.0f * 1e-8f);
    const float eadd  = 1e-8f * cnorm;

    float4 acc0[8], acc1[8];
#pragma unroll
    for (int s = 0; s < 8; ++s) {
        acc0[s] = make_float4(0.f, 0.f, 0.f, 0.f);
        acc1[s] = make_float4(0.f, 0.f, 0.f, 0.f);
    }
    float aS8[8] = {0,0,0,0,0,0,0,0}, tS8[8] = {0,0,0,0,0,0,0,0};

    // batches: 8 x (32 rows: 4 per wave). cur regs hold this wave's 4 rows.
    const float4* xg = (const float4*)(x + rowbase * D_);
    float4 cur[8], nxt[8];
    {
        int r0 = w * 4;                            // batch 0 rows for this wave
#pragma unroll
        for (int i = 0; i < 4; ++i) {
            cur[2*i]   = xg[(size_t)(r0 + i) * 128 + lane];
            cur[2*i+1] = xg[(size_t)(r0 + i) * 128 + 64 + lane];
        }
    }

    for (int jb = 0; jb < 8; ++jb) {
        // ---- loop1: dots + fold for 4 rows; logits -> dds
#pragma unroll
        for (int i = 0; i < 4; ++i) {
            float4 xa = cur[2*i], xb = cur[2*i+1];
            float dd[8];
#pragma unroll
            for (int s = 0; s < 8; ++s) {
                float td = xa.x * qa[s].x;
                td = fmaf(xa.y, qa[s].y, td); td = fmaf(xa.z, qa[s].z, td); td = fmaf(xa.w, qa[s].w, td);
                td = fmaf(xb.x, qb[s].x, td); td = fmaf(xb.y, qb[s].y, td);
                td = fmaf(xb.z, qb[s].z, td); td = fmaf(xb.w, qb[s].w, td);
                dd[s] = td;
            }
            // fold -> lane holds full dot for slot gq=(lane>>3)
            float r4[4];
#pragma unroll
            for (int s = 0; s < 4; ++s) {
                float snd = hb5 ? dd[s] : dd[s + 4];
                float kp  = hb5 ? dd[s + 4] : dd[s];
                r4[s] = kp + __shfl_xor(snd, 32, 64);
            }
            float r2v[2];
#pragma unroll
            for (int s = 0; s < 2; ++s) {
                float snd = hb4 ? r4[s] : r4[s + 2];
                float kp  = hb4 ? r4[s + 2] : r4[s];
                r2v[s] = kp + __shfl_xor(snd, 16, 64);
            }
            float v;
            {
                float snd = hb3 ? r2v[0] : r2v[1];
                float kp  = hb3 ? r2v[1] : r2v[0];
                v = kp + __shfl_xor(snd, 8, 64);
            }
            v += __shfl_xor(v, 4, 64);
            v += __shfl_xor(v, 2, 64);
            v += __shfl_xor(v, 1, 64);
            int rb = w * 4 + i;
            if ((lane & 7) == 0) dds[rb * 12 + (lane >> 3)] = v;

            if (FIRST) {
                float sx = xa.x + xa.y + xa.z + xa.w + xb.x + xb.y + xb.z + xb.w;
                float sxx = xa.x*xa.x; sxx = fmaf(xa.y,xa.y,sxx); sxx = fmaf(xa.z,xa.z,sxx); sxx = fmaf(xa.w,xa.w,sxx);
                sxx = fmaf(xb.x,xb.x,sxx); sxx = fmaf(xb.y,xb.y,sxx); sxx = fmaf(xb.z,xb.z,sxx); sxx = fmaf(xb.w,xb.w,sxx);
#pragma unroll
                for (int off = 32; off > 0; off >>= 1) {
                    sx  += __shfl_xor(sx, off, 64);
                    sxx += __shfl_xor(sxx, off, 64);
                }
                float mean = sx * (1.0f / D_);
                float rs   = rsqrtf(sxx * (1.0f / D_) - mean * mean + 1e-5f);
                if (lane == 0) {
                    int br = jb * 32 + rb;
                    mur[br * 2] = mean; mur[br * 2 + 1] = rs;
                    murs[rowbase + br] = make_float2(mean, rs);
                }
            }
        }
        __syncthreads();
        // ---- loop2: scalar softmax, lane-per-row (wave 0, 32 lanes)
        if (w == 0 && lane < 32) {
            int br = jb * 32 + lane;
            float4 d03 = *(const float4*)&dds[lane * 12];
            float4 d47 = *(const float4*)&dds[lane * 12 + 4];
            float mean = mur[br * 2], rs = mur[br * 2 + 1];
            float mc = -rs * mean;
            float lg[8];
            lg[0] = fmaf(rs, d03.x, fmaf(mc, c1r[0], c2r[0]));
            lg[1] = fmaf(rs, d03.y, fmaf(mc, c1r[1], c2r[1]));
            lg[2] = fmaf(rs, d03.z, fmaf(mc, c1r[2], c2r[2]));
            lg[3] = fmaf(rs, d03.w, fmaf(mc, c1r[3], c2r[3]));
            lg[4] = fmaf(rs, d47.x, fmaf(mc, c1r[4], c2r[4]));
            lg[5] = fmaf(rs, d47.y, fmaf(mc, c1r[5], c2r[5]));
            lg[6] = fmaf(rs, d47.z, fmaf(mc, c1r[6], c2r[6]));
            lg[7] = fmaf(rs, d47.w, fmaf(mc, c1r[7], c2r[7]));
            float mx = lg[0];
#pragma unroll
            for (int s = 1; s < 8; ++s) mx = fmaxf(mx, lg[s]);
            float p[8], psum = 0.f;
#pragma unroll
            for (int s = 0; s < 8; ++s) { p[s] = __expf(lg[s] - mx); psum += p[s]; }
            float ip = cnorm / psum;
            float wv[8];
#pragma unroll
            for (int s = 0; s < 8; ++s) {
                float a = fmaf(p[s], ip, eadd);
                wv[s] = a * rs;
                aS8[s] += a;
                tS8[s] = fmaf(wv[s], mean, tS8[s]);
            }
            *(float4*)&wls[lane * 12]     = make_float4(wv[0], wv[1], wv[2], wv[3]);
            *(float4*)&wls[lane * 12 + 4] = make_float4(wv[4], wv[5], wv[6], wv[7]);
        }
        __syncthreads();
        // ---- prefetch next batch while accumulating
        {
            int jn = (jb < 7) ? jb + 1 : 7;
            int r0 = jn * 32 + w * 4;
#pragma unroll
            for (int i = 0; i < 4; ++i) {
                nxt[2*i]   = xg[(size_t)(r0 + i) * 128 + lane];
                nxt[2*i+1] = xg[(size_t)(r0 + i) * 128 + 64 + lane];
            }
        }
        // ---- loop3: P accumulation (x from regs, w via LDS broadcast)
#pragma unroll
        for (int i = 0; i < 4; ++i) {
            int rb = w * 4 + i;
            float4 w03 = *(const float4*)&wls[rb * 12];
            float4 w47 = *(const float4*)&wls[rb * 12 + 4];
            float4 xa = cur[2*i], xb = cur[2*i+1];
            acc0[0].x = fmaf(w03.x, xa.x, acc0[0].x); acc0[0].y = fmaf(w03.x, xa.y, acc0[0].y);
            acc0[0].z = fmaf(w03.x, xa.z, acc0[0].z); acc0[0].w = fmaf(w03.x, xa.w, acc0[0].w);
            acc1[0].x = fmaf(w03.x, xb.x, acc1[0].x); acc1[0].y = fmaf(w03.x, xb.y, acc1[0].y);
            acc1[0].z = fmaf(w03.x, xb.z, acc1[0].z); acc1[0].w = fmaf(w03.x, xb.w, acc1[0].w);
            acc0[1].x = fmaf(w03.y, xa.x, acc0[1].x); acc0[1].y = fmaf(w03.y, xa.y, acc0[1].y);
            acc0[1].z = fmaf(w03.y, xa.z, acc0[1].z); acc0[1].w = fmaf(w03.y, xa.w, acc0[1].w);
            acc1[1].x = fmaf(w03.y, xb.x, acc1[1].x); acc1[1].y = fmaf(w03.y, xb.y, acc1[1].y);
            acc1[1].z = fmaf(w03.y, xb.z, acc1[1].z); acc1[1].w = fmaf(w03.y, xb.w, acc1[1].w);
            acc0[2].x = fmaf(w03.z, xa.x, acc0[2].x); acc0[2].y = fmaf(w03.z, xa.y, acc0[2].y);
            acc0[2].z = fmaf(w03.z, xa.z, acc0[2].z); acc0[2].w = fmaf(w03.z, xa.w, acc0[2].w);
            acc1[2].x = fmaf(w03.z, xb.x, acc1[2].x); acc1[2].y = fmaf(w03.z, xb.y, acc1[2].y);
            acc1[2].z = fmaf(w03.z, xb.z, acc1[2].z); acc1[2].w = fmaf(w03.z, xb.w, acc1[2].w);
            acc0[3].x = fmaf(w03.w, xa.x, acc0[3].x); acc0[3].y = fmaf(w03.w, xa.y, acc0[3].y);
            acc0[3].z = fmaf(w03.w, xa.z, acc0[3].z); acc0[3].w = fmaf(w03.w, xa.w, acc0[3].w);
            acc1[3].x = fmaf(w03.w, xb.x, acc1[3].x); acc1[3].y = fmaf(w03.w, xb.y, acc1[3].y);
            acc1[3].z = fmaf(w03.w, xb.z, acc1[3].z); acc1[3].w = fmaf(w03.w, xb.w, acc1[3].w);
            acc0[4].x = fmaf(w47.x, xa.x, acc0[4].x); acc0[4].y = fmaf(w47.x, xa.y, acc0[4].y);
            acc0[4].z = fmaf(w47.x, xa.z, acc0[4].z); acc0[4].w = fmaf(w47.x, xa.w, acc0[4].w);
            acc1[4].x = fmaf(w47.x, xb.x, acc1[4].x); acc1[4].y = fmaf(w47.x, xb.y, acc1[4].y);
            acc1[4].z = fmaf(w47.x, xb.z, acc1[4].z); acc1[4].w = fmaf(w47.x, xb.w, acc1[4].w);
            acc0[5].x = fmaf(w47.y, xa.x, acc0[5].x); acc0[5].y = fmaf(w47.y, xa.y, acc0[5].y);
            acc0[5].z = fmaf(w47.y, xa.z, acc0[5].z); acc0[5].w = fmaf(w47.y, xa.w, acc0[5].w);
            acc1[5].x = fmaf(w47.y, xb.x, acc1[5].x); acc1[5].y = fmaf(w47.y, xb.y, acc1[5].y);
            acc1[5].z = fmaf(w47.y, xb.z, acc1[5].z); acc1[5].w = fmaf(w47.y, xb.w, acc1[5].w);
            acc0[6].x = fmaf(w47.z, xa.x, acc0[6].x); acc0[6].y = fmaf(w47.z, xa.y, acc0[6].y);
            acc0[6].z = fmaf(w47.z, xa.z, acc0[6].z); acc0[6].w = fmaf(w47.z, xa.w, acc0[6].w);
            acc1[6].x = fmaf(w47.z, xb.x, acc1[6].x); acc1[6].y = fmaf(w47.z, xb.y, acc1[6].y);
            acc1[6].z = fmaf(w47.z, xb.z, acc1[6].z); acc1[6].w = fmaf(w47.z, xb.w, acc1[6].w);
            acc0[7].x = fmaf(w47.w, xa.x, acc0[7].x); acc0[7].y = fmaf(w47.w, xa.y, acc0[7].y);
            acc0[7].z = fmaf(w47.w, xa.z, acc0[7].z); acc0[7].w = fmaf(w47.w, xa.w, acc0[7].w);
            acc1[7].x = fmaf(w47.w, xb.x, acc1[7].x); acc1[7].y = fmaf(w47.w, xb.y, acc1[7].y);
            acc1[7].z = fmaf(w47.w, xb.z, acc1[7].z); acc1[7].w = fmaf(w47.w, xb.w, acc1[7].w);
        }
#pragma unroll
        for (int i = 0; i < 8; ++i) cur[i] = nxt[i];
        __syncthreads();   // wls/dds safe to overwrite next batch
    }

    // ---- bsum: reduce aS8/tS8 within wave 0 and store
    if (w == 0) {
#pragma unroll
        for (int off = 32; off > 0; off >>= 1) {
#pragma unroll
            for (int s = 0; s < 8; ++s) {
                aS8[s] += __shfl_xor(aS8[s], off, 64);
                tS8[s] += __shfl_xor(tS8[s], off, 64);
            }
        }
        if (lane == 0) {
            float* bs = bsum + (size_t)(b * 16 + nc) * 16;
#pragma unroll
            for (int s = 0; s < 8; ++s) { bs[s] = aS8[s]; bs[8 + s] = tS8[s]; }
        }
    }
    // ---- cross-wave P reduction into LDS (overlaps dead qts)
    for (int w2 = 0; w2 < 8; ++w2) {
        if (w == w2) {
#pragma unroll
            for (int s = 0; s < 8; ++s) {
                float* p0 = &u0s[s * 512 + (lane << 2)];
                float* p1 = p0 + 256;
                if (w2 == 0) {
                    *(float4*)p0 = acc0[s];
                    *(float4*)p1 = acc1[s];
                } else {
                    float4 v0 = *(float4*)p0;
                    v0.x += acc0[s].x; v0.y += acc0[s].y; v0.z += acc0[s].z; v0.w += acc0[s].w;
                    *(float4*)p0 = v0;
                    float4 v1 = *(float4*)p1;
                    v1.x += acc1[s].x; v1.y += acc1[s].y; v1.z += acc1[s].z; v1.w += acc1[s].w;
                    *(float4*)p1 = v1;
                }
            }
        }
        __syncthreads();
    }
    float4* d4 = (float4*)(part + (size_t)(b * 16 + nc) * 4096);
    const float4* s4 = (const float4*)u0s;
    d4[t] = s4[t];
    d4[t + 512] = s4[t + 512];
}

// ---------------------------------------------------------------- u0 reduce + affine correction
__global__ __launch_bounds__(512) void k_ured(const float* __restrict__ part,
                                              const float* __restrict__ bsum,
                                              const float* __restrict__ g,
                                              const float* __restrict__ bvec,
                                              float* __restrict__ u0) {
    const int bs = blockIdx.x;          // 0..255
    const int b = bs >> 3, s = bs & 7;
    const int d = threadIdx.x;
    float Av = 0.f, Tv = 0.f;
#pragma unroll
    for (int nc = 0; nc < 16; ++nc) {
        Av += bsum[(size_t)(b * 16 + nc) * 16 + s];
        Tv += bsum[(size_t)(b * 16 + nc) * 16 + 8 + s];
    }
    float p = 0.f;
#pragma unroll
    for (int nc = 0; nc < 16; ++nc)
        p += part[(size_t)(b * 16 + nc) * 4096 + s * 512 + d];
    u0[(size_t)bs * 512 + d] = fmaf(g[d], p - Tv, Av * bvec[d]);
}

// ---------------------------------------------------------------- gi GEMM into gg cols 1536..3071
__global__ __launch_bounds__(256) void k_gi(const float* __restrict__ u0,
                                            const float* __restrict__ Wiv,
                                            const float* __restrict__ b_ih,
                                            float* __restrict__ gg) {
    __shared__ float As[64][68];
    __shared__ float Ws[64][36];
    const int t = threadIdx.x;
    const int bn = blockIdx.x * 32;
    const int bm = blockIdx.y * 64;
    int tm = t >> 4, tn = t & 15;
    float acc[4][2] = {{0.f,0.f},{0.f,0.f},{0.f,0.f},{0.f,0.f}};

    for (int kk = 0; kk < 512; kk += 64) {
        __syncthreads();
#pragma unroll
        for (int r = 0; r < 4; ++r) {
            int flat = t * 4 + r * 1024;
            int m = flat >> 6, k = flat & 63;
            float4 a4 = *(const float4*)(u0 + (size_t)(bm + m) * 512 + kk + k);
            As[k + 0][m] = a4.x; As[k + 1][m] = a4.y;
            As[k + 2][m] = a4.z; As[k + 3][m] = a4.w;
        }
#pragma unroll
        for (int r = 0; r < 2; ++r) {
            int flat = t * 4 + r * 1024;
            int n = flat >> 6, k = flat & 63;
            float4 w4 = *(const float4*)(Wiv + (size_t)(bn + n) * 512 + kk + k);
            Ws[k + 0][n] = w4.x; Ws[k + 1][n] = w4.y;
            Ws[k + 2][n] = w4.z; Ws[k + 3][n] = w4.w;
        }
        __syncthreads();
#pragma unroll
        for (int k = 0; k < 64; ++k) {
            float4 a = *(const float4*)&As[k][tm << 2];
            float2 w = *(const float2*)&Ws[k][tn << 1];
            acc[0][0] = fmaf(a.x, w.x, acc[0][0]); acc[0][1] = fmaf(a.x, w.y, acc[0][1]);
            acc[1][0] = fmaf(a.y, w.x, acc[1][0]); acc[1][1] = fmaf(a.y, w.y, acc[1][1]);
            acc[2][0] = fmaf(a.z, w.x, acc[2][0]); acc[2][1] = fmaf(a.z, w.y, acc[2][1]);
            acc[3][0] = fmaf(a.w, w.x, acc[3][0]); acc[3][1] = fmaf(a.w, w.y, acc[3][1]);
        }
    }
#pragma unroll
    for (int i = 0; i < 4; ++i) {
#pragma unroll
        for (int j = 0; j < 2; ++j) {
            int row = bm + (tm << 2) + i;
            int cw  = bn + (tn << 1) + j;
            gg[(size_t)row * 3072 + 1536 + cw] = acc[i][j] + b_ih[cw];
        }
    }
}

// ---------------------------------------------------------------- P2: GRU + MLP + LN + qk_next
__global__ __launch_bounds__(512) void k_p2(const float* __restrict__ gg,
                                            const float* __restrict__ slots,
                                            const float* __restrict__ w1, const float* __restrict__ b1,
                                            const float* __restrict__ w2, const float* __restrict__ b2,
                                            const float* __restrict__ wqkT,
                                            const float* __restrict__ ln_m_g, const float* __restrict__ ln_m_b,
                                            const float* __restrict__ ln_s_g, const float* __restrict__ ln_s_b,
                                            float* __restrict__ dst, float* __restrict__ qkout, int last) {
    __shared__ float s2s[2][512];
    __shared__ float t0s[2][512];
    __shared__ float hs[2][512];
    __shared__ float stat[4];
    const int t = threadIdx.x;
    const int wid = t >> 6, lane = t & 63;
    const int r0 = blockIdx.x * 2;

#pragma unroll
    for (int j = 0; j < 2; ++j) {
        int flat = t + j * 512;
        int r = flat >> 9, d = flat & 511;
        size_t row = r0 + r;
        const float* ghb = gg + row * 3072;
        const float* gib = ghb + 1536;
        float gir = gib[d], giz = gib[d + 512], gin = gib[d + 1024];
        float ghr = ghb[d], ghz = ghb[d + 512], ghn = ghb[d + 1024];
        float rr = sigmoid_f(gir + ghr);
        float zz = sigmoid_f(giz + ghz);
        float nn = tanh_f(fmaf(rr, ghn, gin));
        float sp = slots[row * 512 + d];
        s2s[r][d] = fmaf(1.0f - zz, nn, zz * sp);
    }
    __syncthreads();
    if (wid < 2) {
        const float4* sr = (const float4*)s2s[wid];
        float4 a = sr[lane], bq = sr[64 + lane];
        float s1 = a.x + a.y + a.z + a.w + bq.x + bq.y + bq.z + bq.w;
        float s2 = a.x*a.x; s2 = fmaf(a.y,a.y,s2); s2 = fmaf(a.z,a.z,s2); s2 = fmaf(a.w,a.w,s2);
        s2 = fmaf(bq.x,bq.x,s2); s2 = fmaf(bq.y,bq.y,s2); s2 = fmaf(bq.z,bq.z,s2); s2 = fmaf(bq.w,bq.w,s2);
#pragma unroll
        for (int off = 32; off > 0; off >>= 1) {
            s1 += __shfl_xor(s1, off, 64);
            s2 += __shfl_xor(s2, off, 64);
        }
        if (lane == 0) {
            float mean = s1 * (1.0f / D_);
            float var  = s2 * (1.0f / D_) - mean * mean;
            stat[wid * 2] = mean;
            stat[wid * 2 + 1] = rsqrtf(var + 1e-5f);
        }
    }
    __syncthreads();
#pragma unroll
    for (int j = 0; j < 2; ++j) {
        int flat = t + j * 512;
        int r = flat >> 9, d = flat & 511;
        t0s[r][d] = fmaf((s2s[r][d] - stat[r * 2]) * stat[r * 2 + 1], ln_m_g[d], ln_m_b[d]);
    }
    __syncthreads();
    {
        const int c = t;
        const float4* wr = (const float4*)(w1 + (size_t)c * 512);
        float a0 = 0.f, a1 = 0.f;
#pragma unroll 8
        for (int k4 = 0; k4 < 128; ++k4) {
            float4 w4 = wr[k4];
            float4 q0 = *(const float4*)&t0s[0][k4 << 2];
            float4 q1 = *(const float4*)&t0s[1][k4 << 2];
            a0 = fmaf(q0.x, w4.x, a0); a0 = fmaf(q0.y, w4.y, a0);
            a0 = fmaf(q0.z, w4.z, a0); a0 = fmaf(q0.w, w4.w, a0);
            a1 = fmaf(q1.x, w4.x, a1); a1 = fmaf(q1.y, w4.y, a1);
            a1 = fmaf(q1.z, w4.z, a1); a1 = fmaf(q1.w, w4.w, a1);
        }
        float bc = b1[c];
        hs[0][c] = fmaxf(a0 + bc, 0.f);
        hs[1][c] = fmaxf(a1 + bc, 0.f);
    }
    __syncthreads();
    {
        const int c = t;
        const float4* wr = (const float4*)(w2 + (size_t)c * 512);
        float a0 = 0.f, a1 = 0.f;
#pragma unroll 8
        for (int k4 = 0; k4 < 128; ++k4) {
            float4 w4 = wr[k4];
            float4 q0 = *(const float4*)&hs[0][k4 << 2];
            float4 q1 = *(const float4*)&hs[1][k4 << 2];
            a0 = fmaf(q0.x, w4.x, a0); a0 = fmaf(q0.y, w4.y, a0);
            a0 = fmaf(q0.z, w4.z, a0); a0 = fmaf(q0.w, w4.w, a0);
            a1 = fmaf(q1.x, w4.x, a1); a1 = fmaf(q1.y, w4.y, a1);
            a1 = fmaf(q1.z, w4.z, a1); a1 = fmaf(q1.w, w4.w, a1);
        }
        float bc = b2[c];
        float o0 = s2s[0][c] + a0 + bc;
        float o1 = s2s[1][c] + a1 + bc;
        dst[(size_t)r0 * 512 + c] = o0;
        dst[(size_t)(r0 + 1) * 512 + c] = o1;
        s2s[0][c] = o0;
        s2s[1][c] = o1;
    }
    if (last) return;
    __syncthreads();
    if (wid < 2) {
        const float4* sr = (const float4*)s2s[wid];
        float4 a = sr[lane], bq = sr[64 + lane];
        float s1 = a.x + a.y + a.z + a.w + bq.x + bq.y + bq.z + bq.w;
        float s2 = a.x*a.x; s2 = fmaf(a.y,a.y,s2); s2 = fmaf(a.z,a.z,s2); s2 = fmaf(a.w,a.w,s2);
        s2 = fmaf(bq.x,bq.x,s2); s2 = fmaf(bq.y,bq.y,s2); s2 = fmaf(bq.z,bq.z,s2); s2 = fmaf(bq.w,bq.w,s2);
#pragma unroll
        for (int off = 32; off > 0; off >>= 1) {
            s1 += __shfl_xor(s1, off, 64);
            s2 += __shfl_xor(s2, off, 64);
        }
        if (lane == 0) {
            float mean = s1 * (1.0f / D_);
            float var  = s2 * (1.0f / D_) - mean * mean;
            stat[wid * 2] = mean;
            stat[wid * 2 + 1] = rsqrtf(var + 1e-5f);
        }
    }
    __syncthreads();
#pragma unroll
    for (int j = 0; j < 2; ++j) {
        int flat = t + j * 512;
        int r = flat >> 9, d = flat & 511;
        t0s[r][d] = fmaf((s2s[r][d] - stat[r * 2]) * stat[r * 2 + 1], ln_s_g[d], ln_s_b[d]);
    }
    __syncthreads();
    {
        const int c = t;
        const float4* wr = (const float4*)(wqkT + (size_t)c * 512);
        float a0 = 0.f, a1 = 0.f;
#pragma unroll 8
        for (int k4 = 0; k4 < 128; ++k4) {
            float4 w4 = wr[k4];
            float4 q0 = *(const float4*)&t0s[0][k4 << 2];
            float4 q1 = *(const float4*)&t0s[1][k4 << 2];
            a0 = fmaf(q0.x, w4.x, a0); a0 = fmaf(q0.y, w4.y, a0);
            a0 = fmaf(q0.z, w4.z, a0); a0 = fmaf(q0.w, w4.w, a0);
            a1 = fmaf(q1.x, w4.x, a1); a1 = fmaf(q1.y, w4.y, a1);
            a1 = fmaf(q1.z, w4.z, a1); a1 = fmaf(q1.w, w4.w, a1);
        }
        qkout[(size_t)r0 * 512 + c] = a0;
        qkout[(size_t)(r0 + 1) * 512 + c] = a1;
    }
}

// ---------------------------------------------------------------- launch
extern "C" void kernel_launch(void* const* d_in, const int* in_sizes, int n_in,
                              void* d_out, int out_size, void* d_ws, size_t ws_size,
                              hipStream_t stream) {
    const float* inputs  = (const float*)d_in[0];
    const float* noise   = (const float*)d_in[1];
    const float* mu      = (const float*)d_in[2];
    const float* sg      = (const float*)d_in[3];
    const float* ln_in_g = (const float*)d_in[4];
    const float* ln_in_b = (const float*)d_in[5];
    const float* ln_s_g  = (const float*)d_in[6];
    const float* ln_s_b  = (const float*)d_in[7];
    const float* wq      = (const float*)d_in[8];
    const float* wk      = (const float*)d_in[9];
    const float* wv      = (const float*)d_in[10];
    const float* w_ih    = (const float*)d_in[11];
    const float* w_hh    = (const float*)d_in[12];
    const float* b_ih    = (const float*)d_in[13];
    const float* b_hh    = (const float*)d_in[14];
    const float* ln_m_g  = (const float*)d_in[15];
    const float* ln_m_b  = (const float*)d_in[16];
    const float* w1      = (const float*)d_in[17];
    const float* b1      = (const float*)d_in[18];
    const float* w2      = (const float*)d_in[19];
    const float* b2      = (const float*)d_in[20];

    float* ws = (float*)d_ws;
    const size_t SLOT = (size_t)B_ * S_ * D_;      // 131072
    size_t o = 0;
    float* slots = ws + o; o += SLOT;
    float* qk    = ws + o; o += SLOT;
    float* u0    = ws + o; o += SLOT;
    float* gg    = ws + o; o += (size_t)256 * 3072;       // 786432
    float* Mqk   = ws + o; o += (size_t)D_ * D_;          // 262144
    float* Wiv   = ws + o; o += (size_t)3 * D_ * D_;      // 786432
    float* statsS= ws + o; o += 512;
    float* part  = ws + o; o += (size_t)16 * B_ * 4096;   // 2097152
    float* bsum  = ws + o; o += (size_t)B_ * 16 * 16;     // 8192
    float2* murs = (float2*)(ws + o); o += (size_t)2 * B_ * N_;   // 262144 floats

    // ---- prologue (2 dispatches)
    k_pro<<<576, 256, 0, stream>>>(wk, wq, w_ih, wv, Mqk, Wiv, noise, mu, sg, slots, statsS);
    k_gemm<1,1><<<dim3(16, 4), 256, 0, stream>>>(slots, Mqk, nullptr, qk,
                                                 256, 512, 512, statsS, ln_s_g, ln_s_b);

    for (int it = 0; it < ITERS_; ++it) {
        if (it == 0)
            k_attn_gh<1><<<608, 512, 0, stream>>>(inputs, qk, ln_in_g, ln_in_b, part, bsum,
                                                  murs, slots, w_hh, b_hh, gg);
        else
            k_attn_gh<0><<<608, 512, 0, stream>>>(inputs, qk, ln_in_g, ln_in_b, part, bsum,
                                                  murs, slots, w_hh, b_hh, gg);
        k_ured<<<256, 512, 0, stream>>>(part, bsum, ln_in_g, ln_in_b, u0);
        k_gi<<<dim3(48, 4), 256, 0, stream>>>(u0, Wiv, b_ih, gg);
        int last = (it == ITERS_ - 1);
        float* dst = last ? (float*)d_out : slots;
        k_p2<<<128, 512, 0, stream>>>(gg, slots, w1, b1, w2, b2, Mqk,
                                      ln_m_g, ln_m_b, ln_s_g, ln_s_b, dst, qk, last);
    }
}

// Round 11
// 676.996 us; speedup vs baseline: 1.3122x; 1.0246x over previous
//
#include <hip/hip_runtime.h>

#define B_ 32
#define N_ 4096
#define D_ 512
#define S_ 8
#define ITERS_ 3

__device__ __forceinline__ float sigmoid_f(float x) {
    return 1.0f / (1.0f + __expf(-x));
}
__device__ __forceinline__ float tanh_f(float x) {
    float e = __expf(2.0f * x);
    return 1.0f - 2.0f / (e + 1.0f);
}

// ---------------------------------------------------------------- shared GEMM tile body
// WT=0: C = A[M,K] @ W[K,N]; WT=1: C = A[M,K] @ W[N,K]^T; WT=2: C = A[K,M]^T @ W[K,N]
template<int WT, int LNA>
__device__ void gemm_body(const float* __restrict__ A, const float* __restrict__ W,
                          const float* __restrict__ bias, float* __restrict__ C,
                          int M, int N, int K, int bxi, int byi,
                          const float* __restrict__ stats,
                          const float* __restrict__ lng, const float* __restrict__ lnb,
                          float* smem) {
    float (*As)[68] = (float (*)[68])smem;               // 64*68
    float (*Ws)[36] = (float (*)[36])(smem + 64 * 68);   // 64*36
    int t  = threadIdx.x;
    int bm = byi * 64, bn = bxi * 32;
    int tm = t >> 4, tn = t & 15;
    float acc[4][2] = {{0.f,0.f},{0.f,0.f},{0.f,0.f},{0.f,0.f}};

    for (int kk = 0; kk < K; kk += 64) {
        __syncthreads();
        if (WT == 2) {
#pragma unroll
            for (int r = 0; r < 4; ++r) {
                int idx = t + r * 256;
                int k = idx >> 4, m4 = idx & 15;
                float4 a4 = *(const float4*)(A + (size_t)(kk + k) * M + bm + (m4 << 2));
                *(float4*)&As[k][m4 << 2] = a4;
            }
        } else {
#pragma unroll
            for (int r = 0; r < 4; ++r) {
                int flat = t * 4 + r * 1024;
                int m = flat >> 6, k = flat & 63;
                float4 a4 = *(const float4*)(A + (size_t)(bm + m) * K + kk + k);
                if (LNA) {
                    float mean = stats[(bm + m) * 2];
                    float rs   = stats[(bm + m) * 2 + 1];
                    float4 g4 = *(const float4*)(lng + kk + k);
                    float4 b4 = *(const float4*)(lnb + kk + k);
                    a4.x = fmaf((a4.x - mean) * rs, g4.x, b4.x);
                    a4.y = fmaf((a4.y - mean) * rs, g4.y, b4.y);
                    a4.z = fmaf((a4.z - mean) * rs, g4.z, b4.z);
                    a4.w = fmaf((a4.w - mean) * rs, g4.w, b4.w);
                }
                As[k + 0][m] = a4.x; As[k + 1][m] = a4.y;
                As[k + 2][m] = a4.z; As[k + 3][m] = a4.w;
            }
        }
        if (WT == 1) {
#pragma unroll
            for (int r = 0; r < 2; ++r) {
                int flat = t * 4 + r * 1024;
                int n = flat >> 6, k = flat & 63;
                float4 w4 = *(const float4*)(W + (size_t)(bn + n) * K + kk + k);
                Ws[k + 0][n] = w4.x; Ws[k + 1][n] = w4.y;
                Ws[k + 2][n] = w4.z; Ws[k + 3][n] = w4.w;
            }
        } else {
#pragma unroll
            for (int r = 0; r < 2; ++r) {
                int flat = t * 4 + r * 1024;
                int k = flat >> 5, n = flat & 31;
                float4 w4 = *(const float4*)(W + (size_t)(kk + k) * N + bn + n);
                *(float4*)&Ws[k][n] = w4;
            }
        }
        __syncthreads();
#pragma unroll
        for (int k = 0; k < 64; ++k) {
            float4 a = *(const float4*)&As[k][tm << 2];
            float2 w = *(const float2*)&Ws[k][tn << 1];
            acc[0][0] = fmaf(a.x, w.x, acc[0][0]); acc[0][1] = fmaf(a.x, w.y, acc[0][1]);
            acc[1][0] = fmaf(a.y, w.x, acc[1][0]); acc[1][1] = fmaf(a.y, w.y, acc[1][1]);
            acc[2][0] = fmaf(a.z, w.x, acc[2][0]); acc[2][1] = fmaf(a.z, w.y, acc[2][1]);
            acc[3][0] = fmaf(a.w, w.x, acc[3][0]); acc[3][1] = fmaf(a.w, w.y, acc[3][1]);
        }
    }
#pragma unroll
    for (int i = 0; i < 4; ++i) {
#pragma unroll
        for (int j = 0; j < 2; ++j) {
            int row = bm + (tm << 2) + i;
            int col = bn + (tn << 1) + j;
            float v = acc[i][j];
            if (bias) v += bias[col];
            C[(size_t)row * N + col] = v;
        }
    }
}

// ---------------------------------------------------------------- slot init body
__device__ void init_body(const float* __restrict__ noise, const float* __restrict__ mu,
                          const float* __restrict__ sg, float* __restrict__ slots,
                          float* __restrict__ stats, int blk) {
    int wid = threadIdx.x >> 6, lane = threadIdx.x & 63;
    int row = blk * 4 + wid;                              // 0..255
    const float4* nz = (const float4*)(noise + (size_t)row * D_);
    const float4* m4 = (const float4*)(mu + (size_t)(row & 7) * D_);
    const float4* s4 = (const float4*)(sg + (size_t)(row & 7) * D_);
    float4 v0 = nz[lane], v1 = nz[64 + lane];
    float4 a0 = m4[lane], a1 = m4[64 + lane];
    float4 c0 = s4[lane], c1 = s4[64 + lane];
    v0.x = fmaf(c0.x, v0.x, a0.x); v0.y = fmaf(c0.y, v0.y, a0.y);
    v0.z = fmaf(c0.z, v0.z, a0.z); v0.w = fmaf(c0.w, v0.w, a0.w);
    v1.x = fmaf(c1.x, v1.x, a1.x); v1.y = fmaf(c1.y, v1.y, a1.y);
    v1.z = fmaf(c1.z, v1.z, a1.z); v1.w = fmaf(c1.w, v1.w, a1.w);
    float4* o4 = (float4*)(slots + (size_t)row * D_);
    o4[lane] = v0; o4[64 + lane] = v1;
    float s1 = v0.x + v0.y + v0.z + v0.w + v1.x + v1.y + v1.z + v1.w;
    float s2 = v0.x*v0.x; s2 = fmaf(v0.y,v0.y,s2); s2 = fmaf(v0.z,v0.z,s2); s2 = fmaf(v0.w,v0.w,s2);
    s2 = fmaf(v1.x,v1.x,s2); s2 = fmaf(v1.y,v1.y,s2); s2 = fmaf(v1.z,v1.z,s2); s2 = fmaf(v1.w,v1.w,s2);
#pragma unroll
    for (int off = 32; off > 0; off >>= 1) {
        s1 += __shfl_xor(s1, off, 64);
        s2 += __shfl_xor(s2, off, 64);
    }
    if (lane == 0) {
        float mean = s1 * (1.0f / D_);
        float var  = s2 * (1.0f / D_) - mean * mean;
        stats[row * 2]     = mean;
        stats[row * 2 + 1] = rsqrtf(var + 1e-5f);
    }
}

// ---------------------------------------------------------------- merged prologue
// blocks [0,128): Mqk = wk^T @ wq ; [128,512): Wiv = w_ih @ wv ; [512,576): slot init
__global__ __launch_bounds__(256) void k_pro(const float* __restrict__ wk, const float* __restrict__ wq,
                                             const float* __restrict__ w_ih, const float* __restrict__ wv,
                                             float* __restrict__ Mqk, float* __restrict__ Wiv,
                                             const float* __restrict__ noise, const float* __restrict__ mu,
                                             const float* __restrict__ sg, float* __restrict__ slots,
                                             float* __restrict__ stats) {
    __shared__ float smem[64 * 68 + 64 * 36];
    int blk = blockIdx.x;
    if (blk < 128) {
        gemm_body<2,0>(wk, wq, nullptr, Mqk, 512, 512, 512, blk & 15, blk >> 4,
                       nullptr, nullptr, nullptr, smem);
    } else if (blk < 512) {
        int t2 = blk - 128;
        gemm_body<0,0>(w_ih, wv, nullptr, Wiv, 1536, 512, 512, t2 & 15, t2 >> 4,
                       nullptr, nullptr, nullptr, smem);
    } else {
        init_body(noise, mu, sg, slots, stats, blk - 512);
    }
}

// ---------------------------------------------------------------- generic small GEMM kernel
template<int WT, int LNA>
__global__ __launch_bounds__(256) void k_gemm(const float* __restrict__ A, const float* __restrict__ W,
                                              const float* __restrict__ bias, float* __restrict__ C,
                                              int M, int N, int K,
                                              const float* __restrict__ stats,
                                              const float* __restrict__ lng, const float* __restrict__ lnb) {
    __shared__ float smem[64 * 68 + 64 * 36];
    gemm_body<WT,LNA>(A, W, bias, C, M, N, K, blockIdx.x, blockIdx.y, stats, lng, lnb, smem);
}

// ---------------------------------------------------------------- fused attention v7 + gh overlay
// blocks [0,96): gh GEMM (short — runs first, fills CUs while attn queues)
// blocks [96,608): attention. __launch_bounds__(512,1) -> 256-VGPR cap, NO SPILLS.
// qts stored with slot^(k4&7) XOR swizzle to kill the 16-way bank conflict on the q reg load.
template<int FIRST>
__global__ __launch_bounds__(512, 1) void k_attn_gh(const float* __restrict__ x,
                                                    const float* __restrict__ qk,
                                                    const float* __restrict__ g,
                                                    const float* __restrict__ bvec,
                                                    float* __restrict__ part,
                                                    float* __restrict__ bsum,
                                                    float2* __restrict__ murs,
                                                    const float* __restrict__ slots,
                                                    const float* __restrict__ w_hh,
                                                    const float* __restrict__ b_hh,
                                                    float* __restrict__ gg) {
    __shared__ float smem[8704];    // 34.8 KB union: attn uses 5424, gh uses 8704
    const int blk = blockIdx.x;
    const int t = threadIdx.x;

    if (blk < 96) {
        // ---------------- gh GEMM overlay: 64x64 tiles, 512 threads
        const int ci = blk % 24, ri = blk / 24;
        const int bm = ri * 64, bn = ci * 64;
        float (*As)[68] = (float (*)[68])smem;
        float (*Ws)[68] = (float (*)[68])(smem + 64 * 68);
        const int tm = t >> 5, tn = t & 31;
        float acc[4][2] = {{0.f,0.f},{0.f,0.f},{0.f,0.f},{0.f,0.f}};
        for (int kk = 0; kk < 512; kk += 64) {
            __syncthreads();
#pragma unroll
            for (int r = 0; r < 2; ++r) {
                int flat = t * 4 + r * 2048;
                int m = flat >> 6, k = flat & 63;
                float4 a4 = *(const float4*)(slots + (size_t)(bm + m) * 512 + kk + k);
                As[k + 0][m] = a4.x; As[k + 1][m] = a4.y;
                As[k + 2][m] = a4.z; As[k + 3][m] = a4.w;
            }
#pragma unroll
            for (int r = 0; r < 2; ++r) {
                int flat = t * 4 + r * 2048;
                int n = flat >> 6, k = flat & 63;
                float4 w4 = *(const float4*)(w_hh + (size_t)(bn + n) * 512 + kk + k);
                Ws[k + 0][n] = w4.x; Ws[k + 1][n] = w4.y;
                Ws[k + 2][n] = w4.z; Ws[k + 3][n] = w4.w;
            }
            __syncthreads();
#pragma unroll
            for (int k = 0; k < 64; ++k) {
                const float4 a = *(const float4*)&As[k][tm << 2];
                const float2 w = *(const float2*)&Ws[k][tn << 1];
                acc[0][0] = fmaf(a.x, w.x, acc[0][0]); acc[0][1] = fmaf(a.x, w.y, acc[0][1]);
                acc[1][0] = fmaf(a.y, w.x, acc[1][0]); acc[1][1] = fmaf(a.y, w.y, acc[1][1]);
                acc[2][0] = fmaf(a.z, w.x, acc[2][0]); acc[2][1] = fmaf(a.z, w.y, acc[2][1]);
                acc[3][0] = fmaf(a.w, w.x, acc[3][0]); acc[3][1] = fmaf(a.w, w.y, acc[3][1]);
            }
        }
#pragma unroll
        for (int i = 0; i < 4; ++i) {
#pragma unroll
            for (int j = 0; j < 2; ++j) {
                int row = bm + (tm << 2) + i;
                int col = bn + (tn << 1) + j;
                gg[(size_t)row * 3072 + col] = acc[i][j] + b_hh[col];
            }
        }
        return;
    }

    // ---------------- attention: LDS layout (floats)
    float* qts  = smem;            // [0,4096)  q-tilde k-major (slot XOR-swizzled); reused as u0s
    float* dds  = smem + 4096;     // [4096,4480)  32 rows x 12 (logits)
    float* wls  = smem + 4480;     // [4480,4864)  32 rows x 12 (weights)
    float* mur  = smem + 4864;     // [4864,5376)  256 rows x {mean,rs}
    float* redA = smem + 5376;     // 16
    float* redB = smem + 5392;     // 16
    float* c12  = smem + 5408;     // 16
    float* u0s  = smem;
    const int ablk = blk - 96;
    const int nc = ablk & 15, b = ablk >> 4;
    const int w = t >> 6, lane = t & 63;
    const size_t rowbase = (size_t)b * N_ + (size_t)nc * 256;

    // ---- q-prep: qts = g .* qk (k-major, slot-swizzled), c1[s], c2[s]
    {
        const float4* qk4 = (const float4*)(qk + (size_t)b * 4096);
        const float4* g4 = (const float4*)g;
        const float4* b4 = (const float4*)bvec;
        float c1p[2], c2p[2];
#pragma unroll
        for (int r = 0; r < 2; ++r) {
            int f = t + r * 512;
            int k4 = f & 127, sidx = f >> 7;
            float4 v = qk4[f];
            float4 gg4 = g4[k4];
            float4 bb = b4[k4];
            float4 qv = make_float4(v.x*gg4.x, v.y*gg4.y, v.z*gg4.z, v.w*gg4.w);
            *(float4*)&qts[(k4 * 8 + (sidx ^ (k4 & 7))) * 4] = qv;
            c1p[r] = qv.x + qv.y + qv.z + qv.w;
            c2p[r] = bb.x*v.x + bb.y*v.y + bb.z*v.z + bb.w*v.w;
        }
#pragma unroll
        for (int off = 32; off > 0; off >>= 1) {
#pragma unroll
            for (int r = 0; r < 2; ++r) {
                c1p[r] += __shfl_xor(c1p[r], off, 64);
                c2p[r] += __shfl_xor(c2p[r], off, 64);
            }
        }
        if (lane == 0) {
            redA[w * 2 + 0] = c1p[0]; redA[w * 2 + 1] = c1p[1];
            redB[w * 2 + 0] = c2p[0]; redB[w * 2 + 1] = c2p[1];
        }
    }
    if (!FIRST && t < 256) {
        float2 mm = murs[rowbase + t];
        mur[2 * t] = mm.x; mur[2 * t + 1] = mm.y;
    }
    __syncthreads();
    if (t < 8) {
        int s = t;
        float v1, v2;
        if (s < 4) { v1 = redA[4*s]       + redA[4*s + 2];     v2 = redB[4*s]       + redB[4*s + 2]; }
        else       { v1 = redA[4*(s-4)+1] + redA[4*(s-4)+3];   v2 = redB[4*(s-4)+1] + redB[4*(s-4)+3]; }
        c12[s] = v1; c12[8 + s] = v2;
    }
    __syncthreads();

    // ---- q into wave-distributed registers (swizzled read: 2-way conflict max)
    float4 qa[8], qb[8];
#pragma unroll
    for (int s = 0; s < 8; ++s) {
        qa[s] = *(const float4*)&qts[(lane * 8 + (s ^ (lane & 7))) * 4];
        qb[s] = *(const float4*)&qts[((64 + lane) * 8 + (s ^ (lane & 7))) * 4];
    }

    const bool hb5 = (lane & 32) != 0, hb4 = (lane & 16) != 0, hb3 = (lane & 8) != 0;
    const float cnorm = 1.0f / (1.0f + 8.0f * 1e-8f);
    const float eadd  = 1e-8f * cnorm;

    float4 acc0[8], acc1[8];
#pragma unroll
    for (int s = 0; s < 8; ++s) {
        acc0[s] = make_float4(0.f, 0.f, 0.f, 0.f);
        acc1[s] = make_float4(0.f, 0.f, 0.f, 0.f);
    }
    float aS8[8] = {0,0,0,0,0,0,0,0}, tS8[8] = {0,0,0,0,0,0,0,0};

    // batches: 8 x (32 rows: 4 per wave). cur regs hold this wave's 4 rows.
    const float4* xg = (const float4*)(x + rowbase * D_);
    float4 cur[8], nxt[8];
    {
        int r0 = w * 4;
#pragma unroll
        for (int i = 0; i < 4; ++i) {
            cur[2*i]   = xg[(size_t)(r0 + i) * 128 + lane];
            cur[2*i+1] = xg[(size_t)(r0 + i) * 128 + 64 + lane];
        }
    }

    for (int jb = 0; jb < 8; ++jb) {
        // ---- loop1: dots + fold for 4 rows; logits -> dds
#pragma unroll
        for (int i = 0; i < 4; ++i) {
            float4 xa = cur[2*i], xb = cur[2*i+1];
            float dd[8];
#pragma unroll
            for (int s = 0; s < 8; ++s) {
                float td = xa.x * qa[s].x;
                td = fmaf(xa.y, qa[s].y, td); td = fmaf(xa.z, qa[s].z, td); td = fmaf(xa.w, qa[s].w, td);
                td = fmaf(xb.x, qb[s].x, td); td = fmaf(xb.y, qb[s].y, td);
                td = fmaf(xb.z, qb[s].z, td); td = fmaf(xb.w, qb[s].w, td);
                dd[s] = td;
            }
            float r4[4];
#pragma unroll
            for (int s = 0; s < 4; ++s) {
                float snd = hb5 ? dd[s] : dd[s + 4];
                float kp  = hb5 ? dd[s + 4] : dd[s];
                r4[s] = kp + __shfl_xor(snd, 32, 64);
            }
            float r2v[2];
#pragma unroll
            for (int s = 0; s < 2; ++s) {
                float snd = hb4 ? r4[s] : r4[s + 2];
                float kp  = hb4 ? r4[s + 2] : r4[s];
                r2v[s] = kp + __shfl_xor(snd, 16, 64);
            }
            float v;
            {
                float snd = hb3 ? r2v[0] : r2v[1];
                float kp  = hb3 ? r2v[1] : r2v[0];
                v = kp + __shfl_xor(snd, 8, 64);
            }
            v += __shfl_xor(v, 4, 64);
            v += __shfl_xor(v, 2, 64);
            v += __shfl_xor(v, 1, 64);
            int rb = w * 4 + i;
            if ((lane & 7) == 0) dds[rb * 12 + (lane >> 3)] = v;

            if (FIRST) {
                float sx = xa.x + xa.y + xa.z + xa.w + xb.x + xb.y + xb.z + xb.w;
                float sxx = xa.x*xa.x; sxx = fmaf(xa.y,xa.y,sxx); sxx = fmaf(xa.z,xa.z,sxx); sxx = fmaf(xa.w,xa.w,sxx);
                sxx = fmaf(xb.x,xb.x,sxx); sxx = fmaf(xb.y,xb.y,sxx); sxx = fmaf(xb.z,xb.z,sxx); sxx = fmaf(xb.w,xb.w,sxx);
#pragma unroll
                for (int off = 32; off > 0; off >>= 1) {
                    sx  += __shfl_xor(sx, off, 64);
                    sxx += __shfl_xor(sxx, off, 64);
                }
                float mean = sx * (1.0f / D_);
                float rs   = rsqrtf(sxx * (1.0f / D_) - mean * mean + 1e-5f);
                if (lane == 0) {
                    int br = jb * 32 + rb;
                    mur[br * 2] = mean; mur[br * 2 + 1] = rs;
                    murs[rowbase + br] = make_float2(mean, rs);
                }
            }
        }
        __syncthreads();
        // ---- loop2: scalar softmax, lane-per-row (wave 0, 32 lanes)
        if (w == 0 && lane < 32) {
            int br = jb * 32 + lane;
            float4 d03 = *(const float4*)&dds[lane * 12];
            float4 d47 = *(const float4*)&dds[lane * 12 + 4];
            float mean = mur[br * 2], rs = mur[br * 2 + 1];
            float mc = -rs * mean;
            float lg[8];
            lg[0] = fmaf(rs, d03.x, fmaf(mc, c12[0], c12[8]));
            lg[1] = fmaf(rs, d03.y, fmaf(mc, c12[1], c12[9]));
            lg[2] = fmaf(rs, d03.z, fmaf(mc, c12[2], c12[10]));
            lg[3] = fmaf(rs, d03.w, fmaf(mc, c12[3], c12[11]));
            lg[4] = fmaf(rs, d47.x, fmaf(mc, c12[4], c12[12]));
            lg[5] = fmaf(rs, d47.y, fmaf(mc, c12[5], c12[13]));
            lg[6] = fmaf(rs, d47.z, fmaf(mc, c12[6], c12[14]));
            lg[7] = fmaf(rs, d47.w, fmaf(mc, c12[7], c12[15]));
            float mx = lg[0];
#pragma unroll
            for (int s = 1; s < 8; ++s) mx = fmaxf(mx, lg[s]);
            float p[8], psum = 0.f;
#pragma unroll
            for (int s = 0; s < 8; ++s) { p[s] = __expf(lg[s] - mx); psum += p[s]; }
            float ip = cnorm / psum;
            float wv[8];
#pragma unroll
            for (int s = 0; s < 8; ++s) {
                float a = fmaf(p[s], ip, eadd);
                wv[s] = a * rs;
                aS8[s] += a;
                tS8[s] = fmaf(wv[s], mean, tS8[s]);
            }
            *(float4*)&wls[lane * 12]     = make_float4(wv[0], wv[1], wv[2], wv[3]);
            *(float4*)&wls[lane * 12 + 4] = make_float4(wv[4], wv[5], wv[6], wv[7]);
        }
        __syncthreads();
        // ---- prefetch next batch while accumulating
        {
            int jn = (jb < 7) ? jb + 1 : 7;
            int r0 = jn * 32 + w * 4;
#pragma unroll
            for (int i = 0; i < 4; ++i) {
                nxt[2*i]   = xg[(size_t)(r0 + i) * 128 + lane];
                nxt[2*i+1] = xg[(size_t)(r0 + i) * 128 + 64 + lane];
            }
        }
        // ---- loop3: P accumulation (x from regs, w via LDS broadcast)
#pragma unroll
        for (int i = 0; i < 4; ++i) {
            int rb = w * 4 + i;
            float4 w03 = *(const float4*)&wls[rb * 12];
            float4 w47 = *(const float4*)&wls[rb * 12 + 4];
            float4 xa = cur[2*i], xb = cur[2*i+1];
            acc0[0].x = fmaf(w03.x, xa.x, acc0[0].x); acc0[0].y = fmaf(w03.x, xa.y, acc0[0].y);
            acc0[0].z = fmaf(w03.x, xa.z, acc0[0].z); acc0[0].w = fmaf(w03.x, xa.w, acc0[0].w);
            acc1[0].x = fmaf(w03.x, xb.x, acc1[0].x); acc1[0].y = fmaf(w03.x, xb.y, acc1[0].y);
            acc1[0].z = fmaf(w03.x, xb.z, acc1[0].z); acc1[0].w = fmaf(w03.x, xb.w, acc1[0].w);
            acc0[1].x = fmaf(w03.y, xa.x, acc0[1].x); acc0[1].y = fmaf(w03.y, xa.y, acc0[1].y);
            acc0[1].z = fmaf(w03.y, xa.z, acc0[1].z); acc0[1].w = fmaf(w03.y, xa.w, acc0[1].w);
            acc1[1].x = fmaf(w03.y, xb.x, acc1[1].x); acc1[1].y = fmaf(w03.y, xb.y, acc1[1].y);
            acc1[1].z = fmaf(w03.y, xb.z, acc1[1].z); acc1[1].w = fmaf(w03.y, xb.w, acc1[1].w);
            acc0[2].x = fmaf(w03.z, xa.x, acc0[2].x); acc0[2].y = fmaf(w03.z, xa.y, acc0[2].y);
            acc0[2].z = fmaf(w03.z, xa.z, acc0[2].z); acc0[2].w = fmaf(w03.z, xa.w, acc0[2].w);
            acc1[2].x = fmaf(w03.z, xb.x, acc1[2].x); acc1[2].y = fmaf(w03.z, xb.y, acc1[2].y);
            acc1[2].z = fmaf(w03.z, xb.z, acc1[2].z); acc1[2].w = fmaf(w03.z, xb.w, acc1[2].w);
            acc0[3].x = fmaf(w03.w, xa.x, acc0[3].x); acc0[3].y = fmaf(w03.w, xa.y, acc0[3].y);
            acc0[3].z = fmaf(w03.w, xa.z, acc0[3].z); acc0[3].w = fmaf(w03.w, xa.w, acc0[3].w);
            acc1[3].x = fmaf(w03.w, xb.x, acc1[3].x); acc1[3].y = fmaf(w03.w, xb.y, acc1[3].y);
            acc1[3].z = fmaf(w03.w, xb.z, acc1[3].z); acc1[3].w = fmaf(w03.w, xb.w, acc1[3].w);
            acc0[4].x = fmaf(w47.x, xa.x, acc0[4].x); acc0[4].y = fmaf(w47.x, xa.y, acc0[4].y);
            acc0[4].z = fmaf(w47.x, xa.z, acc0[4].z); acc0[4].w = fmaf(w47.x, xa.w, acc0[4].w);
            acc1[4].x = fmaf(w47.x, xb.x, acc1[4].x); acc1[4].y = fmaf(w47.x, xb.y, acc1[4].y);
            acc1[4].z = fmaf(w47.x, xb.z, acc1[4].z); acc1[4].w = fmaf(w47.x, xb.w, acc1[4].w);
            acc0[5].x = fmaf(w47.y, xa.x, acc0[5].x); acc0[5].y = fmaf(w47.y, xa.y, acc0[5].y);
            acc0[5].z = fmaf(w47.y, xa.z, acc0[5].z); acc0[5].w = fmaf(w47.y, xa.w, acc0[5].w);
            acc1[5].x = fmaf(w47.y, xb.x, acc1[5].x); acc1[5].y = fmaf(w47.y, xb.y, acc1[5].y);
            acc1[5].z = fmaf(w47.y, xb.z, acc1[5].z); acc1[5].w = fmaf(w47.y, xb.w, acc1[5].w);
            acc0[6].x = fmaf(w47.z, xa.x, acc0[6].x); acc0[6].y = fmaf(w47.z, xa.y, acc0[6].y);
            acc0[6].z = fmaf(w47.z, xa.z, acc0[6].z); acc0[6].w = fmaf(w47.z, xa.w, acc0[6].w);
            acc1[6].x = fmaf(w47.z, xb.x, acc1[6].x); acc1[6].y = fmaf(w47.z, xb.y, acc1[6].y);
            acc1[6].z = fmaf(w47.z, xb.z, acc1[6].z); acc1[6].w = fmaf(w47.z, xb.w, acc1[6].w);
            acc0[7].x = fmaf(w47.w, xa.x, acc0[7].x); acc0[7].y = fmaf(w47.w, xa.y, acc0[7].y);
            acc0[7].z = fmaf(w47.w, xa.z, acc0[7].z); acc0[7].w = fmaf(w47.w, xa.w, acc0[7].w);
            acc1[7].x = fmaf(w47.w, xb.x, acc1[7].x); acc1[7].y = fmaf(w47.w, xb.y, acc1[7].y);
            acc1[7].z = fmaf(w47.w, xb.z, acc1[7].z); acc1[7].w = fmaf(w47.w, xb.w, acc1[7].w);
        }
#pragma unroll
        for (int i = 0; i < 8; ++i) cur[i] = nxt[i];
        __syncthreads();   // wls/dds safe to overwrite next batch
    }

    // ---- bsum: reduce aS8/tS8 within wave 0 and store
    if (w == 0) {
#pragma unroll
        for (int off = 32; off > 0; off >>= 1) {
#pragma unroll
            for (int s = 0; s < 8; ++s) {
                aS8[s] += __shfl_xor(aS8[s], off, 64);
                tS8[s] += __shfl_xor(tS8[s], off, 64);
            }
        }
        if (lane == 0) {
            float* bs = bsum + (size_t)(b * 16 + nc) * 16;
#pragma unroll
            for (int s = 0; s < 8; ++s) { bs[s] = aS8[s]; bs[8 + s] = tS8[s]; }
        }
    }
    // ---- cross-wave P reduction into LDS (overlaps dead qts)
    for (int w2 = 0; w2 < 8; ++w2) {
        if (w == w2) {
#pragma unroll
            for (int s = 0; s < 8; ++s) {
                float* p0 = &u0s[s * 512 + (lane << 2)];
                float* p1 = p0 + 256;
                if (w2 == 0) {
                    *(float4*)p0 = acc0[s];
                    *(float4*)p1 = acc1[s];
                } else {
                    float4 v0 = *(float4*)p0;
                    v0.x += acc0[s].x; v0.y += acc0[s].y; v0.z += acc0[s].z; v0.w += acc0[s].w;
                    *(float4*)p0 = v0;
                    float4 v1 = *(float4*)p1;
                    v1.x += acc1[s].x; v1.y += acc1[s].y; v1.z += acc1[s].z; v1.w += acc1[s].w;
                    *(float4*)p1 = v1;
                }
            }
        }
        __syncthreads();
    }
    float4* d4 = (float4*)(part + (size_t)(b * 16 + nc) * 4096);
    const float4* s4 = (const float4*)u0s;
    d4[t] = s4[t];
    d4[t + 512] = s4[t + 512];
}

// ---------------------------------------------------------------- u0 reduce + affine correction
__global__ __launch_bounds__(512) void k_ured(const float* __restrict__ part,
                                              const float* __restrict__ bsum,
                                              const float* __restrict__ g,
                                              const float* __restrict__ bvec,
                                              float* __restrict__ u0) {
    const int bs = blockIdx.x;          // 0..255
    const int b = bs >> 3, s = bs & 7;
    const int d = threadIdx.x;
    float Av = 0.f, Tv = 0.f;
#pragma unroll
    for (int nc = 0; nc < 16; ++nc) {
        Av += bsum[(size_t)(b * 16 + nc) * 16 + s];
        Tv += bsum[(size_t)(b * 16 + nc) * 16 + 8 + s];
    }
    float p = 0.f;
#pragma unroll
    for (int nc = 0; nc < 16; ++nc)
        p += part[(size_t)(b * 16 + nc) * 4096 + s * 512 + d];
    u0[(size_t)bs * 512 + d] = fmaf(g[d], p - Tv, Av * bvec[d]);
}

// ---------------------------------------------------------------- gi GEMM into gg cols 1536..3071
__global__ __launch_bounds__(256) void k_gi(const float* __restrict__ u0,
                                            const float* __restrict__ Wiv,
                                            const float* __restrict__ b_ih,
                                            float* __restrict__ gg) {
    __shared__ float As[64][68];
    __shared__ float Ws[64][36];
    const int t = threadIdx.x;
    const int bn = blockIdx.x * 32;
    const int bm = blockIdx.y * 64;
    int tm = t >> 4, tn = t & 15;
    float acc[4][2] = {{0.f,0.f},{0.f,0.f},{0.f,0.f},{0.f,0.f}};

    for (int kk = 0; kk < 512; kk += 64) {
        __syncthreads();
#pragma unroll
        for (int r = 0; r < 4; ++r) {
            int flat = t * 4 + r * 1024;
            int m = flat >> 6, k = flat & 63;
            float4 a4 = *(const float4*)(u0 + (size_t)(bm + m) * 512 + kk + k);
            As[k + 0][m] = a4.x; As[k + 1][m] = a4.y;
            As[k + 2][m] = a4.z; As[k + 3][m] = a4.w;
        }
#pragma unroll
        for (int r = 0; r < 2; ++r) {
            int flat = t * 4 + r * 1024;
            int n = flat >> 6, k = flat & 63;
            float4 w4 = *(const float4*)(Wiv + (size_t)(bn + n) * 512 + kk + k);
            Ws[k + 0][n] = w4.x; Ws[k + 1][n] = w4.y;
            Ws[k + 2][n] = w4.z; Ws[k + 3][n] = w4.w;
        }
        __syncthreads();
#pragma unroll
        for (int k = 0; k < 64; ++k) {
            float4 a = *(const float4*)&As[k][tm << 2];
            float2 w = *(const float2*)&Ws[k][tn << 1];
            acc[0][0] = fmaf(a.x, w.x, acc[0][0]); acc[0][1] = fmaf(a.x, w.y, acc[0][1]);
            acc[1][0] = fmaf(a.y, w.x, acc[1][0]); acc[1][1] = fmaf(a.y, w.y, acc[1][1]);
            acc[2][0] = fmaf(a.z, w.x, acc[2][0]); acc[2][1] = fmaf(a.z, w.y, acc[2][1]);
            acc[3][0] = fmaf(a.w, w.x, acc[3][0]); acc[3][1] = fmaf(a.w, w.y, acc[3][1]);
        }
    }
#pragma unroll
    for (int i = 0; i < 4; ++i) {
#pragma unroll
        for (int j = 0; j < 2; ++j) {
            int row = bm + (tm << 2) + i;
            int cw  = bn + (tn << 1) + j;
            gg[(size_t)row * 3072 + 1536 + cw] = acc[i][j] + b_ih[cw];
        }
    }
}

// ---------------------------------------------------------------- P2: GRU + MLP + LN + qk_next
__global__ __launch_bounds__(512) void k_p2(const float* __restrict__ gg,
                                            const float* __restrict__ slots,
                                            const float* __restrict__ w1, const float* __restrict__ b1,
                                            const float* __restrict__ w2, const float* __restrict__ b2,
                                            const float* __restrict__ wqkT,
                                            const float* __restrict__ ln_m_g, const float* __restrict__ ln_m_b,
                                            const float* __restrict__ ln_s_g, const float* __restrict__ ln_s_b,
                                            float* __restrict__ dst, float* __restrict__ qkout, int last) {
    __shared__ float s2s[2][512];
    __shared__ float t0s[2][512];
    __shared__ float hs[2][512];
    __shared__ float stat[4];
    const int t = threadIdx.x;
    const int wid = t >> 6, lane = t & 63;
    const int r0 = blockIdx.x * 2;

#pragma unroll
    for (int j = 0; j < 2; ++j) {
        int flat = t + j * 512;
        int r = flat >> 9, d = flat & 511;
        size_t row = r0 + r;
        const float* ghb = gg + row * 3072;
        const float* gib = ghb + 1536;
        float gir = gib[d], giz = gib[d + 512], gin = gib[d + 1024];
        float ghr = ghb[d], ghz = ghb[d + 512], ghn = ghb[d + 1024];
        float rr = sigmoid_f(gir + ghr);
        float zz = sigmoid_f(giz + ghz);
        float nn = tanh_f(fmaf(rr, ghn, gin));
        float sp = slots[row * 512 + d];
        s2s[r][d] = fmaf(1.0f - zz, nn, zz * sp);
    }
    __syncthreads();
    if (wid < 2) {
        const float4* sr = (const float4*)s2s[wid];
        float4 a = sr[lane], bq = sr[64 + lane];
        float s1 = a.x + a.y + a.z + a.w + bq.x + bq.y + bq.z + bq.w;
        float s2 = a.x*a.x; s2 = fmaf(a.y,a.y,s2); s2 = fmaf(a.z,a.z,s2); s2 = fmaf(a.w,a.w,s2);
        s2 = fmaf(bq.x,bq.x,s2); s2 = fmaf(bq.y,bq.y,s2); s2 = fmaf(bq.z,bq.z,s2); s2 = fmaf(bq.w,bq.w,s2);
#pragma unroll
        for (int off = 32; off > 0; off >>= 1) {
            s1 += __shfl_xor(s1, off, 64);
            s2 += __shfl_xor(s2, off, 64);
        }
        if (lane == 0) {
            float mean = s1 * (1.0f / D_);
            float var  = s2 * (1.0f / D_) - mean * mean;
            stat[wid * 2] = mean;
            stat[wid * 2 + 1] = rsqrtf(var + 1e-5f);
        }
    }
    __syncthreads();
#pragma unroll
    for (int j = 0; j < 2; ++j) {
        int flat = t + j * 512;
        int r = flat >> 9, d = flat & 511;
        t0s[r][d] = fmaf((s2s[r][d] - stat[r * 2]) * stat[r * 2 + 1], ln_m_g[d], ln_m_b[d]);
    }
    __syncthreads();
    {
        const int c = t;
        const float4* wr = (const float4*)(w1 + (size_t)c * 512);
        float a0 = 0.f, a1 = 0.f;
#pragma unroll 8
        for (int k4 = 0; k4 < 128; ++k4) {
            float4 w4 = wr[k4];
            float4 q0 = *(const float4*)&t0s[0][k4 << 2];
            float4 q1 = *(const float4*)&t0s[1][k4 << 2];
            a0 = fmaf(q0.x, w4.x, a0); a0 = fmaf(q0.y, w4.y, a0);
            a0 = fmaf(q0.z, w4.z, a0); a0 = fmaf(q0.w, w4.w, a0);
            a1 = fmaf(q1.x, w4.x, a1); a1 = fmaf(q1.y, w4.y, a1);
            a1 = fmaf(q1.z, w4.z, a1); a1 = fmaf(q1.w, w4.w, a1);
        }
        float bc = b1[c];
        hs[0][c] = fmaxf(a0 + bc, 0.f);
        hs[1][c] = fmaxf(a1 + bc, 0.f);
    }
    __syncthreads();
    {
        const int c = t;
        const float4* wr = (const float4*)(w2 + (size_t)c * 512);
        float a0 = 0.f, a1 = 0.f;
#pragma unroll 8
        for (int k4 = 0; k4 < 128; ++k4) {
            float4 w4 = wr[k4];
            float4 q0 = *(const float4*)&hs[0][k4 << 2];
            float4 q1 = *(const float4*)&hs[1][k4 << 2];
            a0 = fmaf(q0.x, w4.x, a0); a0 = fmaf(q0.y, w4.y, a0);
            a0 = fmaf(q0.z, w4.z, a0); a0 = fmaf(q0.w, w4.w, a0);
            a1 = fmaf(q1.x, w4.x, a1); a1 = fmaf(q1.y, w4.y, a1);
            a1 = fmaf(q1.z, w4.z, a1); a1 = fmaf(q1.w, w4.w, a1);
        }
        float bc = b2[c];
        float o0 = s2s[0][c] + a0 + bc;
        float o1 = s2s[1][c] + a1 + bc;
        dst[(size_t)r0 * 512 + c] = o0;
        dst[(size_t)(r0 + 1) * 512 + c] = o1;
        s2s[0][c] = o0;
        s2s[1][c] = o1;
    }
    if (last) return;
    __syncthreads();
    if (wid < 2) {
        const float4* sr = (const float4*)s2s[wid];
        float4 a = sr[lane], bq = sr[64 + lane];
        float s1 = a.x + a.y + a.z + a.w + bq.x + bq.y + bq.z + bq.w;
        float s2 = a.x*a.x; s2 = fmaf(a.y,a.y,s2); s2 = fmaf(a.z,a.z,s2); s2 = fmaf(a.w,a.w,s2);
        s2 = fmaf(bq.x,bq.x,s2); s2 = fmaf(bq.y,bq.y,s2); s2 = fmaf(bq.z,bq.z,s2); s2 = fmaf(bq.w,bq.w,s2);
#pragma unroll
        for (int off = 32; off > 0; off >>= 1) {
            s1 += __shfl_xor(s1, off, 64);
            s2 += __shfl_xor(s2, off, 64);
        }
        if (lane == 0) {
            float mean = s1 * (1.0f / D_);
            float var  = s2 * (1.0f / D_) - mean * mean;
            stat[wid * 2] = mean;
            stat[wid * 2 + 1] = rsqrtf(var + 1e-5f);
        }
    }
    __syncthreads();
#pragma unroll
    for (int j = 0; j < 2; ++j) {
        int flat = t + j * 512;
        int r = flat >> 9, d = flat & 511;
        t0s[r][d] = fmaf((s2s[r][d] - stat[r * 2]) * stat[r * 2 + 1], ln_s_g[d], ln_s_b[d]);
    }
    __syncthreads();
    {
        const int c = t;
        const float4* wr = (const float4*)(wqkT + (size_t)c * 512);
        float a0 = 0.f, a1 = 0.f;
#pragma unroll 8
        for (int k4 = 0; k4 < 128; ++k4) {
            float4 w4 = wr[k4];
            float4 q0 = *(const float4*)&t0s[0][k4 << 2];
            float4 q1 = *(const float4*)&t0s[1][k4 << 2];
            a0 = fmaf(q0.x, w4.x, a0); a0 = fmaf(q0.y, w4.y, a0);
            a0 = fmaf(q0.z, w4.z, a0); a0 = fmaf(q0.w, w4.w, a0);
            a1 = fmaf(q1.x, w4.x, a1); a1 = fmaf(q1.y, w4.y, a1);
            a1 = fmaf(q1.z, w4.z, a1); a1 = fmaf(q1.w, w4.w, a1);
        }
        qkout[(size_t)r0 * 512 + c] = a0;
        qkout[(size_t)(r0 + 1) * 512 + c] = a1;
    }
}

// ---------------------------------------------------------------- launch
extern "C" void kernel_launch(void* const* d_in, const int* in_sizes, int n_in,
                              void* d_out, int out_size, void* d_ws, size_t ws_size,
                              hipStream_t stream) {
    const float* inputs  = (const float*)d_in[0];
    const float* noise   = (const float*)d_in[1];
    const float* mu      = (const float*)d_in[2];
    const float* sg      = (const float*)d_in[3];
    const float* ln_in_g = (const float*)d_in[4];
    const float* ln_in_b = (const float*)d_in[5];
    const float* ln_s_g  = (const float*)d_in[6];
    const float* ln_s_b  = (const float*)d_in[7];
    const float* wq      = (const float*)d_in[8];
    const float* wk      = (const float*)d_in[9];
    const float* wv      = (const float*)d_in[10];
    const float* w_ih    = (const float*)d_in[11];
    const float* w_hh    = (const float*)d_in[12];
    const float* b_ih    = (const float*)d_in[13];
    const float* b_hh    = (const float*)d_in[14];
    const float* ln_m_g  = (const float*)d_in[15];
    const float* ln_m_b  = (const float*)d_in[16];
    const float* w1      = (const float*)d_in[17];
    const float* b1      = (const float*)d_in[18];
    const float* w2      = (const float*)d_in[19];
    const float* b2      = (const float*)d_in[20];

    float* ws = (float*)d_ws;
    const size_t SLOT = (size_t)B_ * S_ * D_;      // 131072
    size_t o = 0;
    float* slots = ws + o; o += SLOT;
    float* qk    = ws + o; o += SLOT;
    float* u0    = ws + o; o += SLOT;
    float* gg    = ws + o; o += (size_t)256 * 3072;       // 786432
    float* Mqk   = ws + o; o += (size_t)D_ * D_;          // 262144
    float* Wiv   = ws + o; o += (size_t)3 * D_ * D_;      // 786432
    float* statsS= ws + o; o += 512;
    float* part  = ws + o; o += (size_t)16 * B_ * 4096;   // 2097152
    float* bsum  = ws + o; o += (size_t)B_ * 16 * 16;     // 8192
    float2* murs = (float2*)(ws + o); o += (size_t)2 * B_ * N_;   // 262144 floats

    // ---- prologue (2 dispatches)
    k_pro<<<576, 256, 0, stream>>>(wk, wq, w_ih, wv, Mqk, Wiv, noise, mu, sg, slots, statsS);
    k_gemm<1,1><<<dim3(16, 4), 256, 0, stream>>>(slots, Mqk, nullptr, qk,
                                                 256, 512, 512, statsS, ln_s_g, ln_s_b);

    for (int it = 0; it < ITERS_; ++it) {
        if (it == 0)
            k_attn_gh<1><<<608, 512, 0, stream>>>(inputs, qk, ln_in_g, ln_in_b, part, bsum,
                                                  murs, slots, w_hh, b_hh, gg);
        else
            k_attn_gh<0><<<608, 512, 0, stream>>>(inputs, qk, ln_in_g, ln_in_b, part, bsum,
                                                  murs, slots, w_hh, b_hh, gg);
        k_ured<<<256, 512, 0, stream>>>(part, bsum, ln_in_g, ln_in_b, u0);
        k_gi<<<dim3(48, 4), 256, 0, stream>>>(u0, Wiv, b_ih, gg);
        int last = (it == ITERS_ - 1);
        float* dst = last ? (float*)d_out : slots;
        k_p2<<<128, 512, 0, stream>>>(gg, slots, w1, b1, w2, b2, Mqk,
                                      ln_m_g, ln_m_b, ln_s_g, ln_s_b, dst, qk, last);
    }
}

// Round 12
// 664.605 us; speedup vs baseline: 1.3367x; 1.0186x over previous
//
#include <hip/hip_runtime.h>

#define B_ 32
#define N_ 4096
#define D_ 512
#define S_ 8
#define ITERS_ 3

__device__ __forceinline__ float sigmoid_f(float x) {
    return 1.0f / (1.0f + __expf(-x));
}
__device__ __forceinline__ float tanh_f(float x) {
    float e = __expf(2.0f * x);
    return 1.0f - 2.0f / (e + 1.0f);
}

// ---------------------------------------------------------------- shared GEMM tile body
template<int WT, int LNA>
__device__ void gemm_body(const float* __restrict__ A, const float* __restrict__ W,
                          const float* __restrict__ bias, float* __restrict__ C,
                          int M, int N, int K, int bxi, int byi,
                          const float* __restrict__ stats,
                          const float* __restrict__ lng, const float* __restrict__ lnb,
                          float* smem) {
    float (*As)[68] = (float (*)[68])smem;
    float (*Ws)[36] = (float (*)[36])(smem + 64 * 68);
    int t  = threadIdx.x;
    int bm = byi * 64, bn = bxi * 32;
    int tm = t >> 4, tn = t & 15;
    float acc[4][2] = {{0.f,0.f},{0.f,0.f},{0.f,0.f},{0.f,0.f}};

    for (int kk = 0; kk < K; kk += 64) {
        __syncthreads();
        if (WT == 2) {
#pragma unroll
            for (int r = 0; r < 4; ++r) {
                int idx = t + r * 256;
                int k = idx >> 4, m4 = idx & 15;
                float4 a4 = *(const float4*)(A + (size_t)(kk + k) * M + bm + (m4 << 2));
                *(float4*)&As[k][m4 << 2] = a4;
            }
        } else {
#pragma unroll
            for (int r = 0; r < 4; ++r) {
                int flat = t * 4 + r * 1024;
                int m = flat >> 6, k = flat & 63;
                float4 a4 = *(const float4*)(A + (size_t)(bm + m) * K + kk + k);
                if (LNA) {
                    float mean = stats[(bm + m) * 2];
                    float rs   = stats[(bm + m) * 2 + 1];
                    float4 g4 = *(const float4*)(lng + kk + k);
                    float4 b4 = *(const float4*)(lnb + kk + k);
                    a4.x = fmaf((a4.x - mean) * rs, g4.x, b4.x);
                    a4.y = fmaf((a4.y - mean) * rs, g4.y, b4.y);
                    a4.z = fmaf((a4.z - mean) * rs, g4.z, b4.z);
                    a4.w = fmaf((a4.w - mean) * rs, g4.w, b4.w);
                }
                As[k + 0][m] = a4.x; As[k + 1][m] = a4.y;
                As[k + 2][m] = a4.z; As[k + 3][m] = a4.w;
            }
        }
        if (WT == 1) {
#pragma unroll
            for (int r = 0; r < 2; ++r) {
                int flat = t * 4 + r * 1024;
                int n = flat >> 6, k = flat & 63;
                float4 w4 = *(const float4*)(W + (size_t)(bn + n) * K + kk + k);
                Ws[k + 0][n] = w4.x; Ws[k + 1][n] = w4.y;
                Ws[k + 2][n] = w4.z; Ws[k + 3][n] = w4.w;
            }
        } else {
#pragma unroll
            for (int r = 0; r < 2; ++r) {
                int flat = t * 4 + r * 1024;
                int k = flat >> 5, n = flat & 31;
                float4 w4 = *(const float4*)(W + (size_t)(kk + k) * N + bn + n);
                *(float4*)&Ws[k][n] = w4;
            }
        }
        __syncthreads();
#pragma unroll
        for (int k = 0; k < 64; ++k) {
            float4 a = *(const float4*)&As[k][tm << 2];
            float2 w = *(const float2*)&Ws[k][tn << 1];
            acc[0][0] = fmaf(a.x, w.x, acc[0][0]); acc[0][1] = fmaf(a.x, w.y, acc[0][1]);
            acc[1][0] = fmaf(a.y, w.x, acc[1][0]); acc[1][1] = fmaf(a.y, w.y, acc[1][1]);
            acc[2][0] = fmaf(a.z, w.x, acc[2][0]); acc[2][1] = fmaf(a.z, w.y, acc[2][1]);
            acc[3][0] = fmaf(a.w, w.x, acc[3][0]); acc[3][1] = fmaf(a.w, w.y, acc[3][1]);
        }
    }
#pragma unroll
    for (int i = 0; i < 4; ++i) {
#pragma unroll
        for (int j = 0; j < 2; ++j) {
            int row = bm + (tm << 2) + i;
            int col = bn + (tn << 1) + j;
            float v = acc[i][j];
            if (bias) v += bias[col];
            C[(size_t)row * N + col] = v;
        }
    }
}

// ---------------------------------------------------------------- slot init body
__device__ void init_body(const float* __restrict__ noise, const float* __restrict__ mu,
                          const float* __restrict__ sg, float* __restrict__ slots,
                          float* __restrict__ stats, int blk) {
    int wid = threadIdx.x >> 6, lane = threadIdx.x & 63;
    int row = blk * 4 + wid;
    const float4* nz = (const float4*)(noise + (size_t)row * D_);
    const float4* m4 = (const float4*)(mu + (size_t)(row & 7) * D_);
    const float4* s4 = (const float4*)(sg + (size_t)(row & 7) * D_);
    float4 v0 = nz[lane], v1 = nz[64 + lane];
    float4 a0 = m4[lane], a1 = m4[64 + lane];
    float4 c0 = s4[lane], c1 = s4[64 + lane];
    v0.x = fmaf(c0.x, v0.x, a0.x); v0.y = fmaf(c0.y, v0.y, a0.y);
    v0.z = fmaf(c0.z, v0.z, a0.z); v0.w = fmaf(c0.w, v0.w, a0.w);
    v1.x = fmaf(c1.x, v1.x, a1.x); v1.y = fmaf(c1.y, v1.y, a1.y);
    v1.z = fmaf(c1.z, v1.z, a1.z); v1.w = fmaf(c1.w, v1.w, a1.w);
    float4* o4 = (float4*)(slots + (size_t)row * D_);
    o4[lane] = v0; o4[64 + lane] = v1;
    float s1 = v0.x + v0.y + v0.z + v0.w + v1.x + v1.y + v1.z + v1.w;
    float s2 = v0.x*v0.x; s2 = fmaf(v0.y,v0.y,s2); s2 = fmaf(v0.z,v0.z,s2); s2 = fmaf(v0.w,v0.w,s2);
    s2 = fmaf(v1.x,v1.x,s2); s2 = fmaf(v1.y,v1.y,s2); s2 = fmaf(v1.z,v1.z,s2); s2 = fmaf(v1.w,v1.w,s2);
#pragma unroll
    for (int off = 32; off > 0; off >>= 1) {
        s1 += __shfl_xor(s1, off, 64);
        s2 += __shfl_xor(s2, off, 64);
    }
    if (lane == 0) {
        float mean = s1 * (1.0f / D_);
        float var  = s2 * (1.0f / D_) - mean * mean;
        stats[row * 2]     = mean;
        stats[row * 2 + 1] = rsqrtf(var + 1e-5f);
    }
}

// ---------------------------------------------------------------- merged prologue
__global__ __launch_bounds__(256) void k_pro(const float* __restrict__ wk, const float* __restrict__ wq,
                                             const float* __restrict__ w_ih, const float* __restrict__ wv,
                                             float* __restrict__ Mqk, float* __restrict__ Wiv,
                                             const float* __restrict__ noise, const float* __restrict__ mu,
                                             const float* __restrict__ sg, float* __restrict__ slots,
                                             float* __restrict__ stats) {
    __shared__ float smem[64 * 68 + 64 * 36];
    int blk = blockIdx.x;
    if (blk < 128) {
        gemm_body<2,0>(wk, wq, nullptr, Mqk, 512, 512, 512, blk & 15, blk >> 4,
                       nullptr, nullptr, nullptr, smem);
    } else if (blk < 512) {
        int t2 = blk - 128;
        gemm_body<0,0>(w_ih, wv, nullptr, Wiv, 1536, 512, 512, t2 & 15, t2 >> 4,
                       nullptr, nullptr, nullptr, smem);
    } else {
        init_body(noise, mu, sg, slots, stats, blk - 512);
    }
}

// ---------------------------------------------------------------- generic small GEMM kernel
template<int WT, int LNA>
__global__ __launch_bounds__(256) void k_gemm(const float* __restrict__ A, const float* __restrict__ W,
                                              const float* __restrict__ bias, float* __restrict__ C,
                                              int M, int N, int K,
                                              const float* __restrict__ stats,
                                              const float* __restrict__ lng, const float* __restrict__ lnb) {
    __shared__ float smem[64 * 68 + 64 * 36];
    gemm_body<WT,LNA>(A, W, bias, C, M, N, K, blockIdx.x, blockIdx.y, stats, lng, lnb, smem);
}

// ---------------------------------------------------------------- fused attention v8 + gh overlay
// blocks [0,96): gh GEMM. blocks [96,352): attention, 512 rows each, 16 batches.
// Barrier-free main loop: dds/wls are wave-private; softmax on lanes 0-3 of EACH wave
// (wave-coherent LDS). Prefetch issued at batch top (full-batch latency cover).
template<int FIRST>
__global__ __launch_bounds__(512, 1) void k_attn_gh(const float* __restrict__ x,
                                                    const float* __restrict__ qk,
                                                    const float* __restrict__ g,
                                                    const float* __restrict__ bvec,
                                                    float* __restrict__ part,
                                                    float* __restrict__ bsum,
                                                    float2* __restrict__ murs,
                                                    const float* __restrict__ slots,
                                                    const float* __restrict__ w_hh,
                                                    const float* __restrict__ b_hh,
                                                    float* __restrict__ gg) {
    __shared__ float smem[8704];
    const int blk = blockIdx.x;
    const int t = threadIdx.x;

    if (blk < 96) {
        // ---------------- gh GEMM overlay (runs first; short)
        const int ci = blk % 24, ri = blk / 24;
        const int bm = ri * 64, bn = ci * 64;
        float (*As)[68] = (float (*)[68])smem;
        float (*Ws)[68] = (float (*)[68])(smem + 64 * 68);
        const int tm = t >> 5, tn = t & 31;
        float acc[4][2] = {{0.f,0.f},{0.f,0.f},{0.f,0.f},{0.f,0.f}};
        for (int kk = 0; kk < 512; kk += 64) {
            __syncthreads();
#pragma unroll
            for (int r = 0; r < 2; ++r) {
                int flat = t * 4 + r * 2048;
                int m = flat >> 6, k = flat & 63;
                float4 a4 = *(const float4*)(slots + (size_t)(bm + m) * 512 + kk + k);
                As[k + 0][m] = a4.x; As[k + 1][m] = a4.y;
                As[k + 2][m] = a4.z; As[k + 3][m] = a4.w;
            }
#pragma unroll
            for (int r = 0; r < 2; ++r) {
                int flat = t * 4 + r * 2048;
                int n = flat >> 6, k = flat & 63;
                float4 w4 = *(const float4*)(w_hh + (size_t)(bn + n) * 512 + kk + k);
                Ws[k + 0][n] = w4.x; Ws[k + 1][n] = w4.y;
                Ws[k + 2][n] = w4.z; Ws[k + 3][n] = w4.w;
            }
            __syncthreads();
#pragma unroll
            for (int k = 0; k < 64; ++k) {
                const float4 a = *(const float4*)&As[k][tm << 2];
                const float2 w = *(const float2*)&Ws[k][tn << 1];
                acc[0][0] = fmaf(a.x, w.x, acc[0][0]); acc[0][1] = fmaf(a.x, w.y, acc[0][1]);
                acc[1][0] = fmaf(a.y, w.x, acc[1][0]); acc[1][1] = fmaf(a.y, w.y, acc[1][1]);
                acc[2][0] = fmaf(a.z, w.x, acc[2][0]); acc[2][1] = fmaf(a.z, w.y, acc[2][1]);
                acc[3][0] = fmaf(a.w, w.x, acc[3][0]); acc[3][1] = fmaf(a.w, w.y, acc[3][1]);
            }
        }
#pragma unroll
        for (int i = 0; i < 4; ++i) {
#pragma unroll
            for (int j = 0; j < 2; ++j) {
                int row = bm + (tm << 2) + i;
                int col = bn + (tn << 1) + j;
                gg[(size_t)row * 3072 + col] = acc[i][j] + b_hh[col];
            }
        }
        return;
    }

    // ---------------- attention LDS layout
    float* qts  = smem;            // [0,4096) q-tilde (swizzled); reused as u0s
    float* dds  = smem + 4096;     // [4096,4480) 32 rows x 12 logits (wave-private quarters)
    float* wls  = smem + 4480;     // [4480,4864) 32 rows x 12 weights
    float* mur  = smem + 4864;     // [4864,5888) 512 rows x {mean,rs}
    float* redA = smem + 5888;     // 64
    float* redB = smem + 5952;     // 64
    float* c12  = smem + 6016;     // 16
    float* u0s  = smem;
    const int ablk = blk - 96;
    const int nc = ablk & 7, b = ablk >> 3;
    const int w = t >> 6, lane = t & 63;
    const size_t rowbase = (size_t)b * N_ + (size_t)nc * 512;

    // ---- q-prep: qts = g .* qk (k-major, slot-swizzled), c1[s], c2[s]
    {
        const float4* qk4 = (const float4*)(qk + (size_t)b * 4096);
        const float4* g4 = (const float4*)g;
        const float4* b4 = (const float4*)bvec;
        float c1p[2], c2p[2];
#pragma unroll
        for (int r = 0; r < 2; ++r) {
            int f = t + r * 512;
            int k4 = f & 127, sidx = f >> 7;
            float4 v = qk4[f];
            float4 gg4 = g4[k4];
            float4 bb = b4[k4];
            float4 qv = make_float4(v.x*gg4.x, v.y*gg4.y, v.z*gg4.z, v.w*gg4.w);
            *(float4*)&qts[(k4 * 8 + (sidx ^ (k4 & 7))) * 4] = qv;
            c1p[r] = qv.x + qv.y + qv.z + qv.w;
            c2p[r] = bb.x*v.x + bb.y*v.y + bb.z*v.z + bb.w*v.w;
        }
#pragma unroll
        for (int off = 32; off > 0; off >>= 1) {
#pragma unroll
            for (int r = 0; r < 2; ++r) {
                c1p[r] += __shfl_xor(c1p[r], off, 64);
                c2p[r] += __shfl_xor(c2p[r], off, 64);
            }
        }
        if (lane == 0) {
            redA[w * 2 + 0] = c1p[0]; redA[w * 2 + 1] = c1p[1];
            redB[w * 2 + 0] = c2p[0]; redB[w * 2 + 1] = c2p[1];
        }
    }
    if (!FIRST) {
        float2 mm = murs[rowbase + t];
        mur[2 * t] = mm.x; mur[2 * t + 1] = mm.y;
    }
    __syncthreads();
    if (t < 8) {
        int s = t;
        float v1, v2;
        if (s < 4) { v1 = redA[4*s]       + redA[4*s + 2];     v2 = redB[4*s]       + redB[4*s + 2]; }
        else       { v1 = redA[4*(s-4)+1] + redA[4*(s-4)+3];   v2 = redB[4*(s-4)+1] + redB[4*(s-4)+3]; }
        c12[s] = v1; c12[8 + s] = v2;
    }
    __syncthreads();

    // ---- q into wave-distributed registers (swizzled read)
    float4 qa[8], qb[8];
#pragma unroll
    for (int s = 0; s < 8; ++s) {
        qa[s] = *(const float4*)&qts[(lane * 8 + (s ^ (lane & 7))) * 4];
        qb[s] = *(const float4*)&qts[((64 + lane) * 8 + (s ^ (lane & 7))) * 4];
    }

    const bool hb5 = (lane & 32) != 0, hb4 = (lane & 16) != 0, hb3 = (lane & 8) != 0;
    const float cnorm = 1.0f / (1.0f + 8.0f * 1e-8f);
    const float eadd  = 1e-8f * cnorm;

    float4 acc0[8], acc1[8];
#pragma unroll
    for (int s = 0; s < 8; ++s) {
        acc0[s] = make_float4(0.f, 0.f, 0.f, 0.f);
        acc1[s] = make_float4(0.f, 0.f, 0.f, 0.f);
    }
    float aS8[8] = {0,0,0,0,0,0,0,0}, tS8[8] = {0,0,0,0,0,0,0,0};

    // 16 batches x (32 rows: 4 per wave), fully wave-independent
    const float4* xg = (const float4*)(x + rowbase * D_);
    float4 cur[8], nxt[8];
    {
        int r0 = w * 4;
#pragma unroll
        for (int i = 0; i < 4; ++i) {
            cur[2*i]   = xg[(size_t)(r0 + i) * 128 + lane];
            cur[2*i+1] = xg[(size_t)(r0 + i) * 128 + 64 + lane];
        }
    }

    for (int jb = 0; jb < 16; ++jb) {
        // ---- prefetch next batch FIRST (full-batch latency cover)
        {
            int jn = (jb < 15) ? jb + 1 : 15;
            int r0 = jn * 32 + w * 4;
#pragma unroll
            for (int i = 0; i < 4; ++i) {
                nxt[2*i]   = xg[(size_t)(r0 + i) * 128 + lane];
                nxt[2*i+1] = xg[(size_t)(r0 + i) * 128 + 64 + lane];
            }
        }
        // ---- loop1: dots + fold for this wave's 4 rows; logits -> wave-private dds
#pragma unroll
        for (int i = 0; i < 4; ++i) {
            float4 xa = cur[2*i], xb = cur[2*i+1];
            float dd[8];
#pragma unroll
            for (int s = 0; s < 8; ++s) {
                float td = xa.x * qa[s].x;
                td = fmaf(xa.y, qa[s].y, td); td = fmaf(xa.z, qa[s].z, td); td = fmaf(xa.w, qa[s].w, td);
                td = fmaf(xb.x, qb[s].x, td); td = fmaf(xb.y, qb[s].y, td);
                td = fmaf(xb.z, qb[s].z, td); td = fmaf(xb.w, qb[s].w, td);
                dd[s] = td;
            }
            float r4[4];
#pragma unroll
            for (int s = 0; s < 4; ++s) {
                float snd = hb5 ? dd[s] : dd[s + 4];
                float kp  = hb5 ? dd[s + 4] : dd[s];
                r4[s] = kp + __shfl_xor(snd, 32, 64);
            }
            float r2v[2];
#pragma unroll
            for (int s = 0; s < 2; ++s) {
                float snd = hb4 ? r4[s] : r4[s + 2];
                float kp  = hb4 ? r4[s + 2] : r4[s];
                r2v[s] = kp + __shfl_xor(snd, 16, 64);
            }
            float v;
            {
                float snd = hb3 ? r2v[0] : r2v[1];
                float kp  = hb3 ? r2v[1] : r2v[0];
                v = kp + __shfl_xor(snd, 8, 64);
            }
            v += __shfl_xor(v, 4, 64);
            v += __shfl_xor(v, 2, 64);
            v += __shfl_xor(v, 1, 64);
            int rb = w * 4 + i;
            if ((lane & 7) == 0) dds[rb * 12 + (lane >> 3)] = v;

            if (FIRST) {
                float sx = xa.x + xa.y + xa.z + xa.w + xb.x + xb.y + xb.z + xb.w;
                float sxx = xa.x*xa.x; sxx = fmaf(xa.y,xa.y,sxx); sxx = fmaf(xa.z,xa.z,sxx); sxx = fmaf(xa.w,xa.w,sxx);
                sxx = fmaf(xb.x,xb.x,sxx); sxx = fmaf(xb.y,xb.y,sxx); sxx = fmaf(xb.z,xb.z,sxx); sxx = fmaf(xb.w,xb.w,sxx);
#pragma unroll
                for (int off = 32; off > 0; off >>= 1) {
                    sx  += __shfl_xor(sx, off, 64);
                    sxx += __shfl_xor(sxx, off, 64);
                }
                float mean = sx * (1.0f / D_);
                float rs   = rsqrtf(sxx * (1.0f / D_) - mean * mean + 1e-5f);
                if (lane == 0) {
                    int br = jb * 32 + rb;
                    mur[br * 2] = mean; mur[br * 2 + 1] = rs;
                    murs[rowbase + br] = make_float2(mean, rs);
                }
            }
        }
        // ---- loop2: scalar softmax on lanes 0-3 of THIS wave (wave-coherent LDS, no barrier)
        if (lane < 4) {
            int rb = w * 4 + lane;
            int br = jb * 32 + rb;
            float4 d03 = *(const float4*)&dds[rb * 12];
            float4 d47 = *(const float4*)&dds[rb * 12 + 4];
            float mean = mur[br * 2], rs = mur[br * 2 + 1];
            float mc = -rs * mean;
            float lg[8];
            lg[0] = fmaf(rs, d03.x, fmaf(mc, c12[0], c12[8]));
            lg[1] = fmaf(rs, d03.y, fmaf(mc, c12[1], c12[9]));
            lg[2] = fmaf(rs, d03.z, fmaf(mc, c12[2], c12[10]));
            lg[3] = fmaf(rs, d03.w, fmaf(mc, c12[3], c12[11]));
            lg[4] = fmaf(rs, d47.x, fmaf(mc, c12[4], c12[12]));
            lg[5] = fmaf(rs, d47.y, fmaf(mc, c12[5], c12[13]));
            lg[6] = fmaf(rs, d47.z, fmaf(mc, c12[6], c12[14]));
            lg[7] = fmaf(rs, d47.w, fmaf(mc, c12[7], c12[15]));
            float mx = lg[0];
#pragma unroll
            for (int s = 1; s < 8; ++s) mx = fmaxf(mx, lg[s]);
            float p[8], psum = 0.f;
#pragma unroll
            for (int s = 0; s < 8; ++s) { p[s] = __expf(lg[s] - mx); psum += p[s]; }
            float ip = cnorm / psum;
            float wv[8];
#pragma unroll
            for (int s = 0; s < 8; ++s) {
                float a = fmaf(p[s], ip, eadd);
                wv[s] = a * rs;
                aS8[s] += a;
                tS8[s] = fmaf(wv[s], mean, tS8[s]);
            }
            *(float4*)&wls[rb * 12]     = make_float4(wv[0], wv[1], wv[2], wv[3]);
            *(float4*)&wls[rb * 12 + 4] = make_float4(wv[4], wv[5], wv[6], wv[7]);
        }
        // ---- loop3: P accumulation (x from regs, w via wave-private LDS broadcast)
#pragma unroll
        for (int i = 0; i < 4; ++i) {
            int rb = w * 4 + i;
            float4 w03 = *(const float4*)&wls[rb * 12];
            float4 w47 = *(const float4*)&wls[rb * 12 + 4];
            float4 xa = cur[2*i], xb = cur[2*i+1];
            acc0[0].x = fmaf(w03.x, xa.x, acc0[0].x); acc0[0].y = fmaf(w03.x, xa.y, acc0[0].y);
            acc0[0].z = fmaf(w03.x, xa.z, acc0[0].z); acc0[0].w = fmaf(w03.x, xa.w, acc0[0].w);
            acc1[0].x = fmaf(w03.x, xb.x, acc1[0].x); acc1[0].y = fmaf(w03.x, xb.y, acc1[0].y);
            acc1[0].z = fmaf(w03.x, xb.z, acc1[0].z); acc1[0].w = fmaf(w03.x, xb.w, acc1[0].w);
            acc0[1].x = fmaf(w03.y, xa.x, acc0[1].x); acc0[1].y = fmaf(w03.y, xa.y, acc0[1].y);
            acc0[1].z = fmaf(w03.y, xa.z, acc0[1].z); acc0[1].w = fmaf(w03.y, xa.w, acc0[1].w);
            acc1[1].x = fmaf(w03.y, xb.x, acc1[1].x); acc1[1].y = fmaf(w03.y, xb.y, acc1[1].y);
            acc1[1].z = fmaf(w03.y, xb.z, acc1[1].z); acc1[1].w = fmaf(w03.y, xb.w, acc1[1].w);
            acc0[2].x = fmaf(w03.z, xa.x, acc0[2].x); acc0[2].y = fmaf(w03.z, xa.y, acc0[2].y);
            acc0[2].z = fmaf(w03.z, xa.z, acc0[2].z); acc0[2].w = fmaf(w03.z, xa.w, acc0[2].w);
            acc1[2].x = fmaf(w03.z, xb.x, acc1[2].x); acc1[2].y = fmaf(w03.z, xb.y, acc1[2].y);
            acc1[2].z = fmaf(w03.z, xb.z, acc1[2].z); acc1[2].w = fmaf(w03.z, xb.w, acc1[2].w);
            acc0[3].x = fmaf(w03.w, xa.x, acc0[3].x); acc0[3].y = fmaf(w03.w, xa.y, acc0[3].y);
            acc0[3].z = fmaf(w03.w, xa.z, acc0[3].z); acc0[3].w = fmaf(w03.w, xa.w, acc0[3].w);
            acc1[3].x = fmaf(w03.w, xb.x, acc1[3].x); acc1[3].y = fmaf(w03.w, xb.y, acc1[3].y);
            acc1[3].z = fmaf(w03.w, xb.z, acc1[3].z); acc1[3].w = fmaf(w03.w, xb.w, acc1[3].w);
            acc0[4].x = fmaf(w47.x, xa.x, acc0[4].x); acc0[4].y = fmaf(w47.x, xa.y, acc0[4].y);
            acc0[4].z = fmaf(w47.x, xa.z, acc0[4].z); acc0[4].w = fmaf(w47.x, xa.w, acc0[4].w);
            acc1[4].x = fmaf(w47.x, xb.x, acc1[4].x); acc1[4].y = fmaf(w47.x, xb.y, acc1[4].y);
            acc1[4].z = fmaf(w47.x, xb.z, acc1[4].z); acc1[4].w = fmaf(w47.x, xb.w, acc1[4].w);
            acc0[5].x = fmaf(w47.y, xa.x, acc0[5].x); acc0[5].y = fmaf(w47.y, xa.y, acc0[5].y);
            acc0[5].z = fmaf(w47.y, xa.z, acc0[5].z); acc0[5].w = fmaf(w47.y, xa.w, acc0[5].w);
            acc1[5].x = fmaf(w47.y, xb.x, acc1[5].x); acc1[5].y = fmaf(w47.y, xb.y, acc1[5].y);
            acc1[5].z = fmaf(w47.y, xb.z, acc1[5].z); acc1[5].w = fmaf(w47.y, xb.w, acc1[5].w);
            acc0[6].x = fmaf(w47.z, xa.x, acc0[6].x); acc0[6].y = fmaf(w47.z, xa.y, acc0[6].y);
            acc0[6].z = fmaf(w47.z, xa.z, acc0[6].z); acc0[6].w = fmaf(w47.z, xa.w, acc0[6].w);
            acc1[6].x = fmaf(w47.z, xb.x, acc1[6].x); acc1[6].y = fmaf(w47.z, xb.y, acc1[6].y);
            acc1[6].z = fmaf(w47.z, xb.z, acc1[6].z); acc1[6].w = fmaf(w47.z, xb.w, acc1[6].w);
            acc0[7].x = fmaf(w47.w, xa.x, acc0[7].x); acc0[7].y = fmaf(w47.w, xa.y, acc0[7].y);
            acc0[7].z = fmaf(w47.w, xa.z, acc0[7].z); acc0[7].w = fmaf(w47.w, xa.w, acc0[7].w);
            acc1[7].x = fmaf(w47.w, xb.x, acc1[7].x); acc1[7].y = fmaf(w47.w, xb.y, acc1[7].y);
            acc1[7].z = fmaf(w47.w, xb.z, acc1[7].z); acc1[7].w = fmaf(w47.w, xb.w, acc1[7].w);
        }
#pragma unroll
        for (int i = 0; i < 8; ++i) cur[i] = nxt[i];
    }

    // ---- per-wave Av/Tv: lanes 0-3 hold partials; reduce to lane 0, stash in redA/redB
#pragma unroll
    for (int s = 0; s < 8; ++s) {
        aS8[s] += __shfl_xor(aS8[s], 1, 64);
        aS8[s] += __shfl_xor(aS8[s], 2, 64);
        tS8[s] += __shfl_xor(tS8[s], 1, 64);
        tS8[s] += __shfl_xor(tS8[s], 2, 64);
    }
    if (lane == 0) {
#pragma unroll
        for (int s = 0; s < 8; ++s) { redA[w * 8 + s] = aS8[s]; redB[w * 8 + s] = tS8[s]; }
    }
    // ---- cross-wave P reduction into LDS (u0s overlays dead qts)
    for (int w2 = 0; w2 < 8; ++w2) {
        if (w == w2) {
#pragma unroll
            for (int s = 0; s < 8; ++s) {
                float* p0 = &u0s[s * 512 + (lane << 2)];
                float* p1 = p0 + 256;
                if (w2 == 0) {
                    *(float4*)p0 = acc0[s];
                    *(float4*)p1 = acc1[s];
                } else {
                    float4 v0 = *(float4*)p0;
                    v0.x += acc0[s].x; v0.y += acc0[s].y; v0.z += acc0[s].z; v0.w += acc0[s].w;
                    *(float4*)p0 = v0;
                    float4 v1 = *(float4*)p1;
                    v1.x += acc1[s].x; v1.y += acc1[s].y; v1.z += acc1[s].z; v1.w += acc1[s].w;
                    *(float4*)p1 = v1;
                }
            }
        }
        __syncthreads();
    }
    if (t < 16) {
        int s = t & 7;
        const float* src = (t < 8) ? redA : redB;
        float v = 0.f;
#pragma unroll
        for (int w2 = 0; w2 < 8; ++w2) v += src[w2 * 8 + s];
        bsum[(size_t)(b * 8 + nc) * 16 + t] = v;
    }
    float4* d4 = (float4*)(part + (size_t)(b * 8 + nc) * 4096);
    const float4* s4 = (const float4*)u0s;
    d4[t] = s4[t];
    d4[t + 512] = s4[t + 512];
}

// ---------------------------------------------------------------- u0 reduce + affine correction
__global__ __launch_bounds__(512) void k_ured(const float* __restrict__ part,
                                              const float* __restrict__ bsum,
                                              const float* __restrict__ g,
                                              const float* __restrict__ bvec,
                                              float* __restrict__ u0) {
    const int bs = blockIdx.x;          // 0..255
    const int b = bs >> 3, s = bs & 7;
    const int d = threadIdx.x;
    float Av = 0.f, Tv = 0.f;
#pragma unroll
    for (int nc = 0; nc < 8; ++nc) {
        Av += bsum[(size_t)(b * 8 + nc) * 16 + s];
        Tv += bsum[(size_t)(b * 8 + nc) * 16 + 8 + s];
    }
    float p = 0.f;
#pragma unroll
    for (int nc = 0; nc < 8; ++nc)
        p += part[(size_t)(b * 8 + nc) * 4096 + s * 512 + d];
    u0[(size_t)bs * 512 + d] = fmaf(g[d], p - Tv, Av * bvec[d]);
}

// ---------------------------------------------------------------- gi GEMM into gg cols 1536..3071
__global__ __launch_bounds__(256) void k_gi(const float* __restrict__ u0,
                                            const float* __restrict__ Wiv,
                                            const float* __restrict__ b_ih,
                                            float* __restrict__ gg) {
    __shared__ float As[64][68];
    __shared__ float Ws[64][36];
    const int t = threadIdx.x;
    const int bn = blockIdx.x * 32;
    const int bm = blockIdx.y * 64;
    int tm = t >> 4, tn = t & 15;
    float acc[4][2] = {{0.f,0.f},{0.f,0.f},{0.f,0.f},{0.f,0.f}};

    for (int kk = 0; kk < 512; kk += 64) {
        __syncthreads();
#pragma unroll
        for (int r = 0; r < 4; ++r) {
            int flat = t * 4 + r * 1024;
            int m = flat >> 6, k = flat & 63;
            float4 a4 = *(const float4*)(u0 + (size_t)(bm + m) * 512 + kk + k);
            As[k + 0][m] = a4.x; As[k + 1][m] = a4.y;
            As[k + 2][m] = a4.z; As[k + 3][m] = a4.w;
        }
#pragma unroll
        for (int r = 0; r < 2; ++r) {
            int flat = t * 4 + r * 1024;
            int n = flat >> 6, k = flat & 63;
            float4 w4 = *(const float4*)(Wiv + (size_t)(bn + n) * 512 + kk + k);
            Ws[k + 0][n] = w4.x; Ws[k + 1][n] = w4.y;
            Ws[k + 2][n] = w4.z; Ws[k + 3][n] = w4.w;
        }
        __syncthreads();
#pragma unroll
        for (int k = 0; k < 64; ++k) {
            float4 a = *(const float4*)&As[k][tm << 2];
            float2 w = *(const float2*)&Ws[k][tn << 1];
            acc[0][0] = fmaf(a.x, w.x, acc[0][0]); acc[0][1] = fmaf(a.x, w.y, acc[0][1]);
            acc[1][0] = fmaf(a.y, w.x, acc[1][0]); acc[1][1] = fmaf(a.y, w.y, acc[1][1]);
            acc[2][0] = fmaf(a.z, w.x, acc[2][0]); acc[2][1] = fmaf(a.z, w.y, acc[2][1]);
            acc[3][0] = fmaf(a.w, w.x, acc[3][0]); acc[3][1] = fmaf(a.w, w.y, acc[3][1]);
        }
    }
#pragma unroll
    for (int i = 0; i < 4; ++i) {
#pragma unroll
        for (int j = 0; j < 2; ++j) {
            int row = bm + (tm << 2) + i;
            int cw  = bn + (tn << 1) + j;
            gg[(size_t)row * 3072 + 1536 + cw] = acc[i][j] + b_ih[cw];
        }
    }
}

// ---------------------------------------------------------------- P2: GRU + MLP + LN + qk_next
__global__ __launch_bounds__(512) void k_p2(const float* __restrict__ gg,
                                            const float* __restrict__ slots,
                                            const float* __restrict__ w1, const float* __restrict__ b1,
                                            const float* __restrict__ w2, const float* __restrict__ b2,
                                            const float* __restrict__ wqkT,
                                            const float* __restrict__ ln_m_g, const float* __restrict__ ln_m_b,
                                            const float* __restrict__ ln_s_g, const float* __restrict__ ln_s_b,
                                            float* __restrict__ dst, float* __restrict__ qkout, int last) {
    __shared__ float s2s[2][512];
    __shared__ float t0s[2][512];
    __shared__ float hs[2][512];
    __shared__ float stat[4];
    const int t = threadIdx.x;
    const int wid = t >> 6, lane = t & 63;
    const int r0 = blockIdx.x * 2;

#pragma unroll
    for (int j = 0; j < 2; ++j) {
        int flat = t + j * 512;
        int r = flat >> 9, d = flat & 511;
        size_t row = r0 + r;
        const float* ghb = gg + row * 3072;
        const float* gib = ghb + 1536;
        float gir = gib[d], giz = gib[d + 512], gin = gib[d + 1024];
        float ghr = ghb[d], ghz = ghb[d + 512], ghn = ghb[d + 1024];
        float rr = sigmoid_f(gir + ghr);
        float zz = sigmoid_f(giz + ghz);
        float nn = tanh_f(fmaf(rr, ghn, gin));
        float sp = slots[row * 512 + d];
        s2s[r][d] = fmaf(1.0f - zz, nn, zz * sp);
    }
    __syncthreads();
    if (wid < 2) {
        const float4* sr = (const float4*)s2s[wid];
        float4 a = sr[lane], bq = sr[64 + lane];
        float s1 = a.x + a.y + a.z + a.w + bq.x + bq.y + bq.z + bq.w;
        float s2 = a.x*a.x; s2 = fmaf(a.y,a.y,s2); s2 = fmaf(a.z,a.z,s2); s2 = fmaf(a.w,a.w,s2);
        s2 = fmaf(bq.x,bq.x,s2); s2 = fmaf(bq.y,bq.y,s2); s2 = fmaf(bq.z,bq.z,s2); s2 = fmaf(bq.w,bq.w,s2);
#pragma unroll
        for (int off = 32; off > 0; off >>= 1) {
            s1 += __shfl_xor(s1, off, 64);
            s2 += __shfl_xor(s2, off, 64);
        }
        if (lane == 0) {
            float mean = s1 * (1.0f / D_);
            float var  = s2 * (1.0f / D_) - mean * mean;
            stat[wid * 2] = mean;
            stat[wid * 2 + 1] = rsqrtf(var + 1e-5f);
        }
    }
    __syncthreads();
#pragma unroll
    for (int j = 0; j < 2; ++j) {
        int flat = t + j * 512;
        int r = flat >> 9, d = flat & 511;
        t0s[r][d] = fmaf((s2s[r][d] - stat[r * 2]) * stat[r * 2 + 1], ln_m_g[d], ln_m_b[d]);
    }
    __syncthreads();
    {
        const int c = t;
        const float4* wr = (const float4*)(w1 + (size_t)c * 512);
        float a0 = 0.f, a1 = 0.f;
#pragma unroll 8
        for (int k4 = 0; k4 < 128; ++k4) {
            float4 w4 = wr[k4];
            float4 q0 = *(const float4*)&t0s[0][k4 << 2];
            float4 q1 = *(const float4*)&t0s[1][k4 << 2];
            a0 = fmaf(q0.x, w4.x, a0); a0 = fmaf(q0.y, w4.y, a0);
            a0 = fmaf(q0.z, w4.z, a0); a0 = fmaf(q0.w, w4.w, a0);
            a1 = fmaf(q1.x, w4.x, a1); a1 = fmaf(q1.y, w4.y, a1);
            a1 = fmaf(q1.z, w4.z, a1); a1 = fmaf(q1.w, w4.w, a1);
        }
        float bc = b1[c];
        hs[0][c] = fmaxf(a0 + bc, 0.f);
        hs[1][c] = fmaxf(a1 + bc, 0.f);
    }
    __syncthreads();
    {
        const int c = t;
        const float4* wr = (const float4*)(w2 + (size_t)c * 512);
        float a0 = 0.f, a1 = 0.f;
#pragma unroll 8
        for (int k4 = 0; k4 < 128; ++k4) {
            float4 w4 = wr[k4];
            float4 q0 = *(const float4*)&hs[0][k4 << 2];
            float4 q1 = *(const float4*)&hs[1][k4 << 2];
            a0 = fmaf(q0.x, w4.x, a0); a0 = fmaf(q0.y, w4.y, a0);
            a0 = fmaf(q0.z, w4.z, a0); a0 = fmaf(q0.w, w4.w, a0);
            a1 = fmaf(q1.x, w4.x, a1); a1 = fmaf(q1.y, w4.y, a1);
            a1 = fmaf(q1.z, w4.z, a1); a1 = fmaf(q1.w, w4.w, a1);
        }
        float bc = b2[c];
        float o0 = s2s[0][c] + a0 + bc;
        float o1 = s2s[1][c] + a1 + bc;
        dst[(size_t)r0 * 512 + c] = o0;
        dst[(size_t)(r0 + 1) * 512 + c] = o1;
        s2s[0][c] = o0;
        s2s[1][c] = o1;
    }
    if (last) return;
    __syncthreads();
    if (wid < 2) {
        const float4* sr = (const float4*)s2s[wid];
        float4 a = sr[lane], bq = sr[64 + lane];
        float s1 = a.x + a.y + a.z + a.w + bq.x + bq.y + bq.z + bq.w;
        float s2 = a.x*a.x; s2 = fmaf(a.y,a.y,s2); s2 = fmaf(a.z,a.z,s2); s2 = fmaf(a.w,a.w,s2);
        s2 = fmaf(bq.x,bq.x,s2); s2 = fmaf(bq.y,bq.y,s2); s2 = fmaf(bq.z,bq.z,s2); s2 = fmaf(bq.w,bq.w,s2);
#pragma unroll
        for (int off = 32; off > 0; off >>= 1) {
            s1 += __shfl_xor(s1, off, 64);
            s2 += __shfl_xor(s2, off, 64);
        }
        if (lane == 0) {
            float mean = s1 * (1.0f / D_);
            float var  = s2 * (1.0f / D_) - mean * mean;
            stat[wid * 2] = mean;
            stat[wid * 2 + 1] = rsqrtf(var + 1e-5f);
        }
    }
    __syncthreads();
#pragma unroll
    for (int j = 0; j < 2; ++j) {
        int flat = t + j * 512;
        int r = flat >> 9, d = flat & 511;
        t0s[r][d] = fmaf((s2s[r][d] - stat[r * 2]) * stat[r * 2 + 1], ln_s_g[d], ln_s_b[d]);
    }
    __syncthreads();
    {
        const int c = t;
        const float4* wr = (const float4*)(wqkT + (size_t)c * 512);
        float a0 = 0.f, a1 = 0.f;
#pragma unroll 8
        for (int k4 = 0; k4 < 128; ++k4) {
            float4 w4 = wr[k4];
            float4 q0 = *(const float4*)&t0s[0][k4 << 2];
            float4 q1 = *(const float4*)&t0s[1][k4 << 2];
            a0 = fmaf(q0.x, w4.x, a0); a0 = fmaf(q0.y, w4.y, a0);
            a0 = fmaf(q0.z, w4.z, a0); a0 = fmaf(q0.w, w4.w, a0);
            a1 = fmaf(q1.x, w4.x, a1); a1 = fmaf(q1.y, w4.y, a1);
            a1 = fmaf(q1.z, w4.z, a1); a1 = fmaf(q1.w, w4.w, a1);
        }
        qkout[(size_t)r0 * 512 + c] = a0;
        qkout[(size_t)(r0 + 1) * 512 + c] = a1;
    }
}

// ---------------------------------------------------------------- launch
extern "C" void kernel_launch(void* const* d_in, const int* in_sizes, int n_in,
                              void* d_out, int out_size, void* d_ws, size_t ws_size,
                              hipStream_t stream) {
    const float* inputs  = (const float*)d_in[0];
    const float* noise   = (const float*)d_in[1];
    const float* mu      = (const float*)d_in[2];
    const float* sg      = (const float*)d_in[3];
    const float* ln_in_g = (const float*)d_in[4];
    const float* ln_in_b = (const float*)d_in[5];
    const float* ln_s_g  = (const float*)d_in[6];
    const float* ln_s_b  = (const float*)d_in[7];
    const float* wq      = (const float*)d_in[8];
    const float* wk      = (const float*)d_in[9];
    const float* wv      = (const float*)d_in[10];
    const float* w_ih    = (const float*)d_in[11];
    const float* w_hh    = (const float*)d_in[12];
    const float* b_ih    = (const float*)d_in[13];
    const float* b_hh    = (const float*)d_in[14];
    const float* ln_m_g  = (const float*)d_in[15];
    const float* ln_m_b  = (const float*)d_in[16];
    const float* w1      = (const float*)d_in[17];
    const float* b1      = (const float*)d_in[18];
    const float* w2      = (const float*)d_in[19];
    const float* b2      = (const float*)d_in[20];

    float* ws = (float*)d_ws;
    const size_t SLOT = (size_t)B_ * S_ * D_;      // 131072
    size_t o = 0;
    float* slots = ws + o; o += SLOT;
    float* qk    = ws + o; o += SLOT;
    float* u0    = ws + o; o += SLOT;
    float* gg    = ws + o; o += (size_t)256 * 3072;       // 786432
    float* Mqk   = ws + o; o += (size_t)D_ * D_;          // 262144
    float* Wiv   = ws + o; o += (size_t)3 * D_ * D_;      // 786432
    float* statsS= ws + o; o += 512;
    float* part  = ws + o; o += (size_t)8 * B_ * 4096;    // 1048576
    float* bsum  = ws + o; o += (size_t)B_ * 8 * 16;      // 4096
    float2* murs = (float2*)(ws + o); o += (size_t)2 * B_ * N_;   // 262144 floats

    // ---- prologue (2 dispatches)
    k_pro<<<576, 256, 0, stream>>>(wk, wq, w_ih, wv, Mqk, Wiv, noise, mu, sg, slots, statsS);
    k_gemm<1,1><<<dim3(16, 4), 256, 0, stream>>>(slots, Mqk, nullptr, qk,
                                                 256, 512, 512, statsS, ln_s_g, ln_s_b);

    for (int it = 0; it < ITERS_; ++it) {
        if (it == 0)
            k_attn_gh<1><<<352, 512, 0, stream>>>(inputs, qk, ln_in_g, ln_in_b, part, bsum,
                                                  murs, slots, w_hh, b_hh, gg);
        else
            k_attn_gh<0><<<352, 512, 0, stream>>>(inputs, qk, ln_in_g, ln_in_b, part, bsum,
                                                  murs, slots, w_hh, b_hh, gg);
        k_ured<<<256, 512, 0, stream>>>(part, bsum, ln_in_g, ln_in_b, u0);
        k_gi<<<dim3(48, 4), 256, 0, stream>>>(u0, Wiv, b_ih, gg);
        int last = (it == ITERS_ - 1);
        float* dst = last ? (float*)d_out : slots;
        k_p2<<<128, 512, 0, stream>>>(gg, slots, w1, b1, w2, b2, Mqk,
                                      ln_m_g, ln_m_b, ln_s_g, ln_s_b, dst, qk, last);
    }
}

// Round 13
// 661.930 us; speedup vs baseline: 1.3421x; 1.0040x over previous
//
#include <hip/hip_runtime.h>

#define B_ 32
#define N_ 4096
#define D_ 512
#define S_ 8
#define ITERS_ 3

__device__ __forceinline__ float sigmoid_f(float x) {
    return 1.0f / (1.0f + __expf(-x));
}
__device__ __forceinline__ float tanh_f(float x) {
    float e = __expf(2.0f * x);
    return 1.0f - 2.0f / (e + 1.0f);
}

// ---------------------------------------------------------------- shared GEMM tile body
template<int WT, int LNA>
__device__ void gemm_body(const float* __restrict__ A, const float* __restrict__ W,
                          const float* __restrict__ bias, float* __restrict__ C,
                          int M, int N, int K, int bxi, int byi,
                          const float* __restrict__ stats,
                          const float* __restrict__ lng, const float* __restrict__ lnb,
                          float* smem) {
    float (*As)[68] = (float (*)[68])smem;
    float (*Ws)[36] = (float (*)[36])(smem + 64 * 68);
    int t  = threadIdx.x;
    int bm = byi * 64, bn = bxi * 32;
    int tm = t >> 4, tn = t & 15;
    float acc[4][2] = {{0.f,0.f},{0.f,0.f},{0.f,0.f},{0.f,0.f}};

    for (int kk = 0; kk < K; kk += 64) {
        __syncthreads();
        if (WT == 2) {
#pragma unroll
            for (int r = 0; r < 4; ++r) {
                int idx = t + r * 256;
                int k = idx >> 4, m4 = idx & 15;
                float4 a4 = *(const float4*)(A + (size_t)(kk + k) * M + bm + (m4 << 2));
                *(float4*)&As[k][m4 << 2] = a4;
            }
        } else {
#pragma unroll
            for (int r = 0; r < 4; ++r) {
                int flat = t * 4 + r * 1024;
                int m = flat >> 6, k = flat & 63;
                float4 a4 = *(const float4*)(A + (size_t)(bm + m) * K + kk + k);
                if (LNA) {
                    float mean = stats[(bm + m) * 2];
                    float rs   = stats[(bm + m) * 2 + 1];
                    float4 g4 = *(const float4*)(lng + kk + k);
                    float4 b4 = *(const float4*)(lnb + kk + k);
                    a4.x = fmaf((a4.x - mean) * rs, g4.x, b4.x);
                    a4.y = fmaf((a4.y - mean) * rs, g4.y, b4.y);
                    a4.z = fmaf((a4.z - mean) * rs, g4.z, b4.z);
                    a4.w = fmaf((a4.w - mean) * rs, g4.w, b4.w);
                }
                As[k + 0][m] = a4.x; As[k + 1][m] = a4.y;
                As[k + 2][m] = a4.z; As[k + 3][m] = a4.w;
            }
        }
        if (WT == 1) {
#pragma unroll
            for (int r = 0; r < 2; ++r) {
                int flat = t * 4 + r * 1024;
                int n = flat >> 6, k = flat & 63;
                float4 w4 = *(const float4*)(W + (size_t)(bn + n) * K + kk + k);
                Ws[k + 0][n] = w4.x; Ws[k + 1][n] = w4.y;
                Ws[k + 2][n] = w4.z; Ws[k + 3][n] = w4.w;
            }
        } else {
#pragma unroll
            for (int r = 0; r < 2; ++r) {
                int flat = t * 4 + r * 1024;
                int k = flat >> 5, n = flat & 31;
                float4 w4 = *(const float4*)(W + (size_t)(kk + k) * N + bn + n);
                *(float4*)&Ws[k][n] = w4;
            }
        }
        __syncthreads();
#pragma unroll
        for (int k = 0; k < 64; ++k) {
            float4 a = *(const float4*)&As[k][tm << 2];
            float2 w = *(const float2*)&Ws[k][tn << 1];
            acc[0][0] = fmaf(a.x, w.x, acc[0][0]); acc[0][1] = fmaf(a.x, w.y, acc[0][1]);
            acc[1][0] = fmaf(a.y, w.x, acc[1][0]); acc[1][1] = fmaf(a.y, w.y, acc[1][1]);
            acc[2][0] = fmaf(a.z, w.x, acc[2][0]); acc[2][1] = fmaf(a.z, w.y, acc[2][1]);
            acc[3][0] = fmaf(a.w, w.x, acc[3][0]); acc[3][1] = fmaf(a.w, w.y, acc[3][1]);
        }
    }
#pragma unroll
    for (int i = 0; i < 4; ++i) {
#pragma unroll
        for (int j = 0; j < 2; ++j) {
            int row = bm + (tm << 2) + i;
            int col = bn + (tn << 1) + j;
            float v = acc[i][j];
            if (bias) v += bias[col];
            C[(size_t)row * N + col] = v;
        }
    }
}

// ---------------------------------------------------------------- slot init body
__device__ void init_body(const float* __restrict__ noise, const float* __restrict__ mu,
                          const float* __restrict__ sg, float* __restrict__ slots,
                          float* __restrict__ stats, int blk) {
    int wid = threadIdx.x >> 6, lane = threadIdx.x & 63;
    int row = blk * 4 + wid;
    const float4* nz = (const float4*)(noise + (size_t)row * D_);
    const float4* m4 = (const float4*)(mu + (size_t)(row & 7) * D_);
    const float4* s4 = (const float4*)(sg + (size_t)(row & 7) * D_);
    float4 v0 = nz[lane], v1 = nz[64 + lane];
    float4 a0 = m4[lane], a1 = m4[64 + lane];
    float4 c0 = s4[lane], c1 = s4[64 + lane];
    v0.x = fmaf(c0.x, v0.x, a0.x); v0.y = fmaf(c0.y, v0.y, a0.y);
    v0.z = fmaf(c0.z, v0.z, a0.z); v0.w = fmaf(c0.w, v0.w, a0.w);
    v1.x = fmaf(c1.x, v1.x, a1.x); v1.y = fmaf(c1.y, v1.y, a1.y);
    v1.z = fmaf(c1.z, v1.z, a1.z); v1.w = fmaf(c1.w, v1.w, a1.w);
    float4* o4 = (float4*)(slots + (size_t)row * D_);
    o4[lane] = v0; o4[64 + lane] = v1;
    float s1 = v0.x + v0.y + v0.z + v0.w + v1.x + v1.y + v1.z + v1.w;
    float s2 = v0.x*v0.x; s2 = fmaf(v0.y,v0.y,s2); s2 = fmaf(v0.z,v0.z,s2); s2 = fmaf(v0.w,v0.w,s2);
    s2 = fmaf(v1.x,v1.x,s2); s2 = fmaf(v1.y,v1.y,s2); s2 = fmaf(v1.z,v1.z,s2); s2 = fmaf(v1.w,v1.w,s2);
#pragma unroll
    for (int off = 32; off > 0; off >>= 1) {
        s1 += __shfl_xor(s1, off, 64);
        s2 += __shfl_xor(s2, off, 64);
    }
    if (lane == 0) {
        float mean = s1 * (1.0f / D_);
        float var  = s2 * (1.0f / D_) - mean * mean;
        stats[row * 2]     = mean;
        stats[row * 2 + 1] = rsqrtf(var + 1e-5f);
    }
}

// ---------------------------------------------------------------- merged prologue
__global__ __launch_bounds__(256) void k_pro(const float* __restrict__ wk, const float* __restrict__ wq,
                                             const float* __restrict__ w_ih, const float* __restrict__ wv,
                                             float* __restrict__ Mqk, float* __restrict__ Wiv,
                                             const float* __restrict__ noise, const float* __restrict__ mu,
                                             const float* __restrict__ sg, float* __restrict__ slots,
                                             float* __restrict__ stats) {
    __shared__ float smem[64 * 68 + 64 * 36];
    int blk = blockIdx.x;
    if (blk < 128) {
        gemm_body<2,0>(wk, wq, nullptr, Mqk, 512, 512, 512, blk & 15, blk >> 4,
                       nullptr, nullptr, nullptr, smem);
    } else if (blk < 512) {
        int t2 = blk - 128;
        gemm_body<0,0>(w_ih, wv, nullptr, Wiv, 1536, 512, 512, t2 & 15, t2 >> 4,
                       nullptr, nullptr, nullptr, smem);
    } else {
        init_body(noise, mu, sg, slots, stats, blk - 512);
    }
}

// ---------------------------------------------------------------- generic small GEMM kernel
template<int WT, int LNA>
__global__ __launch_bounds__(256) void k_gemm(const float* __restrict__ A, const float* __restrict__ W,
                                              const float* __restrict__ bias, float* __restrict__ C,
                                              int M, int N, int K,
                                              const float* __restrict__ stats,
                                              const float* __restrict__ lng, const float* __restrict__ lnb) {
    __shared__ float smem[64 * 68 + 64 * 36];
    gemm_body<WT,LNA>(A, W, bias, C, M, N, K, blockIdx.x, blockIdx.y, stats, lng, lnb, smem);
}

// ---------------------------------------------------------------- fused attention v9 + gh prelude
// EXACTLY 256 blocks (1/CU, single occupancy round). Every block runs one 512-row
// attention chunk; blocks 0..95 additionally run one 64x64 gh tile FIRST (~12us).
template<int FIRST>
__global__ __launch_bounds__(512, 1) void k_attn_gh(const float* __restrict__ x,
                                                    const float* __restrict__ qk,
                                                    const float* __restrict__ g,
                                                    const float* __restrict__ bvec,
                                                    float* __restrict__ part,
                                                    float* __restrict__ bsum,
                                                    float2* __restrict__ murs,
                                                    const float* __restrict__ slots,
                                                    const float* __restrict__ w_hh,
                                                    const float* __restrict__ b_hh,
                                                    float* __restrict__ gg) {
    __shared__ float smem[8704];
    const int blk = blockIdx.x;
    const int t = threadIdx.x;

    if (blk < 96) {
        // ---------------- gh GEMM prelude: 64x64 tile, 512 threads
        const int ci = blk % 24, ri = blk / 24;
        const int bm = ri * 64, bn = ci * 64;
        float (*As)[68] = (float (*)[68])smem;
        float (*Ws)[68] = (float (*)[68])(smem + 64 * 68);
        const int tm = t >> 5, tn = t & 31;
        float acc[4][2] = {{0.f,0.f},{0.f,0.f},{0.f,0.f},{0.f,0.f}};
        for (int kk = 0; kk < 512; kk += 64) {
            __syncthreads();
#pragma unroll
            for (int r = 0; r < 2; ++r) {
                int flat = t * 4 + r * 2048;
                int m = flat >> 6, k = flat & 63;
                float4 a4 = *(const float4*)(slots + (size_t)(bm + m) * 512 + kk + k);
                As[k + 0][m] = a4.x; As[k + 1][m] = a4.y;
                As[k + 2][m] = a4.z; As[k + 3][m] = a4.w;
            }
#pragma unroll
            for (int r = 0; r < 2; ++r) {
                int flat = t * 4 + r * 2048;
                int n = flat >> 6, k = flat & 63;
                float4 w4 = *(const float4*)(w_hh + (size_t)(bn + n) * 512 + kk + k);
                Ws[k + 0][n] = w4.x; Ws[k + 1][n] = w4.y;
                Ws[k + 2][n] = w4.z; Ws[k + 3][n] = w4.w;
            }
            __syncthreads();
#pragma unroll
            for (int k = 0; k < 64; ++k) {
                const float4 a = *(const float4*)&As[k][tm << 2];
                const float2 w = *(const float2*)&Ws[k][tn << 1];
                acc[0][0] = fmaf(a.x, w.x, acc[0][0]); acc[0][1] = fmaf(a.x, w.y, acc[0][1]);
                acc[1][0] = fmaf(a.y, w.x, acc[1][0]); acc[1][1] = fmaf(a.y, w.y, acc[1][1]);
                acc[2][0] = fmaf(a.z, w.x, acc[2][0]); acc[2][1] = fmaf(a.z, w.y, acc[2][1]);
                acc[3][0] = fmaf(a.w, w.x, acc[3][0]); acc[3][1] = fmaf(a.w, w.y, acc[3][1]);
            }
        }
#pragma unroll
        for (int i = 0; i < 4; ++i) {
#pragma unroll
            for (int j = 0; j < 2; ++j) {
                int row = bm + (tm << 2) + i;
                int col = bn + (tn << 1) + j;
                gg[(size_t)row * 3072 + col] = acc[i][j] + b_hh[col];
            }
        }
        __syncthreads();   // smem reused by attention below
    }

    // ---------------- attention (ALL 256 blocks)
    float* qts  = smem;            // [0,4096) q-tilde (swizzled); reused as u0s
    float* dds  = smem + 4096;     // 32 rows x 12 logits (wave-private quarters)
    float* wls  = smem + 4480;     // 32 rows x 12 weights
    float* mur  = smem + 4864;     // 512 rows x {mean,rs}
    float* redA = smem + 5888;     // 64
    float* redB = smem + 5952;     // 64
    float* c12  = smem + 6016;     // 16
    float* u0s  = smem;
    const int nc = blk & 7, b = blk >> 3;
    const int w = t >> 6, lane = t & 63;
    const size_t rowbase = (size_t)b * N_ + (size_t)nc * 512;

    // ---- q-prep
    {
        const float4* qk4 = (const float4*)(qk + (size_t)b * 4096);
        const float4* g4 = (const float4*)g;
        const float4* b4 = (const float4*)bvec;
        float c1p[2], c2p[2];
#pragma unroll
        for (int r = 0; r < 2; ++r) {
            int f = t + r * 512;
            int k4 = f & 127, sidx = f >> 7;
            float4 v = qk4[f];
            float4 gg4 = g4[k4];
            float4 bb = b4[k4];
            float4 qv = make_float4(v.x*gg4.x, v.y*gg4.y, v.z*gg4.z, v.w*gg4.w);
            *(float4*)&qts[(k4 * 8 + (sidx ^ (k4 & 7))) * 4] = qv;
            c1p[r] = qv.x + qv.y + qv.z + qv.w;
            c2p[r] = bb.x*v.x + bb.y*v.y + bb.z*v.z + bb.w*v.w;
        }
#pragma unroll
        for (int off = 32; off > 0; off >>= 1) {
#pragma unroll
            for (int r = 0; r < 2; ++r) {
                c1p[r] += __shfl_xor(c1p[r], off, 64);
                c2p[r] += __shfl_xor(c2p[r], off, 64);
            }
        }
        if (lane == 0) {
            redA[w * 2 + 0] = c1p[0]; redA[w * 2 + 1] = c1p[1];
            redB[w * 2 + 0] = c2p[0]; redB[w * 2 + 1] = c2p[1];
        }
    }
    if (!FIRST) {
        float2 mm = murs[rowbase + t];
        mur[2 * t] = mm.x; mur[2 * t + 1] = mm.y;
    }
    __syncthreads();
    if (t < 8) {
        int s = t;
        float v1, v2;
        if (s < 4) { v1 = redA[4*s]       + redA[4*s + 2];     v2 = redB[4*s]       + redB[4*s + 2]; }
        else       { v1 = redA[4*(s-4)+1] + redA[4*(s-4)+3];   v2 = redB[4*(s-4)+1] + redB[4*(s-4)+3]; }
        c12[s] = v1; c12[8 + s] = v2;
    }
    __syncthreads();

    float4 qa[8], qb[8];
#pragma unroll
    for (int s = 0; s < 8; ++s) {
        qa[s] = *(const float4*)&qts[(lane * 8 + (s ^ (lane & 7))) * 4];
        qb[s] = *(const float4*)&qts[((64 + lane) * 8 + (s ^ (lane & 7))) * 4];
    }

    const bool hb5 = (lane & 32) != 0, hb4 = (lane & 16) != 0, hb3 = (lane & 8) != 0;
    const float cnorm = 1.0f / (1.0f + 8.0f * 1e-8f);
    const float eadd  = 1e-8f * cnorm;

    float4 acc0[8], acc1[8];
#pragma unroll
    for (int s = 0; s < 8; ++s) {
        acc0[s] = make_float4(0.f, 0.f, 0.f, 0.f);
        acc1[s] = make_float4(0.f, 0.f, 0.f, 0.f);
    }
    float aS8[8] = {0,0,0,0,0,0,0,0}, tS8[8] = {0,0,0,0,0,0,0,0};

    const float4* xg = (const float4*)(x + rowbase * D_);
    float4 cur[8], nxt[8];
    {
        int r0 = w * 4;
#pragma unroll
        for (int i = 0; i < 4; ++i) {
            cur[2*i]   = xg[(size_t)(r0 + i) * 128 + lane];
            cur[2*i+1] = xg[(size_t)(r0 + i) * 128 + 64 + lane];
        }
    }

    for (int jb = 0; jb < 16; ++jb) {
        {
            int jn = (jb < 15) ? jb + 1 : 15;
            int r0 = jn * 32 + w * 4;
#pragma unroll
            for (int i = 0; i < 4; ++i) {
                nxt[2*i]   = xg[(size_t)(r0 + i) * 128 + lane];
                nxt[2*i+1] = xg[(size_t)(r0 + i) * 128 + 64 + lane];
            }
        }
#pragma unroll
        for (int i = 0; i < 4; ++i) {
            float4 xa = cur[2*i], xb = cur[2*i+1];
            float dd[8];
#pragma unroll
            for (int s = 0; s < 8; ++s) {
                float td = xa.x * qa[s].x;
                td = fmaf(xa.y, qa[s].y, td); td = fmaf(xa.z, qa[s].z, td); td = fmaf(xa.w, qa[s].w, td);
                td = fmaf(xb.x, qb[s].x, td); td = fmaf(xb.y, qb[s].y, td);
                td = fmaf(xb.z, qb[s].z, td); td = fmaf(xb.w, qb[s].w, td);
                dd[s] = td;
            }
            float r4[4];
#pragma unroll
            for (int s = 0; s < 4; ++s) {
                float snd = hb5 ? dd[s] : dd[s + 4];
                float kp  = hb5 ? dd[s + 4] : dd[s];
                r4[s] = kp + __shfl_xor(snd, 32, 64);
            }
            float r2v[2];
#pragma unroll
            for (int s = 0; s < 2; ++s) {
                float snd = hb4 ? r4[s] : r4[s + 2];
                float kp  = hb4 ? r4[s + 2] : r4[s];
                r2v[s] = kp + __shfl_xor(snd, 16, 64);
            }
            float v;
            {
                float snd = hb3 ? r2v[0] : r2v[1];
                float kp  = hb3 ? r2v[1] : r2v[0];
                v = kp + __shfl_xor(snd, 8, 64);
            }
            v += __shfl_xor(v, 4, 64);
            v += __shfl_xor(v, 2, 64);
            v += __shfl_xor(v, 1, 64);
            int rb = w * 4 + i;
            if ((lane & 7) == 0) dds[rb * 12 + (lane >> 3)] = v;

            if (FIRST) {
                float sx = xa.x + xa.y + xa.z + xa.w + xb.x + xb.y + xb.z + xb.w;
                float sxx = xa.x*xa.x; sxx = fmaf(xa.y,xa.y,sxx); sxx = fmaf(xa.z,xa.z,sxx); sxx = fmaf(xa.w,xa.w,sxx);
                sxx = fmaf(xb.x,xb.x,sxx); sxx = fmaf(xb.y,xb.y,sxx); sxx = fmaf(xb.z,xb.z,sxx); sxx = fmaf(xb.w,xb.w,sxx);
#pragma unroll
                for (int off = 32; off > 0; off >>= 1) {
                    sx  += __shfl_xor(sx, off, 64);
                    sxx += __shfl_xor(sxx, off, 64);
                }
                float mean = sx * (1.0f / D_);
                float rs   = rsqrtf(sxx * (1.0f / D_) - mean * mean + 1e-5f);
                if (lane == 0) {
                    int br = jb * 32 + rb;
                    mur[br * 2] = mean; mur[br * 2 + 1] = rs;
                    murs[rowbase + br] = make_float2(mean, rs);
                }
            }
        }
        if (lane < 4) {
            int rb = w * 4 + lane;
            int br = jb * 32 + rb;
            float4 d03 = *(const float4*)&dds[rb * 12];
            float4 d47 = *(const float4*)&dds[rb * 12 + 4];
            float mean = mur[br * 2], rs = mur[br * 2 + 1];
            float mc = -rs * mean;
            float lg[8];
            lg[0] = fmaf(rs, d03.x, fmaf(mc, c12[0], c12[8]));
            lg[1] = fmaf(rs, d03.y, fmaf(mc, c12[1], c12[9]));
            lg[2] = fmaf(rs, d03.z, fmaf(mc, c12[2], c12[10]));
            lg[3] = fmaf(rs, d03.w, fmaf(mc, c12[3], c12[11]));
            lg[4] = fmaf(rs, d47.x, fmaf(mc, c12[4], c12[12]));
            lg[5] = fmaf(rs, d47.y, fmaf(mc, c12[5], c12[13]));
            lg[6] = fmaf(rs, d47.z, fmaf(mc, c12[6], c12[14]));
            lg[7] = fmaf(rs, d47.w, fmaf(mc, c12[7], c12[15]));
            float mx = lg[0];
#pragma unroll
            for (int s = 1; s < 8; ++s) mx = fmaxf(mx, lg[s]);
            float p[8], psum = 0.f;
#pragma unroll
            for (int s = 0; s < 8; ++s) { p[s] = __expf(lg[s] - mx); psum += p[s]; }
            float ip = cnorm / psum;
            float wv[8];
#pragma unroll
            for (int s = 0; s < 8; ++s) {
                float a = fmaf(p[s], ip, eadd);
                wv[s] = a * rs;
                aS8[s] += a;
                tS8[s] = fmaf(wv[s], mean, tS8[s]);
            }
            *(float4*)&wls[rb * 12]     = make_float4(wv[0], wv[1], wv[2], wv[3]);
            *(float4*)&wls[rb * 12 + 4] = make_float4(wv[4], wv[5], wv[6], wv[7]);
        }
#pragma unroll
        for (int i = 0; i < 4; ++i) {
            int rb = w * 4 + i;
            float4 w03 = *(const float4*)&wls[rb * 12];
            float4 w47 = *(const float4*)&wls[rb * 12 + 4];
            float4 xa = cur[2*i], xb = cur[2*i+1];
            acc0[0].x = fmaf(w03.x, xa.x, acc0[0].x); acc0[0].y = fmaf(w03.x, xa.y, acc0[0].y);
            acc0[0].z = fmaf(w03.x, xa.z, acc0[0].z); acc0[0].w = fmaf(w03.x, xa.w, acc0[0].w);
            acc1[0].x = fmaf(w03.x, xb.x, acc1[0].x); acc1[0].y = fmaf(w03.x, xb.y, acc1[0].y);
            acc1[0].z = fmaf(w03.x, xb.z, acc1[0].z); acc1[0].w = fmaf(w03.x, xb.w, acc1[0].w);
            acc0[1].x = fmaf(w03.y, xa.x, acc0[1].x); acc0[1].y = fmaf(w03.y, xa.y, acc0[1].y);
            acc0[1].z = fmaf(w03.y, xa.z, acc0[1].z); acc0[1].w = fmaf(w03.y, xa.w, acc0[1].w);
            acc1[1].x = fmaf(w03.y, xb.x, acc1[1].x); acc1[1].y = fmaf(w03.y, xb.y, acc1[1].y);
            acc1[1].z = fmaf(w03.y, xb.z, acc1[1].z); acc1[1].w = fmaf(w03.y, xb.w, acc1[1].w);
            acc0[2].x = fmaf(w03.z, xa.x, acc0[2].x); acc0[2].y = fmaf(w03.z, xa.y, acc0[2].y);
            acc0[2].z = fmaf(w03.z, xa.z, acc0[2].z); acc0[2].w = fmaf(w03.z, xa.w, acc0[2].w);
            acc1[2].x = fmaf(w03.z, xb.x, acc1[2].x); acc1[2].y = fmaf(w03.z, xb.y, acc1[2].y);
            acc1[2].z = fmaf(w03.z, xb.z, acc1[2].z); acc1[2].w = fmaf(w03.z, xb.w, acc1[2].w);
            acc0[3].x = fmaf(w03.w, xa.x, acc0[3].x); acc0[3].y = fmaf(w03.w, xa.y, acc0[3].y);
            acc0[3].z = fmaf(w03.w, xa.z, acc0[3].z); acc0[3].w = fmaf(w03.w, xa.w, acc0[3].w);
            acc1[3].x = fmaf(w03.w, xb.x, acc1[3].x); acc1[3].y = fmaf(w03.w, xb.y, acc1[3].y);
            acc1[3].z = fmaf(w03.w, xb.z, acc1[3].z); acc1[3].w = fmaf(w03.w, xb.w, acc1[3].w);
            acc0[4].x = fmaf(w47.x, xa.x, acc0[4].x); acc0[4].y = fmaf(w47.x, xa.y, acc0[4].y);
            acc0[4].z = fmaf(w47.x, xa.z, acc0[4].z); acc0[4].w = fmaf(w47.x, xa.w, acc0[4].w);
            acc1[4].x = fmaf(w47.x, xb.x, acc1[4].x); acc1[4].y = fmaf(w47.x, xb.y, acc1[4].y);
            acc1[4].z = fmaf(w47.x, xb.z, acc1[4].z); acc1[4].w = fmaf(w47.x, xb.w, acc1[4].w);
            acc0[5].x = fmaf(w47.y, xa.x, acc0[5].x); acc0[5].y = fmaf(w47.y, xa.y, acc0[5].y);
            acc0[5].z = fmaf(w47.y, xa.z, acc0[5].z); acc0[5].w = fmaf(w47.y, xa.w, acc0[5].w);
            acc1[5].x = fmaf(w47.y, xb.x, acc1[5].x); acc1[5].y = fmaf(w47.y, xb.y, acc1[5].y);
            acc1[5].z = fmaf(w47.y, xb.z, acc1[5].z); acc1[5].w = fmaf(w47.y, xb.w, acc1[5].w);
            acc0[6].x = fmaf(w47.z, xa.x, acc0[6].x); acc0[6].y = fmaf(w47.z, xa.y, acc0[6].y);
            acc0[6].z = fmaf(w47.z, xa.z, acc0[6].z); acc0[6].w = fmaf(w47.z, xa.w, acc0[6].w);
            acc1[6].x = fmaf(w47.z, xb.x, acc1[6].x); acc1[6].y = fmaf(w47.z, xb.y, acc1[6].y);
            acc1[6].z = fmaf(w47.z, xb.z, acc1[6].z); acc1[6].w = fmaf(w47.z, xb.w, acc1[6].w);
            acc0[7].x = fmaf(w47.w, xa.x, acc0[7].x); acc0[7].y = fmaf(w47.w, xa.y, acc0[7].y);
            acc0[7].z = fmaf(w47.w, xa.z, acc0[7].z); acc0[7].w = fmaf(w47.w, xa.w, acc0[7].w);
            acc1[7].x = fmaf(w47.w, xb.x, acc1[7].x); acc1[7].y = fmaf(w47.w, xb.y, acc1[7].y);
            acc1[7].z = fmaf(w47.w, xb.z, acc1[7].z); acc1[7].w = fmaf(w47.w, xb.w, acc1[7].w);
        }
#pragma unroll
        for (int i = 0; i < 8; ++i) cur[i] = nxt[i];
    }

#pragma unroll
    for (int s = 0; s < 8; ++s) {
        aS8[s] += __shfl_xor(aS8[s], 1, 64);
        aS8[s] += __shfl_xor(aS8[s], 2, 64);
        tS8[s] += __shfl_xor(tS8[s], 1, 64);
        tS8[s] += __shfl_xor(tS8[s], 2, 64);
    }
    if (lane == 0) {
#pragma unroll
        for (int s = 0; s < 8; ++s) { redA[w * 8 + s] = aS8[s]; redB[w * 8 + s] = tS8[s]; }
    }
    for (int w2 = 0; w2 < 8; ++w2) {
        if (w == w2) {
#pragma unroll
            for (int s = 0; s < 8; ++s) {
                float* p0 = &u0s[s * 512 + (lane << 2)];
                float* p1 = p0 + 256;
                if (w2 == 0) {
                    *(float4*)p0 = acc0[s];
                    *(float4*)p1 = acc1[s];
                } else {
                    float4 v0 = *(float4*)p0;
                    v0.x += acc0[s].x; v0.y += acc0[s].y; v0.z += acc0[s].z; v0.w += acc0[s].w;
                    *(float4*)p0 = v0;
                    float4 v1 = *(float4*)p1;
                    v1.x += acc1[s].x; v1.y += acc1[s].y; v1.z += acc1[s].z; v1.w += acc1[s].w;
                    *(float4*)p1 = v1;
                }
            }
        }
        __syncthreads();
    }
    if (t < 16) {
        int s = t & 7;
        const float* src = (t < 8) ? redA : redB;
        float v = 0.f;
#pragma unroll
        for (int w2 = 0; w2 < 8; ++w2) v += src[w2 * 8 + s];
        bsum[(size_t)(b * 8 + nc) * 16 + t] = v;
    }
    float4* d4 = (float4*)(part + (size_t)(b * 8 + nc) * 4096);
    const float4* s4 = (const float4*)u0s;
    d4[t] = s4[t];
    d4[t + 512] = s4[t + 512];
}

// ---------------------------------------------------------------- u0 reduce + affine correction
__global__ __launch_bounds__(512) void k_ured(const float* __restrict__ part,
                                              const float* __restrict__ bsum,
                                              const float* __restrict__ g,
                                              const float* __restrict__ bvec,
                                              float* __restrict__ u0) {
    const int bs = blockIdx.x;
    const int b = bs >> 3, s = bs & 7;
    const int d = threadIdx.x;
    float Av = 0.f, Tv = 0.f;
#pragma unroll
    for (int nc = 0; nc < 8; ++nc) {
        Av += bsum[(size_t)(b * 8 + nc) * 16 + s];
        Tv += bsum[(size_t)(b * 8 + nc) * 16 + 8 + s];
    }
    float p = 0.f;
#pragma unroll
    for (int nc = 0; nc < 8; ++nc)
        p += part[(size_t)(b * 8 + nc) * 4096 + s * 512 + d];
    u0[(size_t)bs * 512 + d] = fmaf(g[d], p - Tv, Av * bvec[d]);
}

// ---------------------------------------------------------------- gi GEMM into gg cols 1536..3071
__global__ __launch_bounds__(256) void k_gi(const float* __restrict__ u0,
                                            const float* __restrict__ Wiv,
                                            const float* __restrict__ b_ih,
                                            float* __restrict__ gg) {
    __shared__ float As[64][68];
    __shared__ float Ws[64][36];
    const int t = threadIdx.x;
    const int bn = blockIdx.x * 32;
    const int bm = blockIdx.y * 64;
    int tm = t >> 4, tn = t & 15;
    float acc[4][2] = {{0.f,0.f},{0.f,0.f},{0.f,0.f},{0.f,0.f}};

    for (int kk = 0; kk < 512; kk += 64) {
        __syncthreads();
#pragma unroll
        for (int r = 0; r < 4; ++r) {
            int flat = t * 4 + r * 1024;
            int m = flat >> 6, k = flat & 63;
            float4 a4 = *(const float4*)(u0 + (size_t)(bm + m) * 512 + kk + k);
            As[k + 0][m] = a4.x; As[k + 1][m] = a4.y;
            As[k + 2][m] = a4.z; As[k + 3][m] = a4.w;
        }
#pragma unroll
        for (int r = 0; r < 2; ++r) {
            int flat = t * 4 + r * 1024;
            int n = flat >> 6, k = flat & 63;
            float4 w4 = *(const float4*)(Wiv + (size_t)(bn + n) * 512 + kk + k);
            Ws[k + 0][n] = w4.x; Ws[k + 1][n] = w4.y;
            Ws[k + 2][n] = w4.z; Ws[k + 3][n] = w4.w;
        }
        __syncthreads();
#pragma unroll
        for (int k = 0; k < 64; ++k) {
            float4 a = *(const float4*)&As[k][tm << 2];
            float2 w = *(const float2*)&Ws[k][tn << 1];
            acc[0][0] = fmaf(a.x, w.x, acc[0][0]); acc[0][1] = fmaf(a.x, w.y, acc[0][1]);
            acc[1][0] = fmaf(a.y, w.x, acc[1][0]); acc[1][1] = fmaf(a.y, w.y, acc[1][1]);
            acc[2][0] = fmaf(a.z, w.x, acc[2][0]); acc[2][1] = fmaf(a.z, w.y, acc[2][1]);
            acc[3][0] = fmaf(a.w, w.x, acc[3][0]); acc[3][1] = fmaf(a.w, w.y, acc[3][1]);
        }
    }
#pragma unroll
    for (int i = 0; i < 4; ++i) {
#pragma unroll
        for (int j = 0; j < 2; ++j) {
            int row = bm + (tm << 2) + i;
            int cw  = bn + (tn << 1) + j;
            gg[(size_t)row * 3072 + 1536 + cw] = acc[i][j] + b_ih[cw];
        }
    }
}

// ---------------------------------------------------------------- P2: GRU + MLP + LN + qk_next
// one block per slot row (256 blocks, 512 threads)
__global__ __launch_bounds__(512) void k_p2(const float* __restrict__ gg,
                                            const float* __restrict__ slots,
                                            const float* __restrict__ w1, const float* __restrict__ b1,
                                            const float* __restrict__ w2, const float* __restrict__ b2,
                                            const float* __restrict__ wqkT,
                                            const float* __restrict__ ln_m_g, const float* __restrict__ ln_m_b,
                                            const float* __restrict__ ln_s_g, const float* __restrict__ ln_s_b,
                                            float* __restrict__ dst, float* __restrict__ qkout, int last) {
    __shared__ float s2[512];
    __shared__ float t0[512];
    __shared__ float hh[512];
    __shared__ float red[16];
    __shared__ float stat[2];
    const int t = threadIdx.x;
    const int w = t >> 6, lane = t & 63;
    const size_t row = blockIdx.x;

    // ---- GRU elementwise
    float s2v;
    {
        const float* ghb = gg + row * 3072;
        const float* gib = ghb + 1536;
        float gir = gib[t], giz = gib[t + 512], gin = gib[t + 1024];
        float ghr = ghb[t], ghz = ghb[t + 512], ghn = ghb[t + 1024];
        float rr = sigmoid_f(gir + ghr);
        float zz = sigmoid_f(giz + ghz);
        float nn = tanh_f(fmaf(rr, ghn, gin));
        float sp = slots[row * 512 + t];
        s2v = fmaf(1.0f - zz, nn, zz * sp);
        s2[t] = s2v;
    }
    // ---- block stats of s2
    {
        float s1 = s2v, sq = s2v * s2v;
#pragma unroll
        for (int off = 32; off > 0; off >>= 1) {
            s1 += __shfl_xor(s1, off, 64);
            sq += __shfl_xor(sq, off, 64);
        }
        if (lane == 0) { red[w] = s1; red[8 + w] = sq; }
        __syncthreads();
        if (t == 0) {
            float t1 = 0.f, t2 = 0.f;
#pragma unroll
            for (int i = 0; i < 8; ++i) { t1 += red[i]; t2 += red[8 + i]; }
            float mean = t1 * (1.0f / D_);
            stat[0] = mean;
            stat[1] = rsqrtf(t2 * (1.0f / D_) - mean * mean + 1e-5f);
        }
        __syncthreads();
    }
    t0[t] = fmaf((s2v - stat[0]) * stat[1], ln_m_g[t], ln_m_b[t]);
    __syncthreads();
    // ---- h = relu(t0 @ w1^T + b1)
    {
        const float4* wr = (const float4*)(w1 + (size_t)t * 512);
        float a = 0.f;
#pragma unroll 8
        for (int k4 = 0; k4 < 128; ++k4) {
            float4 w4 = wr[k4];
            float4 q0 = *(const float4*)&t0[k4 << 2];
            a = fmaf(q0.x, w4.x, a); a = fmaf(q0.y, w4.y, a);
            a = fmaf(q0.z, w4.z, a); a = fmaf(q0.w, w4.w, a);
        }
        hh[t] = fmaxf(a + b1[t], 0.f);
    }
    __syncthreads();
    // ---- out = s2 + hh @ w2^T + b2
    float ov;
    {
        const float4* wr = (const float4*)(w2 + (size_t)t * 512);
        float a = 0.f;
#pragma unroll 8
        for (int k4 = 0; k4 < 128; ++k4) {
            float4 w4 = wr[k4];
            float4 q0 = *(const float4*)&hh[k4 << 2];
            a = fmaf(q0.x, w4.x, a); a = fmaf(q0.y, w4.y, a);
            a = fmaf(q0.z, w4.z, a); a = fmaf(q0.w, w4.w, a);
        }
        ov = s2[t] + a + b2[t];
        dst[row * 512 + t] = ov;
    }
    if (last) return;
    // ---- stats of out, sn = LN_s(out)
    {
        float s1 = ov, sq = ov * ov;
#pragma unroll
        for (int off = 32; off > 0; off >>= 1) {
            s1 += __shfl_xor(s1, off, 64);
            sq += __shfl_xor(sq, off, 64);
        }
        if (lane == 0) { red[w] = s1; red[8 + w] = sq; }
        __syncthreads();
        if (t == 0) {
            float t1 = 0.f, t2 = 0.f;
#pragma unroll
            for (int i = 0; i < 8; ++i) { t1 += red[i]; t2 += red[8 + i]; }
            float mean = t1 * (1.0f / D_);
            stat[0] = mean;
            stat[1] = rsqrtf(t2 * (1.0f / D_) - mean * mean + 1e-5f);
        }
        __syncthreads();
    }
    t0[t] = fmaf((ov - stat[0]) * stat[1], ln_s_g[t], ln_s_b[t]);
    __syncthreads();
    // ---- qk = sn @ Mqk^T
    {
        const float4* wr = (const float4*)(wqkT + (size_t)t * 512);
        float a = 0.f;
#pragma unroll 8
        for (int k4 = 0; k4 < 128; ++k4) {
            float4 w4 = wr[k4];
            float4 q0 = *(const float4*)&t0[k4 << 2];
            a = fmaf(q0.x, w4.x, a); a = fmaf(q0.y, w4.y, a);
            a = fmaf(q0.z, w4.z, a); a = fmaf(q0.w, w4.w, a);
        }
        qkout[row * 512 + t] = a;
    }
}

// ---------------------------------------------------------------- launch
extern "C" void kernel_launch(void* const* d_in, const int* in_sizes, int n_in,
                              void* d_out, int out_size, void* d_ws, size_t ws_size,
                              hipStream_t stream) {
    const float* inputs  = (const float*)d_in[0];
    const float* noise   = (const float*)d_in[1];
    const float* mu      = (const float*)d_in[2];
    const float* sg      = (const float*)d_in[3];
    const float* ln_in_g = (const float*)d_in[4];
    const float* ln_in_b = (const float*)d_in[5];
    const float* ln_s_g  = (const float*)d_in[6];
    const float* ln_s_b  = (const float*)d_in[7];
    const float* wq      = (const float*)d_in[8];
    const float* wk      = (const float*)d_in[9];
    const float* wv      = (const float*)d_in[10];
    const float* w_ih    = (const float*)d_in[11];
    const float* w_hh    = (const float*)d_in[12];
    const float* b_ih    = (const float*)d_in[13];
    const float* b_hh    = (const float*)d_in[14];
    const float* ln_m_g  = (const float*)d_in[15];
    const float* ln_m_b  = (const float*)d_in[16];
    const float* w1      = (const float*)d_in[17];
    const float* b1      = (const float*)d_in[18];
    const float* w2      = (const float*)d_in[19];
    const float* b2      = (const float*)d_in[20];

    float* ws = (float*)d_ws;
    const size_t SLOT = (size_t)B_ * S_ * D_;      // 131072
    size_t o = 0;
    float* slots = ws + o; o += SLOT;
    float* qk    = ws + o; o += SLOT;
    float* u0    = ws + o; o += SLOT;
    float* gg    = ws + o; o += (size_t)256 * 3072;
    float* Mqk   = ws + o; o += (size_t)D_ * D_;
    float* Wiv   = ws + o; o += (size_t)3 * D_ * D_;
    float* statsS= ws + o; o += 512;
    float* part  = ws + o; o += (size_t)8 * B_ * 4096;
    float* bsum  = ws + o; o += (size_t)B_ * 8 * 16;
    float2* murs = (float2*)(ws + o); o += (size_t)2 * B_ * N_;

    // ---- prologue (2 dispatches)
    k_pro<<<576, 256, 0, stream>>>(wk, wq, w_ih, wv, Mqk, Wiv, noise, mu, sg, slots, statsS);
    k_gemm<1,1><<<dim3(16, 4), 256, 0, stream>>>(slots, Mqk, nullptr, qk,
                                                 256, 512, 512, statsS, ln_s_g, ln_s_b);

    for (int it = 0; it < ITERS_; ++it) {
        if (it == 0)
            k_attn_gh<1><<<256, 512, 0, stream>>>(inputs, qk, ln_in_g, ln_in_b, part, bsum,
                                                  murs, slots, w_hh, b_hh, gg);
        else
            k_attn_gh<0><<<256, 512, 0, stream>>>(inputs, qk, ln_in_g, ln_in_b, part, bsum,
                                                  murs, slots, w_hh, b_hh, gg);
        k_ured<<<256, 512, 0, stream>>>(part, bsum, ln_in_g, ln_in_b, u0);
        k_gi<<<dim3(48, 4), 256, 0, stream>>>(u0, Wiv, b_ih, gg);
        int last = (it == ITERS_ - 1);
        float* dst = last ? (float*)d_out : slots;
        k_p2<<<256, 512, 0, stream>>>(gg, slots, w1, b1, w2, b2, Mqk,
                                      ln_m_g, ln_m_b, ln_s_g, ln_s_b, dst, qk, last);
    }
}